// Round 2
// baseline (12778.696 us; speedup 1.0000x reference)
//
#include <hip/hip_runtime.h>
#include <cstdint>
#include <cstddef>

// Problem constants (fixed instance)
#define NN 100000
#define EE 320000
#define GG 2048
#define LL 8

// Workspace layout (float offsets). Total ~212 MB.
#define O_BUFA 0ull                      // zin / z buffer [N,256]
#define O_H    25600000ull               // h  [N,256] (t1 aliases this between MLP GEMMs)
#define O_GSUM 51200000ull               // per-graph col sums [G,256] (also meansum)
#define O_MSQ  (O_GSUM + 524288ull)      // [G]
#define O_BNS  (O_MSQ + 2048ull)         // [256]
#define O_BNSQ (O_BNS + 256ull)          // [256]
// zero-region-1 = O_GSUM .. O_BNSQ+256 : 526848 floats
#define O_ATTS (O_BNSQ + 256ull)         // [G,256]
#define O_MAXI (O_ATTS + 524288ull)      // [G,256] int
#define O_WSUM (O_MAXI + 524288ull)      // [G]
// zero-region-2 = O_ATTS .. O_WSUM+2048 : 1050624 floats
#define O_ABUF (O_WSUM + 2048ull)        // [256] bn scale
#define O_BBUF (O_ABUF + 256ull)         // [256] bn shift
#define O_CNTI (O_BBUF + 256ull)         // [G] int
#define O_CNTF (O_CNTI + 2048ull)        // [G]
#define O_SCOR (O_CNTF + 2048ull)        // [N]
#define O_WEFF (O_SCOR + 100000ull)      // [L,6,256] fused edge weights
#define O_BEFF (O_WEFF + 12288ull)       // [L,256] fused edge bias
// total = O_BEFF + 2048 = 52,896,416 floats ~= 211.6 MB

__global__ __launch_bounds__(256) void k_zero(float* __restrict__ p, int n) {
  int i = blockIdx.x * 256 + threadIdx.x;
  int stride = gridDim.x * 256;
  for (; i < n; i += stride) p[i] = 0.0f;
}

__global__ __launch_bounds__(256) void k_count(const int* __restrict__ batch, int* __restrict__ cnti, int n) {
  int i = blockIdx.x * 256 + threadIdx.x;
  if (i < n) atomicAdd(&cnti[batch[i]], 1);
}

__global__ __launch_bounds__(256) void k_cntf(const int* __restrict__ cnti, float* __restrict__ cntf, int g) {
  int i = blockIdx.x * 256 + threadIdx.x;
  if (i < g) { float v = (float)cnti[i]; cntf[i] = v > 1.0f ? v : 1.0f; }
}

// W_eff[i] = edge_w @ conv_w[i]  [6,128]@[128,256]; b_eff[i] = edge_b @ conv_w[i] + conv_b[i]
// one block per layer
__global__ __launch_bounds__(256) void k_wfuse(const float* __restrict__ edge_w, const float* __restrict__ edge_b,
                                               const float* __restrict__ conv_w, const float* __restrict__ conv_b,
                                               float* __restrict__ wef, float* __restrict__ bef) {
  __shared__ float ew[6 * 128 + 128];
  int i = blockIdx.x;
  int c = threadIdx.x;
  for (int idx = c; idx < 896; idx += 256)
    ew[idx] = idx < 768 ? edge_w[idx] : edge_b[idx - 768];
  __syncthreads();
  float acc[7] = {0.f, 0.f, 0.f, 0.f, 0.f, 0.f, 0.f};
  const float* cw = conv_w + (size_t)i * 32768 + c;
  for (int j = 0; j < 128; ++j) {
    float w = cw[(size_t)j * 256];
#pragma unroll
    for (int k = 0; k < 6; ++k) acc[k] = fmaf(ew[k * 128 + j], w, acc[k]);
    acc[6] = fmaf(ew[768 + j], w, acc[6]);
  }
#pragma unroll
  for (int k = 0; k < 6; ++k) wef[(size_t)i * 1536 + k * 256 + c] = acc[k];
  bef[(size_t)i * 256 + c] = acc[6] + conv_b[(size_t)i * 256 + c];
}

// h = x @ node_w + node_b   [N,48]@[48,256]
__global__ __launch_bounds__(256) void k_node_embed(const float* __restrict__ x, const float* __restrict__ w,
                                                    const float* __restrict__ b, float* __restrict__ h, int n) {
  __shared__ float xs[16 * 48];
  int tid = threadIdx.x;
  int row0 = blockIdx.x * 16;
  for (int idx = tid; idx < 16 * 48; idx += 256) {
    int r = idx / 48, c = idx - r * 48;
    int gr = row0 + r; if (gr >= n) gr = n - 1;
    xs[idx] = x[(size_t)gr * 48 + c];
  }
  __syncthreads();
  float acc[16];
#pragma unroll
  for (int r = 0; r < 16; ++r) acc[r] = 0.0f;
  for (int k = 0; k < 48; ++k) {
    float wv = w[k * 256 + tid];
#pragma unroll
    for (int r = 0; r < 16; ++r) acc[r] = fmaf(xs[r * 48 + k], wv, acc[r]);
  }
  float bb = b[tid];
#pragma unroll
  for (int r = 0; r < 16; ++r) {
    int gr = row0 + r;
    if (gr < n) h[(size_t)gr * 256 + tid] = acc[r] + bb;
  }
}

// zin = (1+eps[layer]) * h  (vectorized)
__global__ __launch_bounds__(256) void k_scale(const float* __restrict__ h, float* __restrict__ zin,
                                               const float* __restrict__ eps, int layer, int n4) {
  float s = 1.0f + eps[layer];
  int i = blockIdx.x * 256 + threadIdx.x;
  int stride = gridDim.x * 256;
  const float4* h4 = (const float4*)h;
  float4* z4 = (float4*)zin;
  for (; i < n4; i += stride) {
    float4 v = h4[i];
    v.x *= s; v.y *= s; v.z *= s; v.w *= s;
    z4[i] = v;
  }
}

// edge message + scatter: zin[dst] += relu(h[src] + ea@W_eff + b_eff)
// one wave per edge batch; lane covers 4 cols. 8 edges per wave, 4 waves/block.
__global__ __launch_bounds__(256) void k_edgemsg(const float* __restrict__ ea,
                                                 const float* __restrict__ wef, const float* __restrict__ bef,
                                                 const int* __restrict__ esrc, const int* __restrict__ edst,
                                                 const float* __restrict__ h, float* __restrict__ zin, int ne) {
  int lane = threadIdx.x & 63;
  int wv = threadIdx.x >> 6;
  int c0 = lane * 4;
  float4 w0 = *(const float4*)(wef + 0 * 256 + c0);
  float4 w1 = *(const float4*)(wef + 1 * 256 + c0);
  float4 w2 = *(const float4*)(wef + 2 * 256 + c0);
  float4 w3 = *(const float4*)(wef + 3 * 256 + c0);
  float4 w4 = *(const float4*)(wef + 4 * 256 + c0);
  float4 w5 = *(const float4*)(wef + 5 * 256 + c0);
  float4 bf = *(const float4*)(bef + c0);
  int r0 = blockIdx.x * 32 + wv * 8;
  int rend = r0 + 8 < ne ? r0 + 8 : ne;
  for (int r = r0; r < rend; ++r) {
    int s = esrc[r], d = edst[r];
    const float* eap = ea + (size_t)r * 6;
    float a0 = eap[0], a1 = eap[1], a2 = eap[2], a3 = eap[3], a4 = eap[4], a5 = eap[5];
    float4 hv = *(const float4*)(h + (size_t)s * 256 + c0);
    float mx = fmaf(a0, w0.x, fmaf(a1, w1.x, fmaf(a2, w2.x, fmaf(a3, w3.x, fmaf(a4, w4.x, fmaf(a5, w5.x, hv.x + bf.x))))));
    float my = fmaf(a0, w0.y, fmaf(a1, w1.y, fmaf(a2, w2.y, fmaf(a3, w3.y, fmaf(a4, w4.y, fmaf(a5, w5.y, hv.y + bf.y))))));
    float mz = fmaf(a0, w0.z, fmaf(a1, w1.z, fmaf(a2, w2.z, fmaf(a3, w3.z, fmaf(a4, w4.z, fmaf(a5, w5.z, hv.z + bf.z))))));
    float mw = fmaf(a0, w0.w, fmaf(a1, w1.w, fmaf(a2, w2.w, fmaf(a3, w3.w, fmaf(a4, w4.w, fmaf(a5, w5.w, hv.w + bf.w))))));
    mx = mx > 0.f ? mx : 0.f;
    my = my > 0.f ? my : 0.f;
    mz = mz > 0.f ? mz : 0.f;
    mw = mw > 0.f ? mw : 0.f;
    float* zp = zin + (size_t)d * 256 + c0;
    atomicAdd(zp + 0, mx);
    atomicAdd(zp + 1, my);
    atomicAdd(zp + 2, mz);
    atomicAdd(zp + 3, mw);
  }
}

// Tiled fp32 GEMM: C[M,?] = op(A[M,K] @ B[K,ncols] tile + bias)
// block 256 threads, tile 128x128, 8x8 per thread, K-tile 16.
// MODE: 0 plain, 1 relu, 2 tanh
template <int MODE>
__global__ __launch_bounds__(256) void k_gemm(const float* __restrict__ A, int lda,
                                              const float* __restrict__ B, int ldb,
                                              const float* __restrict__ bias,
                                              float* __restrict__ C, int ldc,
                                              int M, int K) {
  __shared__ __align__(16) float As[16 * 132];
  __shared__ __align__(16) float Bs[16 * 128];
  int tid = threadIdx.x;
  int tx = tid & 15, ty = tid >> 4;
  int row0 = blockIdx.y * 128;
  int col0 = blockIdx.x * 128;
  float acc[8][8];
#pragma unroll
  for (int i = 0; i < 8; ++i)
#pragma unroll
    for (int j = 0; j < 8; ++j) acc[i][j] = 0.0f;

  int arr = tid >> 2, akq = tid & 3;
  int bkr = tid >> 5, bcq = tid & 31;

  for (int k0 = 0; k0 < K; k0 += 16) {
    __syncthreads();
#pragma unroll
    for (int it = 0; it < 2; ++it) {
      int r = arr + it * 64;
      int gr = row0 + r; if (gr >= M) gr = M - 1;
      float4 v = *(const float4*)(A + (size_t)gr * lda + k0 + akq * 4);
      As[(akq * 4 + 0) * 132 + r] = v.x;
      As[(akq * 4 + 1) * 132 + r] = v.y;
      As[(akq * 4 + 2) * 132 + r] = v.z;
      As[(akq * 4 + 3) * 132 + r] = v.w;
    }
#pragma unroll
    for (int it = 0; it < 2; ++it) {
      int k = bkr + it * 8;
      *(float4*)(Bs + k * 128 + bcq * 4) = *(const float4*)(B + (size_t)(k0 + k) * ldb + col0 + bcq * 4);
    }
    __syncthreads();
#pragma unroll
    for (int kt = 0; kt < 16; ++kt) {
      float4 a0 = *(const float4*)(As + kt * 132 + ty * 8);
      float4 a1 = *(const float4*)(As + kt * 132 + ty * 8 + 4);
      float4 b0 = *(const float4*)(Bs + kt * 128 + tx * 8);
      float4 b1 = *(const float4*)(Bs + kt * 128 + tx * 8 + 4);
      float av[8] = {a0.x, a0.y, a0.z, a0.w, a1.x, a1.y, a1.z, a1.w};
      float bv[8] = {b0.x, b0.y, b0.z, b0.w, b1.x, b1.y, b1.z, b1.w};
#pragma unroll
      for (int i = 0; i < 8; ++i)
#pragma unroll
        for (int j = 0; j < 8; ++j) acc[i][j] = fmaf(av[i], bv[j], acc[i][j]);
    }
  }

  int gc = col0 + tx * 8;
  float4 bb0 = *(const float4*)(bias + gc);
  float4 bb1 = *(const float4*)(bias + gc + 4);
  float bvv[8] = {bb0.x, bb0.y, bb0.z, bb0.w, bb1.x, bb1.y, bb1.z, bb1.w};

#pragma unroll
  for (int i = 0; i < 8; ++i) {
    int gr = row0 + ty * 8 + i;
    if (gr >= M) break;
    float o[8];
#pragma unroll
    for (int j = 0; j < 8; ++j) {
      float v = acc[i][j] + bvv[j];
      if (MODE == 1) v = v > 0.0f ? v : 0.0f;
      if (MODE == 2) v = tanhf(v);
      o[j] = v;
    }
    *(float4*)(C + (size_t)gr * ldc + gc) = make_float4(o[0], o[1], o[2], o[3]);
    *(float4*)(C + (size_t)gr * ldc + gc + 4) = make_float4(o[4], o[5], o[6], o[7]);
  }
}

// per-column sum / sumsq over N rows
__global__ __launch_bounds__(256) void k_bn_stats(const float* __restrict__ z, float* __restrict__ bns,
                                                  float* __restrict__ bnsq, int n) {
  int col = threadIdx.x;
  float s = 0.0f, s2 = 0.0f;
  for (int r = blockIdx.x; r < n; r += gridDim.x) {
    float v = z[(size_t)r * 256 + col];
    s += v;
    s2 = fmaf(v, v, s2);
  }
  atomicAdd(&bns[col], s);
  atomicAdd(&bnsq[col], s2);
}

__global__ __launch_bounds__(256) void k_bn_fin(const float* __restrict__ bns, const float* __restrict__ bnsq,
                                                const float* __restrict__ gamma, const float* __restrict__ beta,
                                                float* __restrict__ abuf, float* __restrict__ bbuf, int n) {
  int c = threadIdx.x;
  float inv = 1.0f / (float)n;
  float mu = bns[c] * inv;
  float var = bnsq[c] * inv - mu * mu;
  float rstd = rsqrtf(var + 1e-5f);
  float a = gamma[c] * rstd;
  abuf[c] = a;
  bbuf[c] = beta[c] - mu * a;
}

// per-graph column sums of bn(z); sorted-batch segmented flush
__global__ __launch_bounds__(256) void k_gsum(const float* __restrict__ z, const float* __restrict__ a,
                                              const float* __restrict__ b, const int* __restrict__ batch,
                                              float* __restrict__ gsum, int n) {
  int tid = threadIdx.x;
  int r0 = blockIdx.x * 64;
  int rend = r0 + 64 < n ? r0 + 64 : n;
  float av = a[tid], bv = b[tid];
  float acc = 0.0f;
  int gcur = batch[r0];
  for (int r = r0; r < rend; ++r) {
    int g = batch[r];
    if (g != gcur) { atomicAdd(&gsum[(size_t)gcur * 256 + tid], acc); acc = 0.0f; gcur = g; }
    acc = fmaf(av, z[(size_t)r * 256 + tid], acc + bv);
  }
  atomicAdd(&gsum[(size_t)gcur * 256 + tid], acc);
}

// per-graph sum of row-sumsq of centered bn(z); one wave per 16-row strip
__global__ __launch_bounds__(256) void k_msq(const float* __restrict__ z, const float* __restrict__ a,
                                             const float* __restrict__ b, const int* __restrict__ batch,
                                             const float* __restrict__ gsum, const float* __restrict__ cntf,
                                             float* __restrict__ msq, int n) {
  int lane = threadIdx.x & 63;
  int wv = threadIdx.x >> 6;
  int r0 = (blockIdx.x * 4 + wv) * 16;
  if (r0 >= n) return;
  int rend = r0 + 16 < n ? r0 + 16 : n;
  float4 a4 = *(const float4*)(a + lane * 4);
  float4 b4 = *(const float4*)(b + lane * 4);
  float acc = 0.0f;
  int gcur = batch[r0];
  float ic = 1.0f / cntf[gcur];
  for (int r = r0; r < rend; ++r) {
    int g = batch[r];
    if (g != gcur) {
      float s = acc;
#pragma unroll
      for (int off = 32; off; off >>= 1) s += __shfl_xor(s, off, 64);
      if (lane == 0) atomicAdd(&msq[gcur], s);
      acc = 0.0f; gcur = g; ic = 1.0f / cntf[g];
    }
    float4 z4 = *(const float4*)(z + (size_t)r * 256 + lane * 4);
    float4 g4 = *(const float4*)(gsum + (size_t)g * 256 + lane * 4);
    float vx = fmaf(a4.x, z4.x, b4.x) - g4.x * ic;
    float vy = fmaf(a4.y, z4.y, b4.y) - g4.y * ic;
    float vz = fmaf(a4.z, z4.z, b4.z) - g4.z * ic;
    float vw = fmaf(a4.w, z4.w, b4.w) - g4.w * ic;
    acc += vx * vx + vy * vy + vz * vz + vw * vw;
  }
  float s = acc;
#pragma unroll
  for (int off = 32; off; off >>= 1) s += __shfl_xor(s, off, 64);
  if (lane == 0) atomicAdd(&msq[gcur], s);
}

// h = relu((bn(z) - gmean) * rinv)
__global__ __launch_bounds__(256) void k_apply(const float* __restrict__ z, const float* __restrict__ a,
                                               const float* __restrict__ b, const int* __restrict__ batch,
                                               const float* __restrict__ gsum, const float* __restrict__ cntf,
                                               const float* __restrict__ msq, float* __restrict__ h, int n) {
  int tid = threadIdx.x;
  int r0 = blockIdx.x * 64;
  int rend = r0 + 64 < n ? r0 + 64 : n;
  float av = a[tid], bv = b[tid];
  int gcur = -1;
  float gm = 0.0f, rinv = 0.0f;
  for (int r = r0; r < rend; ++r) {
    int g = batch[r];
    if (g != gcur) {
      gcur = g;
      float ic = 1.0f / cntf[g];
      gm = gsum[(size_t)g * 256 + tid] * ic;
      rinv = rsqrtf(1e-5f + msq[g] * ic);
    }
    float v = (fmaf(av, z[(size_t)r * 256 + tid], bv) - gm) * rinv;
    h[(size_t)r * 256 + tid] = v > 0.0f ? v : 0.0f;
  }
}

// scores[r] = t1[r,:] @ att_w2 + att_b2 ; one wave per row (grid-stride)
__global__ __launch_bounds__(256) void k_att_score(const float* __restrict__ t1, const float* __restrict__ w2,
                                                   const float* __restrict__ b2, float* __restrict__ scores, int n) {
  int lane = threadIdx.x & 63;
  int wv = threadIdx.x >> 6;
  int gw = blockIdx.x * 4 + wv;
  int nw = gridDim.x * 4;
  float2 w = *(const float2*)(w2 + lane * 2);
  float bb = b2[0];
  for (int r = gw; r < n; r += nw) {
    float2 v = *(const float2*)(t1 + (size_t)r * 128 + lane * 2);
    float s = v.x * w.x + v.y * w.y;
#pragma unroll
    for (int off = 32; off; off >>= 1) s += __shfl_xor(s, off, 64);
    if (lane == 0) scores[r] = s + bb;
  }
}

// fused pooling: mean-sum, max (int bits), att-sum, wsum — segmented flush
__global__ __launch_bounds__(256) void k_pool(const float* __restrict__ h, const float* __restrict__ scores,
                                              const int* __restrict__ batch, float* __restrict__ meansum,
                                              float* __restrict__ attsum, int* __restrict__ maxbuf,
                                              float* __restrict__ wsum, int n) {
  int tid = threadIdx.x;
  int r0 = blockIdx.x * 64;
  int rend = r0 + 64 < n ? r0 + 64 : n;
  float ma = 0.0f, aa = 0.0f, mx = 0.0f, wa = 0.0f;
  int gcur = batch[r0];
  for (int r = r0; r < rend; ++r) {
    int g = batch[r];
    if (g != gcur) {
      atomicAdd(&meansum[(size_t)gcur * 256 + tid], ma);
      atomicAdd(&attsum[(size_t)gcur * 256 + tid], aa);
      atomicMax(&maxbuf[(size_t)gcur * 256 + tid], __float_as_int(mx));
      if (tid == 0) atomicAdd(&wsum[gcur], wa);
      ma = 0.0f; aa = 0.0f; mx = 0.0f; wa = 0.0f;
      gcur = g;
    }
    float w = __expf(scores[r]);
    float hv = h[(size_t)r * 256 + tid];
    ma += hv;
    aa = fmaf(hv, w, aa);
    mx = fmaxf(mx, hv);
    wa += w;
  }
  atomicAdd(&meansum[(size_t)gcur * 256 + tid], ma);
  atomicAdd(&attsum[(size_t)gcur * 256 + tid], aa);
  atomicMax(&maxbuf[(size_t)gcur * 256 + tid], __float_as_int(mx));
  if (tid == 0) atomicAdd(&wsum[gcur], wa);
}

__global__ __launch_bounds__(256) void k_out(const float* __restrict__ meansum, const int* __restrict__ maxbuf,
                                             const float* __restrict__ attsum, const float* __restrict__ wsum,
                                             const float* __restrict__ cntf, float* __restrict__ out) {
  int g = blockIdx.x;
  int c = threadIdx.x;
  out[(size_t)g * 768 + c] = meansum[(size_t)g * 256 + c] / cntf[g];
  out[(size_t)g * 768 + 256 + c] = __int_as_float(maxbuf[(size_t)g * 256 + c]);
  out[(size_t)g * 768 + 512 + c] = attsum[(size_t)g * 256 + c] / (wsum[g] + 1e-8f);
}

extern "C" void kernel_launch(void* const* d_in, const int* in_sizes, int n_in,
                              void* d_out, int out_size, void* d_ws, size_t ws_size,
                              hipStream_t stream) {
  const float* x         = (const float*)d_in[0];
  const float* edge_attr = (const float*)d_in[1];
  const float* node_w    = (const float*)d_in[2];
  const float* node_b    = (const float*)d_in[3];
  const float* edge_w    = (const float*)d_in[4];
  const float* edge_b    = (const float*)d_in[5];
  const float* conv_w    = (const float*)d_in[6];
  const float* conv_b    = (const float*)d_in[7];
  const float* mlp_w1    = (const float*)d_in[8];
  const float* mlp_b1    = (const float*)d_in[9];
  const float* mlp_w2    = (const float*)d_in[10];
  const float* mlp_b2    = (const float*)d_in[11];
  const float* eps       = (const float*)d_in[12];
  const float* bn_gamma  = (const float*)d_in[13];
  const float* bn_beta   = (const float*)d_in[14];
  const float* att_w1    = (const float*)d_in[15];
  const float* att_b1    = (const float*)d_in[16];
  const float* att_w2    = (const float*)d_in[17];
  const float* att_b2    = (const float*)d_in[18];
  const int*   eidx      = (const int*)d_in[19];
  const int*   batch     = (const int*)d_in[20];
  float* out = (float*)d_out;
  float* ws  = (float*)d_ws;

  float* bufA  = ws + O_BUFA;
  float* h     = ws + O_H;      // also t1 between the two MLP GEMMs
  float* gsum  = ws + O_GSUM;
  float* msq   = ws + O_MSQ;
  float* bns   = ws + O_BNS;
  float* bnsq  = ws + O_BNSQ;
  float* atts  = ws + O_ATTS;
  int*   maxi  = (int*)(ws + O_MAXI);
  float* wsum  = ws + O_WSUM;
  float* abuf  = ws + O_ABUF;
  float* bbuf  = ws + O_BBUF;
  int*   cnti  = (int*)(ws + O_CNTI);
  float* cntf  = ws + O_CNTF;
  float* scor  = ws + O_SCOR;
  float* weff  = ws + O_WEFF;
  float* beff  = ws + O_BEFF;
  const int* esrc = eidx;
  const int* edst = eidx + EE;

  // graph counts
  k_zero<<<64, 256, 0, stream>>>((float*)cnti, GG);
  k_count<<<(NN + 255) / 256, 256, 0, stream>>>(batch, cnti, NN);
  k_cntf<<<(GG + 255) / 256, 256, 0, stream>>>(cnti, cntf, GG);

  // fused edge weights (all layers)
  k_wfuse<<<LL, 256, 0, stream>>>(edge_w, edge_b, conv_w, conv_b, weff, beff);

  // node embedding
  k_node_embed<<<(NN + 15) / 16, 256, 0, stream>>>(x, node_w, node_b, h, NN);

  const int mtiles_n = (NN + 127) / 128;  // 782

  for (int i = 0; i < LL; ++i) {
    // zero per-layer stats region: gsum + msq + bns + bnsq (contiguous)
    k_zero<<<1024, 256, 0, stream>>>(gsum, 524288 + 2048 + 256 + 256);
    // zin = (1+eps)h
    k_scale<<<4096, 256, 0, stream>>>(h, bufA, eps, i, NN * 64);
    // edge msg + scatter: zin += relu(h[src] + ea@W_eff + b_eff) at dst
    k_edgemsg<<<(EE + 31) / 32, 256, 0, stream>>>(edge_attr, weff + (size_t)i * 1536, beff + (size_t)i * 256,
                                                  esrc, edst, h, bufA, EE);
    // t1 = relu(zin @ w1 + b1)   (t1 overwrites h — h is dead after edge scatter)
    k_gemm<1><<<dim3(2, mtiles_n), 256, 0, stream>>>(bufA, 256, mlp_w1 + (size_t)i * 65536, 256,
                                                     mlp_b1 + (size_t)i * 256, h, 256, NN, 256);
    // z = t1 @ w2 + b2  (overwrites bufA)
    k_gemm<0><<<dim3(2, mtiles_n), 256, 0, stream>>>(h, 256, mlp_w2 + (size_t)i * 65536, 256,
                                                     mlp_b2 + (size_t)i * 256, bufA, 256, NN, 256);
    // batchnorm stats + scale/shift
    k_bn_stats<<<1024, 256, 0, stream>>>(bufA, bns, bnsq, NN);
    k_bn_fin<<<1, 256, 0, stream>>>(bns, bnsq, bn_gamma + (size_t)i * 256, bn_beta + (size_t)i * 256,
                                    abuf, bbuf, NN);
    // pairnorm: per-graph sums, msq, apply (writes h)
    k_gsum<<<(NN + 63) / 64, 256, 0, stream>>>(bufA, abuf, bbuf, batch, gsum, NN);
    k_msq<<<(NN + 63) / 64, 256, 0, stream>>>(bufA, abuf, bbuf, batch, gsum, cntf, msq, NN);
    k_apply<<<(NN + 63) / 64, 256, 0, stream>>>(bufA, abuf, bbuf, batch, gsum, cntf, msq, h, NN);
  }

  // pooling
  k_zero<<<1024, 256, 0, stream>>>(gsum, 524288 + 2048 + 256 + 256);          // meansum reuse
  k_zero<<<1024, 256, 0, stream>>>(atts, 524288 + 524288 + 2048);             // attsum, maxbuf, wsum
  // att hidden = tanh(h @ att_w1 + b1) -> bufA [N,128] (bufA dead after k_apply)
  k_gemm<2><<<dim3(1, mtiles_n), 256, 0, stream>>>(h, 256, att_w1, 128, att_b1, bufA, 128, NN, 256);
  k_att_score<<<1024, 256, 0, stream>>>(bufA, att_w2, att_b2, scor, NN);
  k_pool<<<(NN + 63) / 64, 256, 0, stream>>>(h, scor, batch, gsum, atts, maxi, wsum, NN);
  k_out<<<GG, 256, 0, stream>>>(gsum, maxi, atts, wsum, cntf, out);
}

// Round 3
// 4261.230 us; speedup vs baseline: 2.9988x; 2.9988x over previous
//
#include <hip/hip_runtime.h>
#include <cstdint>
#include <cstddef>

// Problem constants (fixed instance)
#define NN 100000
#define EE 320000
#define GG 2048
#define LL 8

// Workspace layout (float offsets). Total ~225 MB.
#define O_BUFA 0ull                      // zin / z buffer [N,256]
#define O_H    25600000ull               // h [N,256] (t1 aliases between MLP GEMMs)
#define O_GSUM 51200000ull               // per-graph col sums S1 [G,256] -> gmean -> meansum
#define O_GSQ  (O_GSUM + 524288ull)      // per-graph col sumsq S2 [G,256]
#define O_MSQ  (O_GSQ + 524288ull)       // [G] rinv
#define O_ATTS (O_MSQ + 2048ull)         // [G,256]
#define O_MAXI (O_ATTS + 524288ull)      // [G,256] int
#define O_WSUM (O_MAXI + 524288ull)      // [G]
// zero-region-pool = O_ATTS .. O_WSUM+2048 : 1050624 floats
#define O_ABUF (O_WSUM + 2048ull)        // [256] bn scale
#define O_BBUF (O_ABUF + 256ull)         // [256] bn shift
#define O_CNTI (O_BBUF + 256ull)         // [G] int (real counts)
#define O_CNTF (O_CNTI + 2048ull)        // [G] clamped float counts
#define O_SCOR (O_CNTF + 2048ull)        // [N] scores (aliased as CSR cursor during setup)
#define O_WEFF (O_SCOR + 100000ull)      // [L,6,256]
#define O_BEFF (O_WEFF + 12288ull)       // [L,256]
#define O_DEG  (O_BEFF + 2048ull)        // [N] int
#define O_STRT (O_DEG + 100000ull)       // [N] int
#define O_BSUM (O_STRT + 100000ull)      // [512] int
#define O_CSR  (O_BSUM + 512ull)         // [E,8] floats: 0-5 edge_attr, 6 src (int bits)
// total = O_CSR + 2560000 = 56,180,704 floats ~= 225 MB

__global__ __launch_bounds__(256) void k_zero(float* __restrict__ p, int n) {
  int i = blockIdx.x * 256 + threadIdx.x;
  int stride = gridDim.x * 256;
  for (; i < n; i += stride) p[i] = 0.0f;
}

__global__ __launch_bounds__(256) void k_count(const int* __restrict__ batch, int* __restrict__ cnti, int n) {
  int i = blockIdx.x * 256 + threadIdx.x;
  if (i < n) atomicAdd(&cnti[batch[i]], 1);
}

__global__ __launch_bounds__(256) void k_cntf(const int* __restrict__ cnti, float* __restrict__ cntf, int g) {
  int i = blockIdx.x * 256 + threadIdx.x;
  if (i < g) { float v = (float)cnti[i]; cntf[i] = v > 1.0f ? v : 1.0f; }
}

// ---------------- CSR build (once per call) ----------------
__global__ __launch_bounds__(256) void k_deg(const int* __restrict__ edst, int* __restrict__ deg, int ne) {
  int e = blockIdx.x * 256 + threadIdx.x;
  if (e < ne) atomicAdd(&deg[edst[e]], 1);
}

__global__ __launch_bounds__(256) void k_scan_part(const int* __restrict__ deg, int* __restrict__ start,
                                                   int* __restrict__ bsum, int n) {
  __shared__ int s[256];
  int i = blockIdx.x * 256 + threadIdx.x;
  int t = threadIdx.x;
  int v = (i < n) ? deg[i] : 0;
  s[t] = v;
  __syncthreads();
  for (int off = 1; off < 256; off <<= 1) {
    int u = (t >= off) ? s[t - off] : 0;
    __syncthreads();
    s[t] += u;
    __syncthreads();
  }
  if (i < n) start[i] = s[t] - v;  // exclusive
  if (t == 255) bsum[blockIdx.x] = s[255];
}

__global__ __launch_bounds__(512) void k_scan_top(int* __restrict__ bsum, int nb) {
  __shared__ int s[512];
  int t = threadIdx.x;
  int v = (t < nb) ? bsum[t] : 0;
  s[t] = v;
  __syncthreads();
  for (int off = 1; off < 512; off <<= 1) {
    int u = (t >= off) ? s[t - off] : 0;
    __syncthreads();
    s[t] += u;
    __syncthreads();
  }
  if (t < nb) bsum[t] = s[t] - v;  // exclusive
}

__global__ __launch_bounds__(256) void k_scan_add(int* __restrict__ start, const int* __restrict__ bsum,
                                                  int* __restrict__ cursor, int n) {
  int i = blockIdx.x * 256 + threadIdx.x;
  if (i < n) {
    int v = start[i] + bsum[blockIdx.x];
    start[i] = v;
    cursor[i] = v;
  }
}

__global__ __launch_bounds__(256) void k_fill(const float* __restrict__ ea, const int* __restrict__ esrc,
                                              const int* __restrict__ edst, int* __restrict__ cursor,
                                              float* __restrict__ csr, int ne) {
  int e = blockIdx.x * 256 + threadIdx.x;
  if (e >= ne) return;
  int d = edst[e];
  int slot = atomicAdd(&cursor[d], 1);
  float* p = csr + (size_t)slot * 8;
  const float* ap = ea + (size_t)e * 6;
  p[0] = ap[0]; p[1] = ap[1]; p[2] = ap[2];
  p[3] = ap[3]; p[4] = ap[4]; p[5] = ap[5];
  ((int*)p)[6] = esrc[e];
}

// W_eff[i] = edge_w @ conv_w[i]; b_eff[i] = edge_b @ conv_w[i] + conv_b[i] — one block per layer
__global__ __launch_bounds__(256) void k_wfuse(const float* __restrict__ edge_w, const float* __restrict__ edge_b,
                                               const float* __restrict__ conv_w, const float* __restrict__ conv_b,
                                               float* __restrict__ wef, float* __restrict__ bef) {
  __shared__ float ew[6 * 128 + 128];
  int i = blockIdx.x;
  int c = threadIdx.x;
  for (int idx = c; idx < 896; idx += 256)
    ew[idx] = idx < 768 ? edge_w[idx] : edge_b[idx - 768];
  __syncthreads();
  float acc[7] = {0.f, 0.f, 0.f, 0.f, 0.f, 0.f, 0.f};
  const float* cw = conv_w + (size_t)i * 32768 + c;
  for (int j = 0; j < 128; ++j) {
    float w = cw[(size_t)j * 256];
#pragma unroll
    for (int k = 0; k < 6; ++k) acc[k] = fmaf(ew[k * 128 + j], w, acc[k]);
    acc[6] = fmaf(ew[768 + j], w, acc[6]);
  }
#pragma unroll
  for (int k = 0; k < 6; ++k) wef[(size_t)i * 1536 + k * 256 + c] = acc[k];
  bef[(size_t)i * 256 + c] = acc[6] + conv_b[(size_t)i * 256 + c];
}

// h = x @ node_w + node_b   [N,48]@[48,256]
__global__ __launch_bounds__(256) void k_node_embed(const float* __restrict__ x, const float* __restrict__ w,
                                                    const float* __restrict__ b, float* __restrict__ h, int n) {
  __shared__ float xs[16 * 48];
  int tid = threadIdx.x;
  int row0 = blockIdx.x * 16;
  for (int idx = tid; idx < 16 * 48; idx += 256) {
    int r = idx / 48, c = idx - r * 48;
    int gr = row0 + r; if (gr >= n) gr = n - 1;
    xs[idx] = x[(size_t)gr * 48 + c];
  }
  __syncthreads();
  float acc[16];
#pragma unroll
  for (int r = 0; r < 16; ++r) acc[r] = 0.0f;
  for (int k = 0; k < 48; ++k) {
    float wv = w[k * 256 + tid];
#pragma unroll
    for (int r = 0; r < 16; ++r) acc[r] = fmaf(xs[r * 48 + k], wv, acc[r]);
  }
  float bb = b[tid];
#pragma unroll
  for (int r = 0; r < 16; ++r) {
    int gr = row0 + r;
    if (gr < n) h[(size_t)gr * 256 + tid] = acc[r] + bb;
  }
}

// zin[v] = (1+eps)h[v] + sum_{e: dst=v} relu(h[src_e] + ea_e @ W_eff + b_eff)
// one wave per node (4 nodes/block); lane covers 4 cols. No atomics (CSR gather).
__global__ __launch_bounds__(256) void k_edge_csr(const float* __restrict__ csr,
                                                  const int* __restrict__ startv, const int* __restrict__ degv,
                                                  const float* __restrict__ wef, const float* __restrict__ bef,
                                                  const float* __restrict__ h, float* __restrict__ zin,
                                                  const float* __restrict__ eps, int layer, int n) {
  int lane = threadIdx.x & 63;
  int wv = threadIdx.x >> 6;
  int v = blockIdx.x * 4 + wv;
  if (v >= n) return;
  int c0 = lane * 4;
  float4 w0 = *(const float4*)(wef + 0 * 256 + c0);
  float4 w1 = *(const float4*)(wef + 1 * 256 + c0);
  float4 w2 = *(const float4*)(wef + 2 * 256 + c0);
  float4 w3 = *(const float4*)(wef + 3 * 256 + c0);
  float4 w4 = *(const float4*)(wef + 4 * 256 + c0);
  float4 w5 = *(const float4*)(wef + 5 * 256 + c0);
  float4 bf = *(const float4*)(bef + c0);
  int st = startv[v], dg = degv[v];
  float s = 1.0f + eps[layer];
  float4 hv = *(const float4*)(h + (size_t)v * 256 + c0);
  float ax = s * hv.x, ay = s * hv.y, az = s * hv.z, aw = s * hv.w;
  for (int j = st; j < st + dg; ++j) {
    const float* p = csr + (size_t)j * 8;
    float4 e03 = *(const float4*)p;
    float2 e45 = *(const float2*)(p + 4);
    int sidx = ((const int*)p)[6];
    float4 hs = *(const float4*)(h + (size_t)sidx * 256 + c0);
    float mx = fmaf(e03.x, w0.x, fmaf(e03.y, w1.x, fmaf(e03.z, w2.x, fmaf(e03.w, w3.x, fmaf(e45.x, w4.x, fmaf(e45.y, w5.x, hs.x + bf.x))))));
    float my = fmaf(e03.x, w0.y, fmaf(e03.y, w1.y, fmaf(e03.z, w2.y, fmaf(e03.w, w3.y, fmaf(e45.x, w4.y, fmaf(e45.y, w5.y, hs.y + bf.y))))));
    float mz = fmaf(e03.x, w0.z, fmaf(e03.y, w1.z, fmaf(e03.z, w2.z, fmaf(e03.w, w3.z, fmaf(e45.x, w4.z, fmaf(e45.y, w5.z, hs.z + bf.z))))));
    float mw = fmaf(e03.x, w0.w, fmaf(e03.y, w1.w, fmaf(e03.z, w2.w, fmaf(e03.w, w3.w, fmaf(e45.x, w4.w, fmaf(e45.y, w5.w, hs.w + bf.w))))));
    ax += mx > 0.f ? mx : 0.f;
    ay += my > 0.f ? my : 0.f;
    az += mz > 0.f ? mz : 0.f;
    aw += mw > 0.f ? mw : 0.f;
  }
  *(float4*)(zin + (size_t)v * 256 + c0) = make_float4(ax, ay, az, aw);
}

// Tiled fp32 GEMM, tile 128x128, 8x8/thread, K-tile 16. MODE: 0 plain, 1 relu, 2 tanh
template <int MODE>
__global__ __launch_bounds__(256) void k_gemm(const float* __restrict__ A, int lda,
                                              const float* __restrict__ B, int ldb,
                                              const float* __restrict__ bias,
                                              float* __restrict__ C, int ldc,
                                              int M, int K) {
  __shared__ __align__(16) float As[16 * 132];
  __shared__ __align__(16) float Bs[16 * 128];
  int tid = threadIdx.x;
  int tx = tid & 15, ty = tid >> 4;
  int row0 = blockIdx.y * 128;
  int col0 = blockIdx.x * 128;
  float acc[8][8];
#pragma unroll
  for (int i = 0; i < 8; ++i)
#pragma unroll
    for (int j = 0; j < 8; ++j) acc[i][j] = 0.0f;

  int arr = tid >> 2, akq = tid & 3;
  int bkr = tid >> 5, bcq = tid & 31;

  for (int k0 = 0; k0 < K; k0 += 16) {
    __syncthreads();
#pragma unroll
    for (int it = 0; it < 2; ++it) {
      int r = arr + it * 64;
      int gr = row0 + r; if (gr >= M) gr = M - 1;
      float4 v = *(const float4*)(A + (size_t)gr * lda + k0 + akq * 4);
      As[(akq * 4 + 0) * 132 + r] = v.x;
      As[(akq * 4 + 1) * 132 + r] = v.y;
      As[(akq * 4 + 2) * 132 + r] = v.z;
      As[(akq * 4 + 3) * 132 + r] = v.w;
    }
#pragma unroll
    for (int it = 0; it < 2; ++it) {
      int k = bkr + it * 8;
      *(float4*)(Bs + k * 128 + bcq * 4) = *(const float4*)(B + (size_t)(k0 + k) * ldb + col0 + bcq * 4);
    }
    __syncthreads();
#pragma unroll
    for (int kt = 0; kt < 16; ++kt) {
      float4 a0 = *(const float4*)(As + kt * 132 + ty * 8);
      float4 a1 = *(const float4*)(As + kt * 132 + ty * 8 + 4);
      float4 b0 = *(const float4*)(Bs + kt * 128 + tx * 8);
      float4 b1 = *(const float4*)(Bs + kt * 128 + tx * 8 + 4);
      float av[8] = {a0.x, a0.y, a0.z, a0.w, a1.x, a1.y, a1.z, a1.w};
      float bv[8] = {b0.x, b0.y, b0.z, b0.w, b1.x, b1.y, b1.z, b1.w};
#pragma unroll
      for (int i = 0; i < 8; ++i)
#pragma unroll
        for (int j = 0; j < 8; ++j) acc[i][j] = fmaf(av[i], bv[j], acc[i][j]);
    }
  }

  int gc = col0 + tx * 8;
  float4 bb0 = *(const float4*)(bias + gc);
  float4 bb1 = *(const float4*)(bias + gc + 4);
  float bvv[8] = {bb0.x, bb0.y, bb0.z, bb0.w, bb1.x, bb1.y, bb1.z, bb1.w};

#pragma unroll
  for (int i = 0; i < 8; ++i) {
    int gr = row0 + ty * 8 + i;
    if (gr >= M) break;
    float o[8];
#pragma unroll
    for (int j = 0; j < 8; ++j) {
      float v = acc[i][j] + bvv[j];
      if (MODE == 1) v = v > 0.0f ? v : 0.0f;
      if (MODE == 2) v = tanhf(v);
      o[j] = v;
    }
    *(float4*)(C + (size_t)gr * ldc + gc) = make_float4(o[0], o[1], o[2], o[3]);
    *(float4*)(C + (size_t)gr * ldc + gc + 4) = make_float4(o[4], o[5], o[6], o[7]);
  }
}

// per-graph per-column S1/S2 of raw z (sorted batch, segmented flush)
__global__ __launch_bounds__(256) void k_stats(const float* __restrict__ z, const int* __restrict__ batch,
                                               float* __restrict__ S1, float* __restrict__ S2, int n) {
  int tid = threadIdx.x;
  int r0 = blockIdx.x * 64;
  int rend = r0 + 64 < n ? r0 + 64 : n;
  float s1 = 0.0f, s2 = 0.0f;
  int gcur = batch[r0];
  for (int r = r0; r < rend; ++r) {
    int g = batch[r];
    if (g != gcur) {
      atomicAdd(&S1[(size_t)gcur * 256 + tid], s1);
      atomicAdd(&S2[(size_t)gcur * 256 + tid], s2);
      s1 = 0.0f; s2 = 0.0f; gcur = g;
    }
    float v = z[(size_t)r * 256 + tid];
    s1 += v;
    s2 = fmaf(v, v, s2);
  }
  atomicAdd(&S1[(size_t)gcur * 256 + tid], s1);
  atomicAdd(&S2[(size_t)gcur * 256 + tid], s2);
}

// column BN stats from per-graph S1/S2: one block per column
__global__ __launch_bounds__(256) void k_bn_fin(const float* __restrict__ S1, const float* __restrict__ S2,
                                                const float* __restrict__ gamma, const float* __restrict__ beta,
                                                float* __restrict__ abuf, float* __restrict__ bbuf, int n) {
  __shared__ float r1[256], r2[256];
  int c = blockIdx.x;
  int t = threadIdx.x;
  float s1 = 0.0f, s2 = 0.0f;
  for (int g = t; g < GG; g += 256) {
    s1 += S1[(size_t)g * 256 + c];
    s2 += S2[(size_t)g * 256 + c];
  }
  r1[t] = s1; r2[t] = s2;
  __syncthreads();
  for (int off = 128; off; off >>= 1) {
    if (t < off) { r1[t] += r1[t + off]; r2[t] += r2[t + off]; }
    __syncthreads();
  }
  if (t == 0) {
    float inv = 1.0f / (float)n;
    float mu = r1[0] * inv;
    float var = r2[0] * inv - mu * mu;
    float rstd = rsqrtf(var + 1e-5f);
    float a = gamma[c] * rstd;
    abuf[c] = a;
    bbuf[c] = beta[c] - mu * a;
  }
}

// per-graph pairnorm: gmean (into S1) and rinv (into msq) from S1/S2 — one block per graph
__global__ __launch_bounds__(256) void k_msq(float* __restrict__ S1, const float* __restrict__ S2,
                                             const float* __restrict__ abuf, const float* __restrict__ bbuf,
                                             const int* __restrict__ cnti, const float* __restrict__ cntf,
                                             float* __restrict__ msqb) {
  __shared__ float rT[256], rM[256];
  int g = blockIdx.x;
  int c = threadIdx.x;
  float a = abuf[c], b = bbuf[c];
  float s1 = S1[(size_t)g * 256 + c];
  float s2 = S2[(size_t)g * 256 + c];
  float nr = (float)cnti[g];
  float ic = 1.0f / cntf[g];
  float mean = (a * s1 + nr * b) * ic;
  float term = a * a * s2 + 2.0f * a * b * s1 + nr * b * b;
  rT[c] = term;
  rM[c] = mean * mean;
  __syncthreads();
  for (int off = 128; off; off >>= 1) {
    if (c < off) { rT[c] += rT[c + off]; rM[c] += rM[c + off]; }
    __syncthreads();
  }
  S1[(size_t)g * 256 + c] = mean;
  if (c == 0) {
    float cr = nr > 0.0f ? 1.0f : 0.0f;  // cnt*ic == 1 for nonempty, 0 for empty
    float m = rT[0] * ic - cr * rM[0];
    msqb[g] = rsqrtf(1e-5f + m);
  }
}

// h = relu((a*z + b - gmean) * rinv)
__global__ __launch_bounds__(256) void k_apply(const float* __restrict__ z, const float* __restrict__ a,
                                               const float* __restrict__ b, const int* __restrict__ batch,
                                               const float* __restrict__ gmean, const float* __restrict__ rinvb,
                                               float* __restrict__ h, int n) {
  int tid = threadIdx.x;
  int r0 = blockIdx.x * 64;
  int rend = r0 + 64 < n ? r0 + 64 : n;
  float av = a[tid], bv = b[tid];
  int gcur = -1;
  float gm = 0.0f, rinv = 0.0f;
  for (int r = r0; r < rend; ++r) {
    int g = batch[r];
    if (g != gcur) {
      gcur = g;
      gm = gmean[(size_t)g * 256 + tid];
      rinv = rinvb[g];
    }
    float v = (fmaf(av, z[(size_t)r * 256 + tid], bv) - gm) * rinv;
    h[(size_t)r * 256 + tid] = v > 0.0f ? v : 0.0f;
  }
}

// scores[r] = t1[r,:] @ att_w2 + att_b2 ; one wave per row (grid-stride)
__global__ __launch_bounds__(256) void k_att_score(const float* __restrict__ t1, const float* __restrict__ w2,
                                                   const float* __restrict__ b2, float* __restrict__ scores, int n) {
  int lane = threadIdx.x & 63;
  int wv = threadIdx.x >> 6;
  int gw = blockIdx.x * 4 + wv;
  int nw = gridDim.x * 4;
  float2 w = *(const float2*)(w2 + lane * 2);
  float bb = b2[0];
  for (int r = gw; r < n; r += nw) {
    float2 v = *(const float2*)(t1 + (size_t)r * 128 + lane * 2);
    float s = v.x * w.x + v.y * w.y;
#pragma unroll
    for (int off = 32; off; off >>= 1) s += __shfl_xor(s, off, 64);
    if (lane == 0) scores[r] = s + bb;
  }
}

// fused pooling: mean-sum, max (int bits), att-sum, wsum — segmented flush
__global__ __launch_bounds__(256) void k_pool(const float* __restrict__ h, const float* __restrict__ scores,
                                              const int* __restrict__ batch, float* __restrict__ meansum,
                                              float* __restrict__ attsum, int* __restrict__ maxbuf,
                                              float* __restrict__ wsum, int n) {
  int tid = threadIdx.x;
  int r0 = blockIdx.x * 64;
  int rend = r0 + 64 < n ? r0 + 64 : n;
  float ma = 0.0f, aa = 0.0f, mx = 0.0f, wa = 0.0f;
  int gcur = batch[r0];
  for (int r = r0; r < rend; ++r) {
    int g = batch[r];
    if (g != gcur) {
      atomicAdd(&meansum[(size_t)gcur * 256 + tid], ma);
      atomicAdd(&attsum[(size_t)gcur * 256 + tid], aa);
      atomicMax(&maxbuf[(size_t)gcur * 256 + tid], __float_as_int(mx));
      if (tid == 0) atomicAdd(&wsum[gcur], wa);
      ma = 0.0f; aa = 0.0f; mx = 0.0f; wa = 0.0f;
      gcur = g;
    }
    float w = __expf(scores[r]);
    float hv = h[(size_t)r * 256 + tid];
    ma += hv;
    aa = fmaf(hv, w, aa);
    mx = fmaxf(mx, hv);
    wa += w;
  }
  atomicAdd(&meansum[(size_t)gcur * 256 + tid], ma);
  atomicAdd(&attsum[(size_t)gcur * 256 + tid], aa);
  atomicMax(&maxbuf[(size_t)gcur * 256 + tid], __float_as_int(mx));
  if (tid == 0) atomicAdd(&wsum[gcur], wa);
}

__global__ __launch_bounds__(256) void k_out(const float* __restrict__ meansum, const int* __restrict__ maxbuf,
                                             const float* __restrict__ attsum, const float* __restrict__ wsum,
                                             const float* __restrict__ cntf, float* __restrict__ out) {
  int g = blockIdx.x;
  int c = threadIdx.x;
  out[(size_t)g * 768 + c] = meansum[(size_t)g * 256 + c] / cntf[g];
  out[(size_t)g * 768 + 256 + c] = __int_as_float(maxbuf[(size_t)g * 256 + c]);
  out[(size_t)g * 768 + 512 + c] = attsum[(size_t)g * 256 + c] / (wsum[g] + 1e-8f);
}

extern "C" void kernel_launch(void* const* d_in, const int* in_sizes, int n_in,
                              void* d_out, int out_size, void* d_ws, size_t ws_size,
                              hipStream_t stream) {
  const float* x         = (const float*)d_in[0];
  const float* edge_attr = (const float*)d_in[1];
  const float* node_w    = (const float*)d_in[2];
  const float* node_b    = (const float*)d_in[3];
  const float* edge_w    = (const float*)d_in[4];
  const float* edge_b    = (const float*)d_in[5];
  const float* conv_w    = (const float*)d_in[6];
  const float* conv_b    = (const float*)d_in[7];
  const float* mlp_w1    = (const float*)d_in[8];
  const float* mlp_b1    = (const float*)d_in[9];
  const float* mlp_w2    = (const float*)d_in[10];
  const float* mlp_b2    = (const float*)d_in[11];
  const float* eps       = (const float*)d_in[12];
  const float* bn_gamma  = (const float*)d_in[13];
  const float* bn_beta   = (const float*)d_in[14];
  const float* att_w1    = (const float*)d_in[15];
  const float* att_b1    = (const float*)d_in[16];
  const float* att_w2    = (const float*)d_in[17];
  const float* att_b2    = (const float*)d_in[18];
  const int*   eidx      = (const int*)d_in[19];
  const int*   batch     = (const int*)d_in[20];
  float* out = (float*)d_out;
  float* ws  = (float*)d_ws;

  float* bufA  = ws + O_BUFA;
  float* h     = ws + O_H;
  float* S1    = ws + O_GSUM;
  float* S2    = ws + O_GSQ;
  float* msqb  = ws + O_MSQ;
  float* atts  = ws + O_ATTS;
  int*   maxi  = (int*)(ws + O_MAXI);
  float* wsum  = ws + O_WSUM;
  float* abuf  = ws + O_ABUF;
  float* bbuf  = ws + O_BBUF;
  int*   cnti  = (int*)(ws + O_CNTI);
  float* cntf  = ws + O_CNTF;
  float* scor  = ws + O_SCOR;
  int*   curs  = (int*)(ws + O_SCOR);   // cursor aliases scores (setup-only use)
  float* weff  = ws + O_WEFF;
  float* beff  = ws + O_BEFF;
  int*   deg   = (int*)(ws + O_DEG);
  int*   strt  = (int*)(ws + O_STRT);
  int*   bsum  = (int*)(ws + O_BSUM);
  float* csr   = ws + O_CSR;
  const int* esrc = eidx;
  const int* edst = eidx + EE;

  // graph counts
  k_zero<<<64, 256, 0, stream>>>((float*)cnti, GG);
  k_count<<<(NN + 255) / 256, 256, 0, stream>>>(batch, cnti, NN);
  k_cntf<<<(GG + 255) / 256, 256, 0, stream>>>(cnti, cntf, GG);

  // fused edge weights + node embedding
  k_wfuse<<<LL, 256, 0, stream>>>(edge_w, edge_b, conv_w, conv_b, weff, beff);
  k_node_embed<<<(NN + 15) / 16, 256, 0, stream>>>(x, node_w, node_b, h, NN);

  // CSR build (by dst)
  const int nscan = (NN + 255) / 256;  // 391
  k_zero<<<256, 256, 0, stream>>>((float*)deg, NN);
  k_deg<<<(EE + 255) / 256, 256, 0, stream>>>(edst, deg, EE);
  k_scan_part<<<nscan, 256, 0, stream>>>(deg, strt, bsum, NN);
  k_scan_top<<<1, 512, 0, stream>>>(bsum, nscan);
  k_scan_add<<<nscan, 256, 0, stream>>>(strt, bsum, curs, NN);
  k_fill<<<(EE + 255) / 256, 256, 0, stream>>>(edge_attr, esrc, edst, curs, csr, EE);

  const int mtiles_n = (NN + 127) / 128;  // 782
  const int nstrips  = (NN + 63) / 64;    // 1563

  for (int i = 0; i < LL; ++i) {
    k_zero<<<1024, 256, 0, stream>>>(S1, 2 * 524288);  // S1+S2 contiguous
    // zin = (1+eps)h + CSR-gathered messages
    k_edge_csr<<<NN / 4, 256, 0, stream>>>(csr, strt, deg, weff + (size_t)i * 1536,
                                           beff + (size_t)i * 256, h, bufA, eps, i, NN);
    // t1 = relu(zin @ w1 + b1)  (t1 overwrites h)
    k_gemm<1><<<dim3(2, mtiles_n), 256, 0, stream>>>(bufA, 256, mlp_w1 + (size_t)i * 65536, 256,
                                                     mlp_b1 + (size_t)i * 256, h, 256, NN, 256);
    // z = t1 @ w2 + b2  (overwrites bufA)
    k_gemm<0><<<dim3(2, mtiles_n), 256, 0, stream>>>(h, 256, mlp_w2 + (size_t)i * 65536, 256,
                                                     mlp_b2 + (size_t)i * 256, bufA, 256, NN, 256);
    // stats: per-graph S1/S2 -> BN affine -> pairnorm gmean/rinv
    k_stats<<<nstrips, 256, 0, stream>>>(bufA, batch, S1, S2, NN);
    k_bn_fin<<<256, 256, 0, stream>>>(S1, S2, bn_gamma + (size_t)i * 256, bn_beta + (size_t)i * 256,
                                      abuf, bbuf, NN);
    k_msq<<<GG, 256, 0, stream>>>(S1, S2, abuf, bbuf, cnti, cntf, msqb);
    k_apply<<<nstrips, 256, 0, stream>>>(bufA, abuf, bbuf, batch, S1, msqb, h, NN);
  }

  // pooling
  k_zero<<<1024, 256, 0, stream>>>(S1, 524288);                 // meansum
  k_zero<<<1024, 256, 0, stream>>>(atts, 524288 + 524288 + 2048);  // attsum, maxbuf, wsum
  k_gemm<2><<<dim3(1, mtiles_n), 256, 0, stream>>>(h, 256, att_w1, 128, att_b1, bufA, 128, NN, 256);
  k_att_score<<<1024, 256, 0, stream>>>(bufA, att_w2, att_b2, scor, NN);
  k_pool<<<nstrips, 256, 0, stream>>>(h, scor, batch, S1, atts, maxi, wsum, NN);
  k_out<<<GG, 256, 0, stream>>>(S1, maxi, atts, wsum, cntf, out);
}

// Round 4
// 2285.471 us; speedup vs baseline: 5.5913x; 1.8645x over previous
//
#include <hip/hip_runtime.h>
#include <cstdint>
#include <cstddef>

// Problem constants (fixed instance)
#define NN 100000
#define EE 320000
#define GG 2048
#define LL 8

// Workspace layout (float offsets). Total ~228 MB.
#define O_Z    0ull                      // [N,256] fp32: z per layer; h (in-place) after last apply
#define O_ZB   25600000ull               // [N,256] bf16 zin; reused as att t1 fp32 [N,128] at the end
#define O_HB   38400000ull               // [N,256] bf16 h (also t1b between the MLP GEMMs)
#define O_S1   51200000ull               // [G,256]
#define O_S2   (O_S1 + 524288ull)        // [G,256]
#define O_MSQ  (O_S2 + 524288ull)        // [G] rinv
#define O_ATTS (O_MSQ + 2048ull)         // [G,256]
#define O_MAXI (O_ATTS + 524288ull)      // [G,256] int
#define O_WSUM (O_MAXI + 524288ull)      // [G]
#define O_ABUF (O_WSUM + 2048ull)        // [256]
#define O_BBUF (O_ABUF + 256ull)         // [256]
#define O_CNTI (O_BBUF + 256ull)         // [G] int
#define O_CNTF (O_CNTI + 2048ull)        // [G]
#define O_SCOR (O_CNTF + 2048ull)        // [N] scores (CSR cursor during setup)
#define O_WEFF (O_SCOR + 100000ull)      // [L,6,256]
#define O_BEFF (O_WEFF + 12288ull)       // [L,256]
#define O_DEG  (O_BEFF + 2048ull)        // [N] int
#define O_STRT (O_DEG + 100000ull)       // [N] int
#define O_BSUM (O_STRT + 100000ull)      // [512] int
#define O_CSR  (O_BSUM + 512ull)         // [E,8]
#define O_W1P  (O_CSR + 2560000ull)      // 8 x 65536 bf16 packed = 262144 floats
#define O_W2P  (O_W1P + 262144ull)
#define O_ATP  (O_W2P + 262144ull)       // 32768 bf16 = 16384 floats
// end = O_ATP + 16384 ~= 56.9M floats ~= 228 MB

typedef short s16x8 __attribute__((ext_vector_type(8)));
typedef float f32x4 __attribute__((ext_vector_type(4)));

__device__ inline float b2f(unsigned int lo16) {  // bf16 (in low 16 bits) -> f32
  union { float f; unsigned int u; } x; x.u = lo16 << 16; return x.f;
}
__device__ inline unsigned short f2b(float f) {   // f32 -> bf16 RNE
  union { float f; unsigned int u; } x; x.f = f;
  unsigned int r = x.u + 0x7FFFu + ((x.u >> 16) & 1u);
  return (unsigned short)(r >> 16);
}

__global__ __launch_bounds__(256) void k_zero(float* __restrict__ p, int n) {
  int i = blockIdx.x * 256 + threadIdx.x;
  int stride = gridDim.x * 256;
  for (; i < n; i += stride) p[i] = 0.0f;
}

__global__ __launch_bounds__(256) void k_count(const int* __restrict__ batch, int* __restrict__ cnti, int n) {
  int i = blockIdx.x * 256 + threadIdx.x;
  if (i < n) atomicAdd(&cnti[batch[i]], 1);
}

__global__ __launch_bounds__(256) void k_cntf(const int* __restrict__ cnti, float* __restrict__ cntf, int g) {
  int i = blockIdx.x * 256 + threadIdx.x;
  if (i < g) { float v = (float)cnti[i]; cntf[i] = v > 1.0f ? v : 1.0f; }
}

// ---------------- CSR build ----------------
__global__ __launch_bounds__(256) void k_deg(const int* __restrict__ edst, int* __restrict__ deg, int ne) {
  int e = blockIdx.x * 256 + threadIdx.x;
  if (e < ne) atomicAdd(&deg[edst[e]], 1);
}

__global__ __launch_bounds__(256) void k_scan_part(const int* __restrict__ deg, int* __restrict__ start,
                                                   int* __restrict__ bsum, int n) {
  __shared__ int s[256];
  int i = blockIdx.x * 256 + threadIdx.x;
  int t = threadIdx.x;
  int v = (i < n) ? deg[i] : 0;
  s[t] = v;
  __syncthreads();
  for (int off = 1; off < 256; off <<= 1) {
    int u = (t >= off) ? s[t - off] : 0;
    __syncthreads();
    s[t] += u;
    __syncthreads();
  }
  if (i < n) start[i] = s[t] - v;
  if (t == 255) bsum[blockIdx.x] = s[255];
}

__global__ __launch_bounds__(512) void k_scan_top(int* __restrict__ bsum, int nb) {
  __shared__ int s[512];
  int t = threadIdx.x;
  int v = (t < nb) ? bsum[t] : 0;
  s[t] = v;
  __syncthreads();
  for (int off = 1; off < 512; off <<= 1) {
    int u = (t >= off) ? s[t - off] : 0;
    __syncthreads();
    s[t] += u;
    __syncthreads();
  }
  if (t < nb) bsum[t] = s[t] - v;
}

__global__ __launch_bounds__(256) void k_scan_add(int* __restrict__ start, const int* __restrict__ bsum,
                                                  int* __restrict__ cursor, int n) {
  int i = blockIdx.x * 256 + threadIdx.x;
  if (i < n) {
    int v = start[i] + bsum[blockIdx.x];
    start[i] = v;
    cursor[i] = v;
  }
}

__global__ __launch_bounds__(256) void k_fill(const float* __restrict__ ea, const int* __restrict__ esrc,
                                              const int* __restrict__ edst, int* __restrict__ cursor,
                                              float* __restrict__ csr, int ne) {
  int e = blockIdx.x * 256 + threadIdx.x;
  if (e >= ne) return;
  int d = edst[e];
  int slot = atomicAdd(&cursor[d], 1);
  float* p = csr + (size_t)slot * 8;
  const float* ap = ea + (size_t)e * 6;
  p[0] = ap[0]; p[1] = ap[1]; p[2] = ap[2];
  p[3] = ap[3]; p[4] = ap[4]; p[5] = ap[5];
  ((int*)p)[6] = esrc[e];
}

// W_eff[i] = edge_w @ conv_w[i]; b_eff[i] = edge_b @ conv_w[i] + conv_b[i]
__global__ __launch_bounds__(256) void k_wfuse(const float* __restrict__ edge_w, const float* __restrict__ edge_b,
                                               const float* __restrict__ conv_w, const float* __restrict__ conv_b,
                                               float* __restrict__ wef, float* __restrict__ bef) {
  __shared__ float ew[6 * 128 + 128];
  int i = blockIdx.x;
  int c = threadIdx.x;
  for (int idx = c; idx < 896; idx += 256)
    ew[idx] = idx < 768 ? edge_w[idx] : edge_b[idx - 768];
  __syncthreads();
  float acc[7] = {0.f, 0.f, 0.f, 0.f, 0.f, 0.f, 0.f};
  const float* cw = conv_w + (size_t)i * 32768 + c;
  for (int j = 0; j < 128; ++j) {
    float w = cw[(size_t)j * 256];
#pragma unroll
    for (int k = 0; k < 6; ++k) acc[k] = fmaf(ew[k * 128 + j], w, acc[k]);
    acc[6] = fmaf(ew[768 + j], w, acc[6]);
  }
#pragma unroll
  for (int k = 0; k < 6; ++k) wef[(size_t)i * 1536 + k * 256 + c] = acc[k];
  bef[(size_t)i * 256 + c] = acc[6] + conv_b[(size_t)i * 256 + c];
}

// pack weight [K=256, ldb] fp32 -> bf16 MFMA B-fragment order: [cb][ks][ct][lane][j]
__global__ __launch_bounds__(256) void k_pack(const float* __restrict__ B, int ldb,
                                              unsigned short* __restrict__ Bp, int ncb) {
  int id = blockIdx.x * 256 + threadIdx.x;
  int total = ncb * 8 * 8 * 64;
  if (id >= total) return;
  int l = id & 63;
  int ct = (id >> 6) & 7;
  int ks = (id >> 9) & 7;
  int cb = id >> 12;
  int n = cb * 128 + ct * 16 + (l & 15);
  int k0 = ks * 32 + (l >> 4) * 8;
  unsigned short* dst = Bp + (size_t)id * 8;
#pragma unroll
  for (int j = 0; j < 8; ++j) dst[j] = f2b(B[(size_t)(k0 + j) * ldb + n]);
}

// hb = bf16(x @ node_w + node_b)   [N,48]@[48,256]
__global__ __launch_bounds__(256) void k_node_embed(const float* __restrict__ x, const float* __restrict__ w,
                                                    const float* __restrict__ b, unsigned short* __restrict__ hb,
                                                    int n) {
  __shared__ float xs[16 * 48];
  int tid = threadIdx.x;
  int row0 = blockIdx.x * 16;
  for (int idx = tid; idx < 16 * 48; idx += 256) {
    int r = idx / 48, c = idx - r * 48;
    int gr = row0 + r; if (gr >= n) gr = n - 1;
    xs[idx] = x[(size_t)gr * 48 + c];
  }
  __syncthreads();
  float acc[16];
#pragma unroll
  for (int r = 0; r < 16; ++r) acc[r] = 0.0f;
  for (int k = 0; k < 48; ++k) {
    float wv = w[k * 256 + tid];
#pragma unroll
    for (int r = 0; r < 16; ++r) acc[r] = fmaf(xs[r * 48 + k], wv, acc[r]);
  }
  float bb = b[tid];
#pragma unroll
  for (int r = 0; r < 16; ++r) {
    int gr = row0 + r;
    if (gr < n) hb[(size_t)gr * 256 + tid] = f2b(acc[r] + bb);
  }
}

// zin_b[v] = bf16( (1+eps)h[v] + sum_{e:dst=v} relu(h[src]+ea@W_eff+b_eff) ); h read as bf16
__global__ __launch_bounds__(256) void k_edge_csr(const float* __restrict__ csr,
                                                  const int* __restrict__ startv, const int* __restrict__ degv,
                                                  const float* __restrict__ wef, const float* __restrict__ bef,
                                                  const unsigned short* __restrict__ hb,
                                                  unsigned short* __restrict__ zb,
                                                  const float* __restrict__ eps, int layer, int n) {
  int lane = threadIdx.x & 63;
  int wv = threadIdx.x >> 6;
  int v = blockIdx.x * 4 + wv;
  if (v >= n) return;
  int c0 = lane * 4;
  float4 w0 = *(const float4*)(wef + 0 * 256 + c0);
  float4 w1 = *(const float4*)(wef + 1 * 256 + c0);
  float4 w2 = *(const float4*)(wef + 2 * 256 + c0);
  float4 w3 = *(const float4*)(wef + 3 * 256 + c0);
  float4 w4 = *(const float4*)(wef + 4 * 256 + c0);
  float4 w5 = *(const float4*)(wef + 5 * 256 + c0);
  float4 bf = *(const float4*)(bef + c0);
  int st = startv[v], dg = degv[v];
  float s = 1.0f + eps[layer];
  uint2 hu = *(const uint2*)(hb + (size_t)v * 256 + c0);
  float ax = s * b2f(hu.x & 0xFFFFu), ay = s * b2f(hu.x >> 16);
  float az = s * b2f(hu.y & 0xFFFFu), aw = s * b2f(hu.y >> 16);
  for (int j = st; j < st + dg; ++j) {
    const float* p = csr + (size_t)j * 8;
    float4 e03 = *(const float4*)p;
    float2 e45 = *(const float2*)(p + 4);
    int sidx = ((const int*)p)[6];
    uint2 su = *(const uint2*)(hb + (size_t)sidx * 256 + c0);
    float h0 = b2f(su.x & 0xFFFFu), h1 = b2f(su.x >> 16), h2 = b2f(su.y & 0xFFFFu), h3 = b2f(su.y >> 16);
    float mx = fmaf(e03.x, w0.x, fmaf(e03.y, w1.x, fmaf(e03.z, w2.x, fmaf(e03.w, w3.x, fmaf(e45.x, w4.x, fmaf(e45.y, w5.x, h0 + bf.x))))));
    float my = fmaf(e03.x, w0.y, fmaf(e03.y, w1.y, fmaf(e03.z, w2.y, fmaf(e03.w, w3.y, fmaf(e45.x, w4.y, fmaf(e45.y, w5.y, h1 + bf.y))))));
    float mz = fmaf(e03.x, w0.z, fmaf(e03.y, w1.z, fmaf(e03.z, w2.z, fmaf(e03.w, w3.z, fmaf(e45.x, w4.z, fmaf(e45.y, w5.z, h2 + bf.z))))));
    float mw = fmaf(e03.x, w0.w, fmaf(e03.y, w1.w, fmaf(e03.z, w2.w, fmaf(e03.w, w3.w, fmaf(e45.x, w4.w, fmaf(e45.y, w5.w, h3 + bf.w))))));
    ax += mx > 0.f ? mx : 0.f;
    ay += my > 0.f ? my : 0.f;
    az += mz > 0.f ? mz : 0.f;
    aw += mw > 0.f ? mw : 0.f;
  }
  uint2 o;
  o.x = (unsigned int)f2b(ax) | ((unsigned int)f2b(ay) << 16);
  o.y = (unsigned int)f2b(az) | ((unsigned int)f2b(aw) << 16);
  *(uint2*)(zb + (size_t)v * 256 + c0) = o;
}

// bf16 MFMA GEMM: [M,256]bf16 @ packed[256,128*gridx]bf16 -> epilogue
// block 256 (4 waves); wave w does rows [w*32,w*32+32), 128 cols; no LDS, no syncthreads.
// EPI: 0 = +bias fp32 out; 1 = relu bf16 out; 2 = tanh fp32 out
template <int EPI>
__global__ __launch_bounds__(256) void k_mm(const unsigned short* __restrict__ A,
                                            const unsigned short* __restrict__ Bp,
                                            const float* __restrict__ bias,
                                            void* __restrict__ Cout, int ldc, int M) {
  int l = threadIdx.x & 63;
  int w = threadIdx.x >> 6;
  int mloc = l & 15, q = l >> 4;
  int row0 = blockIdx.y * 128 + w * 32;
  int cb = blockIdx.x;
  int col0 = cb * 128;

  int r0 = row0 + mloc;       if (r0 > M - 1) r0 = M - 1;
  int r1 = row0 + 16 + mloc;  if (r1 > M - 1) r1 = M - 1;
  const unsigned short* ap0 = A + (size_t)r0 * 256 + q * 8;
  const unsigned short* ap1 = A + (size_t)r1 * 256 + q * 8;
  const unsigned short* bp = Bp + (size_t)cb * 32768 + (size_t)l * 8;

  f32x4 acc[2][8];
#pragma unroll
  for (int rt = 0; rt < 2; ++rt)
#pragma unroll
    for (int ct = 0; ct < 8; ++ct) acc[rt][ct] = (f32x4){0.f, 0.f, 0.f, 0.f};

#pragma unroll
  for (int ks = 0; ks < 8; ++ks) {
    s16x8 a0 = *(const s16x8*)(ap0 + ks * 32);
    s16x8 a1 = *(const s16x8*)(ap1 + ks * 32);
#pragma unroll
    for (int ct = 0; ct < 8; ++ct) {
      s16x8 b = *(const s16x8*)(bp + ks * 4096 + ct * 512);
      acc[0][ct] = __builtin_amdgcn_mfma_f32_16x16x32_bf16(a0, b, acc[0][ct], 0, 0, 0);
      acc[1][ct] = __builtin_amdgcn_mfma_f32_16x16x32_bf16(a1, b, acc[1][ct], 0, 0, 0);
    }
  }

  float bv[8];
#pragma unroll
  for (int ct = 0; ct < 8; ++ct) bv[ct] = bias[col0 + ct * 16 + mloc];

#pragma unroll
  for (int rt = 0; rt < 2; ++rt) {
#pragma unroll
    for (int r = 0; r < 4; ++r) {
      int row = row0 + rt * 16 + q * 4 + r;
      if (row >= M) continue;
#pragma unroll
      for (int ct = 0; ct < 8; ++ct) {
        float v = acc[rt][ct][r] + bv[ct];
        size_t idx = (size_t)row * ldc + col0 + ct * 16 + mloc;
        if (EPI == 1) {
          v = v > 0.f ? v : 0.f;
          ((unsigned short*)Cout)[idx] = f2b(v);
        } else if (EPI == 2) {
          ((float*)Cout)[idx] = tanhf(v);
        } else {
          ((float*)Cout)[idx] = v;
        }
      }
    }
  }
}

// per-graph per-column S1/S2 of raw z
__global__ __launch_bounds__(256) void k_stats(const float* __restrict__ z, const int* __restrict__ batch,
                                               float* __restrict__ S1, float* __restrict__ S2, int n) {
  int tid = threadIdx.x;
  int r0 = blockIdx.x * 64;
  int rend = r0 + 64 < n ? r0 + 64 : n;
  float s1 = 0.0f, s2 = 0.0f;
  int gcur = batch[r0];
  for (int r = r0; r < rend; ++r) {
    int g = batch[r];
    if (g != gcur) {
      atomicAdd(&S1[(size_t)gcur * 256 + tid], s1);
      atomicAdd(&S2[(size_t)gcur * 256 + tid], s2);
      s1 = 0.0f; s2 = 0.0f; gcur = g;
    }
    float v = z[(size_t)r * 256 + tid];
    s1 += v;
    s2 = fmaf(v, v, s2);
  }
  atomicAdd(&S1[(size_t)gcur * 256 + tid], s1);
  atomicAdd(&S2[(size_t)gcur * 256 + tid], s2);
}

__global__ __launch_bounds__(256) void k_bn_fin(const float* __restrict__ S1, const float* __restrict__ S2,
                                                const float* __restrict__ gamma, const float* __restrict__ beta,
                                                float* __restrict__ abuf, float* __restrict__ bbuf, int n) {
  __shared__ float r1[256], r2[256];
  int c = blockIdx.x;
  int t = threadIdx.x;
  float s1 = 0.0f, s2 = 0.0f;
  for (int g = t; g < GG; g += 256) {
    s1 += S1[(size_t)g * 256 + c];
    s2 += S2[(size_t)g * 256 + c];
  }
  r1[t] = s1; r2[t] = s2;
  __syncthreads();
  for (int off = 128; off; off >>= 1) {
    if (t < off) { r1[t] += r1[t + off]; r2[t] += r2[t + off]; }
    __syncthreads();
  }
  if (t == 0) {
    float inv = 1.0f / (float)n;
    float mu = r1[0] * inv;
    float var = r2[0] * inv - mu * mu;
    float rstd = rsqrtf(var + 1e-5f);
    float a = gamma[c] * rstd;
    abuf[c] = a;
    bbuf[c] = beta[c] - mu * a;
  }
}

__global__ __launch_bounds__(256) void k_msq(float* __restrict__ S1, const float* __restrict__ S2,
                                             const float* __restrict__ abuf, const float* __restrict__ bbuf,
                                             const int* __restrict__ cnti, const float* __restrict__ cntf,
                                             float* __restrict__ msqb) {
  __shared__ float rT[256], rM[256];
  int g = blockIdx.x;
  int c = threadIdx.x;
  float a = abuf[c], b = bbuf[c];
  float s1 = S1[(size_t)g * 256 + c];
  float s2 = S2[(size_t)g * 256 + c];
  float nr = (float)cnti[g];
  float ic = 1.0f / cntf[g];
  float mean = (a * s1 + nr * b) * ic;
  float term = a * a * s2 + 2.0f * a * b * s1 + nr * b * b;
  rT[c] = term;
  rM[c] = mean * mean;
  __syncthreads();
  for (int off = 128; off; off >>= 1) {
    if (c < off) { rT[c] += rT[c + off]; rM[c] += rM[c + off]; }
    __syncthreads();
  }
  S1[(size_t)g * 256 + c] = mean;
  if (c == 0) {
    float cr = nr > 0.0f ? 1.0f : 0.0f;
    float m = rT[0] * ic - cr * rM[0];
    msqb[g] = rsqrtf(1e-5f + m);
  }
}

// h = relu((a*z+b-gmean)*rinv) -> hb bf16 always; LAST also writes fp32 h in-place into z
template <int LAST>
__global__ __launch_bounds__(256) void k_apply(float* __restrict__ z, const float* __restrict__ a,
                                               const float* __restrict__ b, const int* __restrict__ batch,
                                               const float* __restrict__ gmean, const float* __restrict__ rinvb,
                                               unsigned short* __restrict__ hb, int n) {
  int tid = threadIdx.x;
  int r0 = blockIdx.x * 64;
  int rend = r0 + 64 < n ? r0 + 64 : n;
  float av = a[tid], bv = b[tid];
  int gcur = -1;
  float gm = 0.0f, rinv = 0.0f;
  for (int r = r0; r < rend; ++r) {
    int g = batch[r];
    if (g != gcur) {
      gcur = g;
      gm = gmean[(size_t)g * 256 + tid];
      rinv = rinvb[g];
    }
    float v = (fmaf(av, z[(size_t)r * 256 + tid], bv) - gm) * rinv;
    v = v > 0.0f ? v : 0.0f;
    hb[(size_t)r * 256 + tid] = f2b(v);
    if (LAST) z[(size_t)r * 256 + tid] = v;
  }
}

__global__ __launch_bounds__(256) void k_att_score(const float* __restrict__ t1, const float* __restrict__ w2,
                                                   const float* __restrict__ b2, float* __restrict__ scores, int n) {
  int lane = threadIdx.x & 63;
  int wv = threadIdx.x >> 6;
  int gw = blockIdx.x * 4 + wv;
  int nw = gridDim.x * 4;
  float2 w = *(const float2*)(w2 + lane * 2);
  float bb = b2[0];
  for (int r = gw; r < n; r += nw) {
    float2 v = *(const float2*)(t1 + (size_t)r * 128 + lane * 2);
    float s = v.x * w.x + v.y * w.y;
#pragma unroll
    for (int off = 32; off; off >>= 1) s += __shfl_xor(s, off, 64);
    if (lane == 0) scores[r] = s + bb;
  }
}

__global__ __launch_bounds__(256) void k_pool(const float* __restrict__ h, const float* __restrict__ scores,
                                              const int* __restrict__ batch, float* __restrict__ meansum,
                                              float* __restrict__ attsum, int* __restrict__ maxbuf,
                                              float* __restrict__ wsum, int n) {
  int tid = threadIdx.x;
  int r0 = blockIdx.x * 64;
  int rend = r0 + 64 < n ? r0 + 64 : n;
  float ma = 0.0f, aa = 0.0f, mx = 0.0f, wa = 0.0f;
  int gcur = batch[r0];
  for (int r = r0; r < rend; ++r) {
    int g = batch[r];
    if (g != gcur) {
      atomicAdd(&meansum[(size_t)gcur * 256 + tid], ma);
      atomicAdd(&attsum[(size_t)gcur * 256 + tid], aa);
      atomicMax(&maxbuf[(size_t)gcur * 256 + tid], __float_as_int(mx));
      if (tid == 0) atomicAdd(&wsum[gcur], wa);
      ma = 0.0f; aa = 0.0f; mx = 0.0f; wa = 0.0f;
      gcur = g;
    }
    float w = __expf(scores[r]);
    float hv = h[(size_t)r * 256 + tid];
    ma += hv;
    aa = fmaf(hv, w, aa);
    mx = fmaxf(mx, hv);
    wa += w;
  }
  atomicAdd(&meansum[(size_t)gcur * 256 + tid], ma);
  atomicAdd(&attsum[(size_t)gcur * 256 + tid], aa);
  atomicMax(&maxbuf[(size_t)gcur * 256 + tid], __float_as_int(mx));
  if (tid == 0) atomicAdd(&wsum[gcur], wa);
}

__global__ __launch_bounds__(256) void k_out(const float* __restrict__ meansum, const int* __restrict__ maxbuf,
                                             const float* __restrict__ attsum, const float* __restrict__ wsum,
                                             const float* __restrict__ cntf, float* __restrict__ out) {
  int g = blockIdx.x;
  int c = threadIdx.x;
  out[(size_t)g * 768 + c] = meansum[(size_t)g * 256 + c] / cntf[g];
  out[(size_t)g * 768 + 256 + c] = __int_as_float(maxbuf[(size_t)g * 256 + c]);
  out[(size_t)g * 768 + 512 + c] = attsum[(size_t)g * 256 + c] / (wsum[g] + 1e-8f);
}

extern "C" void kernel_launch(void* const* d_in, const int* in_sizes, int n_in,
                              void* d_out, int out_size, void* d_ws, size_t ws_size,
                              hipStream_t stream) {
  const float* x         = (const float*)d_in[0];
  const float* edge_attr = (const float*)d_in[1];
  const float* node_w    = (const float*)d_in[2];
  const float* node_b    = (const float*)d_in[3];
  const float* edge_w    = (const float*)d_in[4];
  const float* edge_b    = (const float*)d_in[5];
  const float* conv_w    = (const float*)d_in[6];
  const float* conv_b    = (const float*)d_in[7];
  const float* mlp_w1    = (const float*)d_in[8];
  const float* mlp_b1    = (const float*)d_in[9];
  const float* mlp_w2    = (const float*)d_in[10];
  const float* mlp_b2    = (const float*)d_in[11];
  const float* eps       = (const float*)d_in[12];
  const float* bn_gamma  = (const float*)d_in[13];
  const float* bn_beta   = (const float*)d_in[14];
  const float* att_w1    = (const float*)d_in[15];
  const float* att_b1    = (const float*)d_in[16];
  const float* att_w2    = (const float*)d_in[17];
  const float* att_b2    = (const float*)d_in[18];
  const int*   eidx      = (const int*)d_in[19];
  const int*   batch     = (const int*)d_in[20];
  float* out = (float*)d_out;
  float* ws  = (float*)d_ws;

  float*          zbuf = ws + O_Z;
  unsigned short* zb   = (unsigned short*)(ws + O_ZB);
  float*          t1f  = ws + O_ZB;                      // att hidden fp32 [N,128], reuses zb
  unsigned short* hb   = (unsigned short*)(ws + O_HB);   // h bf16; also t1b
  float* S1    = ws + O_S1;
  float* S2    = ws + O_S2;
  float* msqb  = ws + O_MSQ;
  float* atts  = ws + O_ATTS;
  int*   maxi  = (int*)(ws + O_MAXI);
  float* wsum  = ws + O_WSUM;
  float* abuf  = ws + O_ABUF;
  float* bbuf  = ws + O_BBUF;
  int*   cnti  = (int*)(ws + O_CNTI);
  float* cntf  = ws + O_CNTF;
  float* scor  = ws + O_SCOR;
  int*   curs  = (int*)(ws + O_SCOR);
  float* weff  = ws + O_WEFF;
  float* beff  = ws + O_BEFF;
  int*   deg   = (int*)(ws + O_DEG);
  int*   strt  = (int*)(ws + O_STRT);
  int*   bsum  = (int*)(ws + O_BSUM);
  float* csr   = ws + O_CSR;
  unsigned short* w1p = (unsigned short*)(ws + O_W1P);
  unsigned short* w2p = (unsigned short*)(ws + O_W2P);
  unsigned short* atp = (unsigned short*)(ws + O_ATP);
  const int* esrc = eidx;
  const int* edst = eidx + EE;

  // graph counts
  k_zero<<<64, 256, 0, stream>>>((float*)cnti, GG);
  k_count<<<(NN + 255) / 256, 256, 0, stream>>>(batch, cnti, NN);
  k_cntf<<<(GG + 255) / 256, 256, 0, stream>>>(cnti, cntf, GG);

  // fused edge weights + node embedding (bf16 h)
  k_wfuse<<<LL, 256, 0, stream>>>(edge_w, edge_b, conv_w, conv_b, weff, beff);
  k_node_embed<<<(NN + 15) / 16, 256, 0, stream>>>(x, node_w, node_b, hb, NN);

  // pack weights to MFMA fragment order (bf16)
  for (int i = 0; i < LL; ++i) {
    k_pack<<<32, 256, 0, stream>>>(mlp_w1 + (size_t)i * 65536, 256, w1p + (size_t)i * 65536, 2);
    k_pack<<<32, 256, 0, stream>>>(mlp_w2 + (size_t)i * 65536, 256, w2p + (size_t)i * 65536, 2);
  }
  k_pack<<<16, 256, 0, stream>>>(att_w1, 128, atp, 1);

  // CSR build (by dst)
  const int nscan = (NN + 255) / 256;  // 391
  k_zero<<<256, 256, 0, stream>>>((float*)deg, NN);
  k_deg<<<(EE + 255) / 256, 256, 0, stream>>>(edst, deg, EE);
  k_scan_part<<<nscan, 256, 0, stream>>>(deg, strt, bsum, NN);
  k_scan_top<<<1, 512, 0, stream>>>(bsum, nscan);
  k_scan_add<<<nscan, 256, 0, stream>>>(strt, bsum, curs, NN);
  k_fill<<<(EE + 255) / 256, 256, 0, stream>>>(edge_attr, esrc, edst, curs, csr, EE);

  const int mtiles = (NN + 127) / 128;  // 782
  const int nstrips = (NN + 63) / 64;   // 1563

  for (int i = 0; i < LL; ++i) {
    k_zero<<<1024, 256, 0, stream>>>(S1, 2 * 524288);
    // zin_b = bf16((1+eps)h + gathered messages)
    k_edge_csr<<<NN / 4, 256, 0, stream>>>(csr, strt, deg, weff + (size_t)i * 1536,
                                           beff + (size_t)i * 256, hb, zb, eps, i, NN);
    // t1b = bf16(relu(zin @ w1 + b1))  (overwrites hb — dead until apply rewrites it)
    k_mm<1><<<dim3(2, mtiles), 256, 0, stream>>>(zb, w1p + (size_t)i * 65536,
                                                 mlp_b1 + (size_t)i * 256, hb, 256, NN);
    // z = t1 @ w2 + b2 (fp32)
    k_mm<0><<<dim3(2, mtiles), 256, 0, stream>>>(hb, w2p + (size_t)i * 65536,
                                                 mlp_b2 + (size_t)i * 256, zbuf, 256, NN);
    // norm stats + apply
    k_stats<<<nstrips, 256, 0, stream>>>(zbuf, batch, S1, S2, NN);
    k_bn_fin<<<256, 256, 0, stream>>>(S1, S2, bn_gamma + (size_t)i * 256, bn_beta + (size_t)i * 256,
                                      abuf, bbuf, NN);
    k_msq<<<GG, 256, 0, stream>>>(S1, S2, abuf, bbuf, cnti, cntf, msqb);
    if (i == LL - 1)
      k_apply<1><<<nstrips, 256, 0, stream>>>(zbuf, abuf, bbuf, batch, S1, msqb, hb, NN);
    else
      k_apply<0><<<nstrips, 256, 0, stream>>>(zbuf, abuf, bbuf, batch, S1, msqb, hb, NN);
  }

  // pooling (zbuf now holds fp32 h)
  k_zero<<<1024, 256, 0, stream>>>(S1, 524288);
  k_zero<<<1024, 256, 0, stream>>>(atts, 524288 + 524288 + 2048);
  k_mm<2><<<dim3(1, mtiles), 256, 0, stream>>>(hb, atp, att_b1, t1f, 128, NN);
  k_att_score<<<1024, 256, 0, stream>>>(t1f, att_w2, att_b2, scor, NN);
  k_pool<<<nstrips, 256, 0, stream>>>(zbuf, scor, batch, S1, atts, maxi, wsum, NN);
  k_out<<<GG, 256, 0, stream>>>(S1, maxi, atts, wsum, cntf, out);
}

// Round 5
// 2238.432 us; speedup vs baseline: 5.7088x; 1.0210x over previous
//
#include <hip/hip_runtime.h>
#include <cstdint>
#include <cstddef>

// Problem constants (fixed instance)
#define NN 100000
#define EE 320000
#define GG 2048
#define LL 8

// Workspace layout (float offsets).
#define O_Z    0ull                      // [N,256] fp32 z; h fp32 (in-place) after last apply
#define O_ZB   25600000ull               // [N,256] bf16 zin
#define O_HB   38400000ull               // [N,256] bf16 h
#define O_S1   51200000ull               // [G,256] S1 -> gmean
#define O_S2   (O_S1 + 524288ull)        // [G,256] S2
#define O_MSQ  (O_S2 + 524288ull)        // [G] rinv
#define O_ABUF (O_MSQ + 2048ull)         // [256]
#define O_BBUF (O_ABUF + 256ull)         // [256]
#define O_CNTI (O_BBUF + 256ull)         // [G] int
#define O_CNTF (O_CNTI + 2048ull)        // [G]
#define O_SCOR (O_CNTF + 2048ull)        // [N] scores (CSR cursor during setup)
#define O_WEFF (O_SCOR + 100000ull)      // [L,6,256]
#define O_BEFF (O_WEFF + 12288ull)       // [L,256]
#define O_DEG  (O_BEFF + 2048ull)        // [N] int
#define O_STRT (O_DEG + 100000ull)       // [N] int
#define O_BSUM (O_STRT + 100000ull)      // [512] int
#define O_CSR  (O_BSUM + 512ull)         // [E,8]
#define O_W1P  (O_CSR + 2560000ull)      // 8 x 65536 bf16 = 262144 floats
#define O_W2P  (O_W1P + 262144ull)
#define O_ATP  (O_W2P + 262144ull)       // 16384 bf16*... 32768 shorts = 16384 floats
#define O_GST  (O_ATP + 16384ull)        // [G] int gstart

typedef short s16x8 __attribute__((ext_vector_type(8)));
typedef float f32x4 __attribute__((ext_vector_type(4)));

__device__ inline float b2f(unsigned int lo16) {
  union { float f; unsigned int u; } x; x.u = lo16 << 16; return x.f;
}
__device__ inline unsigned short f2b(float f) {
  union { float f; unsigned int u; } x; x.f = f;
  unsigned int r = x.u + 0x7FFFu + ((x.u >> 16) & 1u);
  return (unsigned short)(r >> 16);
}

__global__ __launch_bounds__(256) void k_zero(float* __restrict__ p, int n) {
  int i = blockIdx.x * 256 + threadIdx.x;
  int stride = gridDim.x * 256;
  for (; i < n; i += stride) p[i] = 0.0f;
}

__global__ __launch_bounds__(256) void k_count(const int* __restrict__ batch, int* __restrict__ cnti, int n) {
  int i = blockIdx.x * 256 + threadIdx.x;
  if (i < n) atomicAdd(&cnti[batch[i]], 1);
}

// single-block scan over G=2048 counts -> gstart (exclusive), cntf (clamped)
__global__ __launch_bounds__(256) void k_gscan(const int* __restrict__ cnti, int* __restrict__ gstart,
                                               float* __restrict__ cntf) {
  __shared__ int part[256];
  int t = threadIdx.x;
  int base = t * 8;
  int loc[8];
  int s = 0;
#pragma unroll
  for (int i = 0; i < 8; ++i) { loc[i] = s; s += cnti[base + i]; }
  part[t] = s;
  __syncthreads();
  for (int off = 1; off < 256; off <<= 1) {
    int u = (t >= off) ? part[t - off] : 0;
    __syncthreads();
    part[t] += u;
    __syncthreads();
  }
  int p = (t > 0) ? part[t - 1] : 0;
#pragma unroll
  for (int i = 0; i < 8; ++i) {
    gstart[base + i] = p + loc[i];
    float v = (float)cnti[base + i];
    cntf[base + i] = v > 1.0f ? v : 1.0f;
  }
}

// ---------------- CSR build ----------------
__global__ __launch_bounds__(256) void k_deg(const int* __restrict__ edst, int* __restrict__ deg, int ne) {
  int e = blockIdx.x * 256 + threadIdx.x;
  if (e < ne) atomicAdd(&deg[edst[e]], 1);
}

__global__ __launch_bounds__(256) void k_scan_part(const int* __restrict__ deg, int* __restrict__ start,
                                                   int* __restrict__ bsum, int n) {
  __shared__ int s[256];
  int i = blockIdx.x * 256 + threadIdx.x;
  int t = threadIdx.x;
  int v = (i < n) ? deg[i] : 0;
  s[t] = v;
  __syncthreads();
  for (int off = 1; off < 256; off <<= 1) {
    int u = (t >= off) ? s[t - off] : 0;
    __syncthreads();
    s[t] += u;
    __syncthreads();
  }
  if (i < n) start[i] = s[t] - v;
  if (t == 255) bsum[blockIdx.x] = s[255];
}

__global__ __launch_bounds__(512) void k_scan_top(int* __restrict__ bsum, int nb) {
  __shared__ int s[512];
  int t = threadIdx.x;
  int v = (t < nb) ? bsum[t] : 0;
  s[t] = v;
  __syncthreads();
  for (int off = 1; off < 512; off <<= 1) {
    int u = (t >= off) ? s[t - off] : 0;
    __syncthreads();
    s[t] += u;
    __syncthreads();
  }
  if (t < nb) bsum[t] = s[t] - v;
}

__global__ __launch_bounds__(256) void k_scan_add(int* __restrict__ start, const int* __restrict__ bsum,
                                                  int* __restrict__ cursor, int n) {
  int i = blockIdx.x * 256 + threadIdx.x;
  if (i < n) {
    int v = start[i] + bsum[blockIdx.x];
    start[i] = v;
    cursor[i] = v;
  }
}

__global__ __launch_bounds__(256) void k_fill(const float* __restrict__ ea, const int* __restrict__ esrc,
                                              const int* __restrict__ edst, int* __restrict__ cursor,
                                              float* __restrict__ csr, int ne) {
  int e = blockIdx.x * 256 + threadIdx.x;
  if (e >= ne) return;
  int d = edst[e];
  int slot = atomicAdd(&cursor[d], 1);
  float* p = csr + (size_t)slot * 8;
  const float* ap = ea + (size_t)e * 6;
  p[0] = ap[0]; p[1] = ap[1]; p[2] = ap[2];
  p[3] = ap[3]; p[4] = ap[4]; p[5] = ap[5];
  ((int*)p)[6] = esrc[e];
}

// W_eff[i] = edge_w @ conv_w[i]; b_eff[i] = edge_b @ conv_w[i] + conv_b[i]
__global__ __launch_bounds__(256) void k_wfuse(const float* __restrict__ edge_w, const float* __restrict__ edge_b,
                                               const float* __restrict__ conv_w, const float* __restrict__ conv_b,
                                               float* __restrict__ wef, float* __restrict__ bef) {
  __shared__ float ew[6 * 128 + 128];
  int i = blockIdx.x;
  int c = threadIdx.x;
  for (int idx = c; idx < 896; idx += 256)
    ew[idx] = idx < 768 ? edge_w[idx] : edge_b[idx - 768];
  __syncthreads();
  float acc[7] = {0.f, 0.f, 0.f, 0.f, 0.f, 0.f, 0.f};
  const float* cw = conv_w + (size_t)i * 32768 + c;
  for (int j = 0; j < 128; ++j) {
    float w = cw[(size_t)j * 256];
#pragma unroll
    for (int k = 0; k < 6; ++k) acc[k] = fmaf(ew[k * 128 + j], w, acc[k]);
    acc[6] = fmaf(ew[768 + j], w, acc[6]);
  }
#pragma unroll
  for (int k = 0; k < 6; ++k) wef[(size_t)i * 1536 + k * 256 + c] = acc[k];
  bef[(size_t)i * 256 + c] = acc[6] + conv_b[(size_t)i * 256 + c];
}

// pack weight [K=256, ldb] fp32 -> bf16 MFMA B-fragment order: [cb][ks][ct][lane][j]
__global__ __launch_bounds__(256) void k_pack(const float* __restrict__ B, int ldb,
                                              unsigned short* __restrict__ Bp, int ncb) {
  int id = blockIdx.x * 256 + threadIdx.x;
  int total = ncb * 8 * 8 * 64;
  if (id >= total) return;
  int l = id & 63;
  int ct = (id >> 6) & 7;
  int ks = (id >> 9) & 7;
  int cb = id >> 12;
  int n = cb * 128 + ct * 16 + (l & 15);
  int k0 = ks * 32 + (l >> 4) * 8;
  unsigned short* dst = Bp + (size_t)id * 8;
#pragma unroll
  for (int j = 0; j < 8; ++j) dst[j] = f2b(B[(size_t)(k0 + j) * ldb + n]);
}

// hb = bf16(x @ node_w + node_b)
__global__ __launch_bounds__(256) void k_node_embed(const float* __restrict__ x, const float* __restrict__ w,
                                                    const float* __restrict__ b, unsigned short* __restrict__ hb,
                                                    int n) {
  __shared__ float xs[16 * 48];
  int tid = threadIdx.x;
  int row0 = blockIdx.x * 16;
  for (int idx = tid; idx < 16 * 48; idx += 256) {
    int r = idx / 48, c = idx - r * 48;
    int gr = row0 + r; if (gr >= n) gr = n - 1;
    xs[idx] = x[(size_t)gr * 48 + c];
  }
  __syncthreads();
  float acc[16];
#pragma unroll
  for (int r = 0; r < 16; ++r) acc[r] = 0.0f;
  for (int k = 0; k < 48; ++k) {
    float wv = w[k * 256 + tid];
#pragma unroll
    for (int r = 0; r < 16; ++r) acc[r] = fmaf(xs[r * 48 + k], wv, acc[r]);
  }
  float bb = b[tid];
#pragma unroll
  for (int r = 0; r < 16; ++r) {
    int gr = row0 + r;
    if (gr < n) hb[(size_t)gr * 256 + tid] = f2b(acc[r] + bb);
  }
}

// zin_b[v] = bf16((1+eps)h[v] + sum relu(h[src]+ea@W_eff+b_eff))
// 2 waves per node (128 cols each), 2 nodes per 256-thread block; unroll-2 edges.
__global__ __launch_bounds__(256) void k_edge_csr(const float* __restrict__ csr,
                                                  const int* __restrict__ startv, const int* __restrict__ degv,
                                                  const float* __restrict__ wef, const float* __restrict__ bef,
                                                  const unsigned short* __restrict__ hb,
                                                  unsigned short* __restrict__ zb,
                                                  const float* __restrict__ eps, int layer, int n) {
  int lane = threadIdx.x & 63;
  int w = threadIdx.x >> 6;
  int v = blockIdx.x * 2 + (w >> 1);
  if (v >= n) return;
  int c0 = (w & 1) * 128 + lane * 2;
  float2 w0 = *(const float2*)(wef + 0 * 256 + c0);
  float2 w1 = *(const float2*)(wef + 1 * 256 + c0);
  float2 w2 = *(const float2*)(wef + 2 * 256 + c0);
  float2 w3 = *(const float2*)(wef + 3 * 256 + c0);
  float2 w4 = *(const float2*)(wef + 4 * 256 + c0);
  float2 w5 = *(const float2*)(wef + 5 * 256 + c0);
  float2 bf = *(const float2*)(bef + c0);
  int st = startv[v], en = st + degv[v];
  float s = 1.0f + eps[layer];
  unsigned int hu = *(const unsigned int*)(hb + (size_t)v * 256 + c0);
  float a0 = s * b2f(hu & 0xFFFFu);
  float a1 = s * b2f(hu >> 16);
  int j = st;
  for (; j + 2 <= en; j += 2) {
    const float* p0 = csr + (size_t)j * 8;
    const float* p1 = p0 + 8;
    float4 ex0 = *(const float4*)p0; float2 ey0 = *(const float2*)(p0 + 4); int s0 = ((const int*)p0)[6];
    float4 ex1 = *(const float4*)p1; float2 ey1 = *(const float2*)(p1 + 4); int s1 = ((const int*)p1)[6];
    unsigned int g0 = *(const unsigned int*)(hb + (size_t)s0 * 256 + c0);
    unsigned int g1 = *(const unsigned int*)(hb + (size_t)s1 * 256 + c0);
    float m00 = fmaf(ex0.x, w0.x, fmaf(ex0.y, w1.x, fmaf(ex0.z, w2.x, fmaf(ex0.w, w3.x, fmaf(ey0.x, w4.x, fmaf(ey0.y, w5.x, b2f(g0 & 0xFFFFu) + bf.x))))));
    float m01 = fmaf(ex0.x, w0.y, fmaf(ex0.y, w1.y, fmaf(ex0.z, w2.y, fmaf(ex0.w, w3.y, fmaf(ey0.x, w4.y, fmaf(ey0.y, w5.y, b2f(g0 >> 16) + bf.y))))));
    float m10 = fmaf(ex1.x, w0.x, fmaf(ex1.y, w1.x, fmaf(ex1.z, w2.x, fmaf(ex1.w, w3.x, fmaf(ey1.x, w4.x, fmaf(ey1.y, w5.x, b2f(g1 & 0xFFFFu) + bf.x))))));
    float m11 = fmaf(ex1.x, w0.y, fmaf(ex1.y, w1.y, fmaf(ex1.z, w2.y, fmaf(ex1.w, w3.y, fmaf(ey1.x, w4.y, fmaf(ey1.y, w5.y, b2f(g1 >> 16) + bf.y))))));
    a0 += (m00 > 0.f ? m00 : 0.f) + (m10 > 0.f ? m10 : 0.f);
    a1 += (m01 > 0.f ? m01 : 0.f) + (m11 > 0.f ? m11 : 0.f);
  }
  if (j < en) {
    const float* p0 = csr + (size_t)j * 8;
    float4 ex0 = *(const float4*)p0; float2 ey0 = *(const float2*)(p0 + 4); int s0 = ((const int*)p0)[6];
    unsigned int g0 = *(const unsigned int*)(hb + (size_t)s0 * 256 + c0);
    float m00 = fmaf(ex0.x, w0.x, fmaf(ex0.y, w1.x, fmaf(ex0.z, w2.x, fmaf(ex0.w, w3.x, fmaf(ey0.x, w4.x, fmaf(ey0.y, w5.x, b2f(g0 & 0xFFFFu) + bf.x))))));
    float m01 = fmaf(ex0.x, w0.y, fmaf(ex0.y, w1.y, fmaf(ex0.z, w2.y, fmaf(ex0.w, w3.y, fmaf(ey0.x, w4.y, fmaf(ey0.y, w5.y, b2f(g0 >> 16) + bf.y))))));
    a0 += m00 > 0.f ? m00 : 0.f;
    a1 += m01 > 0.f ? m01 : 0.f;
  }
  *(unsigned int*)(zb + (size_t)v * 256 + c0) =
      (unsigned int)f2b(a0) | ((unsigned int)f2b(a1) << 16);
}

// Fused MLP: z = relu(zin@W1+b1)@W2+b2 for a 128-row tile.
// 4 waves: wave w -> rows (w&1)*64..+64, cols (w>>1)*128..+128. t1 in LDS (bf16, XOR-swizzled 16B chunks).
__global__ __launch_bounds__(256, 2) void k_mlp(const unsigned short* __restrict__ A,
                                                const unsigned short* __restrict__ W1p,
                                                const float* __restrict__ b1,
                                                const unsigned short* __restrict__ W2p,
                                                const float* __restrict__ b2,
                                                float* __restrict__ Z, int M) {
  __shared__ unsigned short t1s[128 * 256];  // 64 KB
  int l = threadIdx.x & 63;
  int w = threadIdx.x >> 6;
  int mloc = l & 15, q = l >> 4;
  int rowh = (w & 1) * 64;
  int colh = (w >> 1) * 128;
  int row0 = blockIdx.x * 128;

  const unsigned short* ap[4];
#pragma unroll
  for (int rt = 0; rt < 4; ++rt) {
    int r = row0 + rowh + rt * 16 + mloc;
    if (r > M - 1) r = M - 1;
    ap[rt] = A + (size_t)r * 256 + q * 8;
  }
  f32x4 acc[4][8];
#pragma unroll
  for (int rt = 0; rt < 4; ++rt)
#pragma unroll
    for (int ct = 0; ct < 8; ++ct) acc[rt][ct] = (f32x4){0.f, 0.f, 0.f, 0.f};

  const unsigned short* w1base = W1p + ((size_t)(colh >> 7)) * 32768 + (size_t)l * 8;
#pragma unroll
  for (int ks = 0; ks < 8; ++ks) {
    s16x8 a[4];
#pragma unroll
    for (int rt = 0; rt < 4; ++rt) a[rt] = *(const s16x8*)(ap[rt] + ks * 32);
#pragma unroll
    for (int ct = 0; ct < 8; ++ct) {
      s16x8 b = *(const s16x8*)(w1base + ks * 4096 + ct * 512);
#pragma unroll
      for (int rt = 0; rt < 4; ++rt)
        acc[rt][ct] = __builtin_amdgcn_mfma_f32_16x16x32_bf16(a[rt], b, acc[rt][ct], 0, 0, 0);
    }
  }
  // epilogue 1: bias+relu -> LDS bf16 (swizzled)
#pragma unroll
  for (int ct = 0; ct < 8; ++ct) {
    int col = colh + ct * 16 + mloc;
    float bv = b1[col];
    int cc = col >> 3, pos = col & 7;
#pragma unroll
    for (int rt = 0; rt < 4; ++rt)
#pragma unroll
      for (int r = 0; r < 4; ++r) {
        int row = rowh + rt * 16 + q * 4 + r;
        float v = acc[rt][ct][r] + bv;
        v = v > 0.f ? v : 0.f;
        t1s[row * 256 + ((cc ^ (row & 31)) << 3) + pos] = f2b(v);
      }
  }
  __syncthreads();
  // GEMM2: A from LDS
#pragma unroll
  for (int rt = 0; rt < 4; ++rt)
#pragma unroll
    for (int ct = 0; ct < 8; ++ct) acc[rt][ct] = (f32x4){0.f, 0.f, 0.f, 0.f};
  const unsigned short* w2base = W2p + ((size_t)(colh >> 7)) * 32768 + (size_t)l * 8;
#pragma unroll
  for (int ks = 0; ks < 8; ++ks) {
    s16x8 a[4];
#pragma unroll
    for (int rt = 0; rt < 4; ++rt) {
      int row = rowh + rt * 16 + mloc;
      int cc = (q + ks * 4) ^ (row & 31);
      a[rt] = *(const s16x8*)(t1s + row * 256 + (cc << 3));
    }
#pragma unroll
    for (int ct = 0; ct < 8; ++ct) {
      s16x8 b = *(const s16x8*)(w2base + ks * 4096 + ct * 512);
#pragma unroll
      for (int rt = 0; rt < 4; ++rt)
        acc[rt][ct] = __builtin_amdgcn_mfma_f32_16x16x32_bf16(a[rt], b, acc[rt][ct], 0, 0, 0);
    }
  }
  // epilogue 2: bias -> fp32 Z
#pragma unroll
  for (int ct = 0; ct < 8; ++ct) {
    int col = colh + ct * 16 + mloc;
    float bv = b2[col];
#pragma unroll
    for (int rt = 0; rt < 4; ++rt)
#pragma unroll
      for (int r = 0; r < 4; ++r) {
        int grow = row0 + rowh + rt * 16 + q * 4 + r;
        if (grow < M) Z[(size_t)grow * 256 + col] = acc[rt][ct][r] + bv;
      }
  }
}

// attention: t1 = tanh(h@W1+b1); score[row] = t1[row,:]@w2 + b2 — fused, no t1 materialization
__global__ __launch_bounds__(256) void k_att(const unsigned short* __restrict__ A,
                                             const unsigned short* __restrict__ Bp,
                                             const float* __restrict__ b1,
                                             const float* __restrict__ w2,
                                             const float* __restrict__ b2,
                                             float* __restrict__ scores, int M) {
  int l = threadIdx.x & 63;
  int w = threadIdx.x >> 6;
  int mloc = l & 15, q = l >> 4;
  int row0 = blockIdx.x * 128 + w * 32;

  int r0 = row0 + mloc;      if (r0 > M - 1) r0 = M - 1;
  int r1 = row0 + 16 + mloc; if (r1 > M - 1) r1 = M - 1;
  const unsigned short* ap0 = A + (size_t)r0 * 256 + q * 8;
  const unsigned short* ap1 = A + (size_t)r1 * 256 + q * 8;
  const unsigned short* bp = Bp + (size_t)l * 8;

  f32x4 acc[2][8];
#pragma unroll
  for (int rt = 0; rt < 2; ++rt)
#pragma unroll
    for (int ct = 0; ct < 8; ++ct) acc[rt][ct] = (f32x4){0.f, 0.f, 0.f, 0.f};
#pragma unroll
  for (int ks = 0; ks < 8; ++ks) {
    s16x8 a0 = *(const s16x8*)(ap0 + ks * 32);
    s16x8 a1 = *(const s16x8*)(ap1 + ks * 32);
#pragma unroll
    for (int ct = 0; ct < 8; ++ct) {
      s16x8 b = *(const s16x8*)(bp + ks * 4096 + ct * 512);
      acc[0][ct] = __builtin_amdgcn_mfma_f32_16x16x32_bf16(a0, b, acc[0][ct], 0, 0, 0);
      acc[1][ct] = __builtin_amdgcn_mfma_f32_16x16x32_bf16(a1, b, acc[1][ct], 0, 0, 0);
    }
  }
  float bv[8], wv[8];
#pragma unroll
  for (int ct = 0; ct < 8; ++ct) {
    bv[ct] = b1[ct * 16 + mloc];
    wv[ct] = w2[ct * 16 + mloc];
  }
  float b2v = b2[0];
#pragma unroll
  for (int rt = 0; rt < 2; ++rt)
#pragma unroll
    for (int r = 0; r < 4; ++r) {
      float p = 0.0f;
#pragma unroll
      for (int ct = 0; ct < 8; ++ct) p = fmaf(tanhf(acc[rt][ct][r] + bv[ct]), wv[ct], p);
      p += __shfl_xor(p, 1, 64);
      p += __shfl_xor(p, 2, 64);
      p += __shfl_xor(p, 4, 64);
      p += __shfl_xor(p, 8, 64);
      int row = row0 + rt * 16 + q * 4 + r;
      if (mloc == 0 && row < M) scores[row] = p + b2v;
    }
}

// per-graph per-column S1/S2 of z — one block per graph, no atomics
__global__ __launch_bounds__(256) void k_stats(const float* __restrict__ z, const int* __restrict__ gstart,
                                               const int* __restrict__ cnti,
                                               float* __restrict__ S1, float* __restrict__ S2) {
  int g = blockIdx.x, c = threadIdx.x;
  int r0 = gstart[g], r1 = r0 + cnti[g];
  float s1 = 0.0f, s2 = 0.0f;
  for (int r = r0; r < r1; ++r) {
    float v = z[(size_t)r * 256 + c];
    s1 += v;
    s2 = fmaf(v, v, s2);
  }
  S1[(size_t)g * 256 + c] = s1;
  S2[(size_t)g * 256 + c] = s2;
}

// column BN stats from per-graph S1/S2: one block per column
__global__ __launch_bounds__(256) void k_bn_fin(const float* __restrict__ S1, const float* __restrict__ S2,
                                                const float* __restrict__ gamma, const float* __restrict__ beta,
                                                float* __restrict__ abuf, float* __restrict__ bbuf, int n) {
  __shared__ float r1[256], r2[256];
  int c = blockIdx.x;
  int t = threadIdx.x;
  float s1 = 0.0f, s2 = 0.0f;
  for (int g = t; g < GG; g += 256) {
    s1 += S1[(size_t)g * 256 + c];
    s2 += S2[(size_t)g * 256 + c];
  }
  r1[t] = s1; r2[t] = s2;
  __syncthreads();
  for (int off = 128; off; off >>= 1) {
    if (t < off) { r1[t] += r1[t + off]; r2[t] += r2[t + off]; }
    __syncthreads();
  }
  if (t == 0) {
    float inv = 1.0f / (float)n;
    float mu = r1[0] * inv;
    float var = r2[0] * inv - mu * mu;
    float rstd = rsqrtf(var + 1e-5f);
    float a = gamma[c] * rstd;
    abuf[c] = a;
    bbuf[c] = beta[c] - mu * a;
  }
}

// per-graph pairnorm: gmean (into S1) and rinv (into msqb)
__global__ __launch_bounds__(256) void k_msq(float* __restrict__ S1, const float* __restrict__ S2,
                                             const float* __restrict__ abuf, const float* __restrict__ bbuf,
                                             const int* __restrict__ cnti, const float* __restrict__ cntf,
                                             float* __restrict__ msqb) {
  __shared__ float rT[256], rM[256];
  int g = blockIdx.x;
  int c = threadIdx.x;
  float a = abuf[c], b = bbuf[c];
  float s1 = S1[(size_t)g * 256 + c];
  float s2 = S2[(size_t)g * 256 + c];
  float nr = (float)cnti[g];
  float ic = 1.0f / cntf[g];
  float mean = (a * s1 + nr * b) * ic;
  float term = a * a * s2 + 2.0f * a * b * s1 + nr * b * b;
  rT[c] = term;
  rM[c] = mean * mean;
  __syncthreads();
  for (int off = 128; off; off >>= 1) {
    if (c < off) { rT[c] += rT[c + off]; rM[c] += rM[c + off]; }
    __syncthreads();
  }
  S1[(size_t)g * 256 + c] = mean;
  if (c == 0) {
    float cr = nr > 0.0f ? 1.0f : 0.0f;
    float m = rT[0] * ic - cr * rM[0];
    msqb[g] = rsqrtf(1e-5f + m);
  }
}

// per-graph apply: h = relu((a*z+b-gmean)*rinv) -> hb bf16; LAST also fp32 into z
template <int LAST>
__global__ __launch_bounds__(256) void k_apply(float* __restrict__ z, const float* __restrict__ a,
                                               const float* __restrict__ b, const int* __restrict__ gstart,
                                               const int* __restrict__ cnti,
                                               const float* __restrict__ gmean, const float* __restrict__ rinvb,
                                               unsigned short* __restrict__ hb) {
  int g = blockIdx.x, c = threadIdx.x;
  int r0 = gstart[g], r1 = r0 + cnti[g];
  float av = a[c], bv = b[c];
  float gm = gmean[(size_t)g * 256 + c];
  float rinv = rinvb[g];
  for (int r = r0; r < r1; ++r) {
    float v = (fmaf(av, z[(size_t)r * 256 + c], bv) - gm) * rinv;
    v = v > 0.0f ? v : 0.0f;
    hb[(size_t)r * 256 + c] = f2b(v);
    if (LAST) z[(size_t)r * 256 + c] = v;
  }
}

// per-graph fused pooling + output — one block per graph, no atomics
__global__ __launch_bounds__(256) void k_poolout(const float* __restrict__ h, const float* __restrict__ scores,
                                                 const int* __restrict__ gstart, const int* __restrict__ cnti,
                                                 const float* __restrict__ cntf, float* __restrict__ out) {
  int g = blockIdx.x, c = threadIdx.x;
  int r0 = gstart[g], r1 = r0 + cnti[g];
  float ma = 0.0f, aa = 0.0f, mx = 0.0f, wa = 0.0f;
  for (int r = r0; r < r1; ++r) {
    float wgt = __expf(scores[r]);
    float hv = h[(size_t)r * 256 + c];
    ma += hv;
    aa = fmaf(hv, wgt, aa);
    mx = fmaxf(mx, hv);
    wa += wgt;
  }
  out[(size_t)g * 768 + c] = ma / cntf[g];
  out[(size_t)g * 768 + 256 + c] = mx;
  out[(size_t)g * 768 + 512 + c] = aa / (wa + 1e-8f);
}

extern "C" void kernel_launch(void* const* d_in, const int* in_sizes, int n_in,
                              void* d_out, int out_size, void* d_ws, size_t ws_size,
                              hipStream_t stream) {
  const float* x         = (const float*)d_in[0];
  const float* edge_attr = (const float*)d_in[1];
  const float* node_w    = (const float*)d_in[2];
  const float* node_b    = (const float*)d_in[3];
  const float* edge_w    = (const float*)d_in[4];
  const float* edge_b    = (const float*)d_in[5];
  const float* conv_w    = (const float*)d_in[6];
  const float* conv_b    = (const float*)d_in[7];
  const float* mlp_w1    = (const float*)d_in[8];
  const float* mlp_b1    = (const float*)d_in[9];
  const float* mlp_w2    = (const float*)d_in[10];
  const float* mlp_b2    = (const float*)d_in[11];
  const float* eps       = (const float*)d_in[12];
  const float* bn_gamma  = (const float*)d_in[13];
  const float* bn_beta   = (const float*)d_in[14];
  const float* att_w1    = (const float*)d_in[15];
  const float* att_b1    = (const float*)d_in[16];
  const float* att_w2    = (const float*)d_in[17];
  const float* att_b2    = (const float*)d_in[18];
  const int*   eidx      = (const int*)d_in[19];
  const int*   batch     = (const int*)d_in[20];
  float* out = (float*)d_out;
  float* ws  = (float*)d_ws;

  float*          zbuf = ws + O_Z;
  unsigned short* zb   = (unsigned short*)(ws + O_ZB);
  unsigned short* hb   = (unsigned short*)(ws + O_HB);
  float* S1    = ws + O_S1;
  float* S2    = ws + O_S2;
  float* msqb  = ws + O_MSQ;
  float* abuf  = ws + O_ABUF;
  float* bbuf  = ws + O_BBUF;
  int*   cnti  = (int*)(ws + O_CNTI);
  float* cntf  = ws + O_CNTF;
  float* scor  = ws + O_SCOR;
  int*   curs  = (int*)(ws + O_SCOR);
  float* weff  = ws + O_WEFF;
  float* beff  = ws + O_BEFF;
  int*   deg   = (int*)(ws + O_DEG);
  int*   strt  = (int*)(ws + O_STRT);
  int*   bsum  = (int*)(ws + O_BSUM);
  float* csr   = ws + O_CSR;
  unsigned short* w1p = (unsigned short*)(ws + O_W1P);
  unsigned short* w2p = (unsigned short*)(ws + O_W2P);
  unsigned short* atp = (unsigned short*)(ws + O_ATP);
  int*   gst   = (int*)(ws + O_GST);
  const int* esrc = eidx;
  const int* edst = eidx + EE;

  // graph counts + offsets
  k_zero<<<8, 256, 0, stream>>>((float*)cnti, GG);
  k_count<<<(NN + 255) / 256, 256, 0, stream>>>(batch, cnti, NN);
  k_gscan<<<1, 256, 0, stream>>>(cnti, gst, cntf);

  // fused edge weights + node embedding (bf16 h)
  k_wfuse<<<LL, 256, 0, stream>>>(edge_w, edge_b, conv_w, conv_b, weff, beff);
  k_node_embed<<<(NN + 15) / 16, 256, 0, stream>>>(x, node_w, node_b, hb, NN);

  // pack weights to MFMA fragment order (bf16)
  for (int i = 0; i < LL; ++i) {
    k_pack<<<32, 256, 0, stream>>>(mlp_w1 + (size_t)i * 65536, 256, w1p + (size_t)i * 65536, 2);
    k_pack<<<32, 256, 0, stream>>>(mlp_w2 + (size_t)i * 65536, 256, w2p + (size_t)i * 65536, 2);
  }
  k_pack<<<16, 256, 0, stream>>>(att_w1, 128, atp, 1);

  // CSR build (by dst)
  const int nscan = (NN + 255) / 256;  // 391
  k_zero<<<256, 256, 0, stream>>>((float*)deg, NN);
  k_deg<<<(EE + 255) / 256, 256, 0, stream>>>(edst, deg, EE);
  k_scan_part<<<nscan, 256, 0, stream>>>(deg, strt, bsum, NN);
  k_scan_top<<<1, 512, 0, stream>>>(bsum, nscan);
  k_scan_add<<<nscan, 256, 0, stream>>>(strt, bsum, curs, NN);
  k_fill<<<(EE + 255) / 256, 256, 0, stream>>>(edge_attr, esrc, edst, curs, csr, EE);

  const int mtiles = (NN + 127) / 128;  // 782

  for (int i = 0; i < LL; ++i) {
    k_edge_csr<<<(NN + 1) / 2, 256, 0, stream>>>(csr, strt, deg, weff + (size_t)i * 1536,
                                                 beff + (size_t)i * 256, hb, zb, eps, i, NN);
    k_mlp<<<mtiles, 256, 0, stream>>>(zb, w1p + (size_t)i * 65536, mlp_b1 + (size_t)i * 256,
                                      w2p + (size_t)i * 65536, mlp_b2 + (size_t)i * 256, zbuf, NN);
    k_stats<<<GG, 256, 0, stream>>>(zbuf, gst, cnti, S1, S2);
    k_bn_fin<<<256, 256, 0, stream>>>(S1, S2, bn_gamma + (size_t)i * 256, bn_beta + (size_t)i * 256,
                                      abuf, bbuf, NN);
    k_msq<<<GG, 256, 0, stream>>>(S1, S2, abuf, bbuf, cnti, cntf, msqb);
    if (i == LL - 1)
      k_apply<1><<<GG, 256, 0, stream>>>(zbuf, abuf, bbuf, gst, cnti, S1, msqb, hb);
    else
      k_apply<0><<<GG, 256, 0, stream>>>(zbuf, abuf, bbuf, gst, cnti, S1, msqb, hb);
  }

  // pooling (zbuf holds fp32 h)
  k_att<<<mtiles, 256, 0, stream>>>(hb, atp, att_b1, att_w2, att_b2, scor, NN);
  k_poolout<<<GG, 256, 0, stream>>>(zbuf, scor, gst, cnti, cntf, out);
}

// Round 6
// 2074.501 us; speedup vs baseline: 6.1599x; 1.0790x over previous
//
#include <hip/hip_runtime.h>
#include <cstdint>
#include <cstddef>

// Problem constants (fixed instance)
#define NN 100000
#define EE 320000
#define GG 2048
#define LL 8

// Workspace layout (float offsets).
#define O_Z    0ull                      // [N,256] fp32 z; h fp32 (in-place) after last apply
#define O_ZB   25600000ull               // [N,256] bf16 zin
#define O_HB   38400000ull               // [N,256] bf16 h
#define O_S1   51200000ull               // [G,256] S1
#define O_S2   (O_S1 + 524288ull)        // [G,256] S2
#define O_ABUF (O_S2 + 524288ull)        // [256]
#define O_BBUF (O_ABUF + 256ull)         // [256]
#define O_CNTI (O_BBUF + 256ull)         // [G] int
#define O_CNTF (O_CNTI + 2048ull)        // [G]
#define O_SCOR (O_CNTF + 2048ull)        // [N] scores (CSR cursor during setup)
#define O_WEFF (O_SCOR + 100000ull)      // [L,6,256]
#define O_BEFF (O_WEFF + 12288ull)       // [L,256]
#define O_DEG  (O_BEFF + 2048ull)        // [N] int
#define O_STRT (O_DEG + 100000ull)       // [N] int
#define O_BSUM (O_STRT + 100000ull)      // [512] int
#define O_CSR  (O_BSUM + 512ull)         // [E] x 16 B: 6 bf16 attrs + int src
#define O_W1P  (O_CSR + 1280000ull)      // 8 x 65536 bf16 = 262144 floats
#define O_W2P  (O_W1P + 262144ull)
#define O_ATP  (O_W2P + 262144ull)       // 32768 shorts = 16384 floats
#define O_GST  (O_ATP + 16384ull)        // [G] int gstart

typedef short s16x8 __attribute__((ext_vector_type(8)));
typedef float f32x4 __attribute__((ext_vector_type(4)));

__device__ inline float b2f(unsigned int lo16) {
  union { float f; unsigned int u; } x; x.u = lo16 << 16; return x.f;
}
__device__ inline unsigned short f2b(float f) {
  union { float f; unsigned int u; } x; x.f = f;
  unsigned int r = x.u + 0x7FFFu + ((x.u >> 16) & 1u);
  return (unsigned short)(r >> 16);
}

__global__ __launch_bounds__(256) void k_zero(float* __restrict__ p, int n) {
  int i = blockIdx.x * 256 + threadIdx.x;
  int stride = gridDim.x * 256;
  for (; i < n; i += stride) p[i] = 0.0f;
}

__global__ __launch_bounds__(256) void k_count(const int* __restrict__ batch, int* __restrict__ cnti, int n) {
  int i = blockIdx.x * 256 + threadIdx.x;
  if (i < n) atomicAdd(&cnti[batch[i]], 1);
}

// single-block scan over G=2048 counts -> gstart (exclusive), cntf (clamped)
__global__ __launch_bounds__(256) void k_gscan(const int* __restrict__ cnti, int* __restrict__ gstart,
                                               float* __restrict__ cntf) {
  __shared__ int part[256];
  int t = threadIdx.x;
  int base = t * 8;
  int loc[8];
  int s = 0;
#pragma unroll
  for (int i = 0; i < 8; ++i) { loc[i] = s; s += cnti[base + i]; }
  part[t] = s;
  __syncthreads();
  for (int off = 1; off < 256; off <<= 1) {
    int u = (t >= off) ? part[t - off] : 0;
    __syncthreads();
    part[t] += u;
    __syncthreads();
  }
  int p = (t > 0) ? part[t - 1] : 0;
#pragma unroll
  for (int i = 0; i < 8; ++i) {
    gstart[base + i] = p + loc[i];
    float v = (float)cnti[base + i];
    cntf[base + i] = v > 1.0f ? v : 1.0f;
  }
}

// ---------------- CSR build ----------------
__global__ __launch_bounds__(256) void k_deg(const int* __restrict__ edst, int* __restrict__ deg, int ne) {
  int e = blockIdx.x * 256 + threadIdx.x;
  if (e < ne) atomicAdd(&deg[edst[e]], 1);
}

__global__ __launch_bounds__(256) void k_scan_part(const int* __restrict__ deg, int* __restrict__ start,
                                                   int* __restrict__ bsum, int n) {
  __shared__ int s[256];
  int i = blockIdx.x * 256 + threadIdx.x;
  int t = threadIdx.x;
  int v = (i < n) ? deg[i] : 0;
  s[t] = v;
  __syncthreads();
  for (int off = 1; off < 256; off <<= 1) {
    int u = (t >= off) ? s[t - off] : 0;
    __syncthreads();
    s[t] += u;
    __syncthreads();
  }
  if (i < n) start[i] = s[t] - v;
  if (t == 255) bsum[blockIdx.x] = s[255];
}

__global__ __launch_bounds__(512) void k_scan_top(int* __restrict__ bsum, int nb) {
  __shared__ int s[512];
  int t = threadIdx.x;
  int v = (t < nb) ? bsum[t] : 0;
  s[t] = v;
  __syncthreads();
  for (int off = 1; off < 512; off <<= 1) {
    int u = (t >= off) ? s[t - off] : 0;
    __syncthreads();
    s[t] += u;
    __syncthreads();
  }
  if (t < nb) bsum[t] = s[t] - v;
}

__global__ __launch_bounds__(256) void k_scan_add(int* __restrict__ start, const int* __restrict__ bsum,
                                                  int* __restrict__ cursor, int n) {
  int i = blockIdx.x * 256 + threadIdx.x;
  if (i < n) {
    int v = start[i] + bsum[blockIdx.x];
    start[i] = v;
    cursor[i] = v;
  }
}

// CSR entry: uint4 = {attr0|attr1<<16, attr2|attr3<<16, attr4|attr5<<16, src}
__global__ __launch_bounds__(256) void k_fill(const float* __restrict__ ea, const int* __restrict__ esrc,
                                              const int* __restrict__ edst, int* __restrict__ cursor,
                                              uint4* __restrict__ csr, int ne) {
  int e = blockIdx.x * 256 + threadIdx.x;
  if (e >= ne) return;
  int d = edst[e];
  int slot = atomicAdd(&cursor[d], 1);
  const float* ap = ea + (size_t)e * 6;
  uint4 v;
  v.x = (unsigned int)f2b(ap[0]) | ((unsigned int)f2b(ap[1]) << 16);
  v.y = (unsigned int)f2b(ap[2]) | ((unsigned int)f2b(ap[3]) << 16);
  v.z = (unsigned int)f2b(ap[4]) | ((unsigned int)f2b(ap[5]) << 16);
  v.w = (unsigned int)esrc[e];
  csr[slot] = v;
}

// W_eff[i] = edge_w @ conv_w[i]; b_eff[i] = edge_b @ conv_w[i] + conv_b[i]
__global__ __launch_bounds__(256) void k_wfuse(const float* __restrict__ edge_w, const float* __restrict__ edge_b,
                                               const float* __restrict__ conv_w, const float* __restrict__ conv_b,
                                               float* __restrict__ wef, float* __restrict__ bef) {
  __shared__ float ew[6 * 128 + 128];
  int i = blockIdx.x;
  int c = threadIdx.x;
  for (int idx = c; idx < 896; idx += 256)
    ew[idx] = idx < 768 ? edge_w[idx] : edge_b[idx - 768];
  __syncthreads();
  float acc[7] = {0.f, 0.f, 0.f, 0.f, 0.f, 0.f, 0.f};
  const float* cw = conv_w + (size_t)i * 32768 + c;
  for (int j = 0; j < 128; ++j) {
    float w = cw[(size_t)j * 256];
#pragma unroll
    for (int k = 0; k < 6; ++k) acc[k] = fmaf(ew[k * 128 + j], w, acc[k]);
    acc[6] = fmaf(ew[768 + j], w, acc[6]);
  }
#pragma unroll
  for (int k = 0; k < 6; ++k) wef[(size_t)i * 1536 + k * 256 + c] = acc[k];
  bef[(size_t)i * 256 + c] = acc[6] + conv_b[(size_t)i * 256 + c];
}

// pack ALL weights to MFMA B-fragment order in one launch.
// cbu 0..31: mlp (m = cbu>>1: 0-7 w1, 8-15 w2; cb = cbu&1); cbu 32: att_w1 (ldb=128, cb=0).
__global__ __launch_bounds__(256) void k_pack_all(const float* __restrict__ mw1, const float* __restrict__ mw2,
                                                  const float* __restrict__ aw1,
                                                  unsigned short* __restrict__ w1p,
                                                  unsigned short* __restrict__ w2p,
                                                  unsigned short* __restrict__ atp) {
  int id = blockIdx.x * 256 + threadIdx.x;   // 33*4096 total
  int cbu = id >> 12;
  if (cbu >= 33) return;
  int lid = id & 4095;
  int l = lid & 63;
  int ct = (lid >> 6) & 7;
  int ks = (lid >> 9) & 7;
  const float* B;
  unsigned short* Bp;
  int ldb, cb;
  if (cbu < 32) {
    int m = cbu >> 1;
    cb = cbu & 1;
    ldb = 256;
    if (m < 8) { B = mw1 + (size_t)m * 65536; Bp = w1p + (size_t)m * 65536; }
    else       { B = mw2 + (size_t)(m - 8) * 65536; Bp = w2p + (size_t)(m - 8) * 65536; }
  } else {
    B = aw1; Bp = atp; ldb = 128; cb = 0;
  }
  int n = cb * 128 + ct * 16 + (l & 15);
  int k0 = ks * 32 + (l >> 4) * 8;
  unsigned short* dst = Bp + (((size_t)cb << 12) | (size_t)lid) * 8;
#pragma unroll
  for (int j = 0; j < 8; ++j) dst[j] = f2b(B[(size_t)(k0 + j) * ldb + n]);
}

// hb = bf16(x @ node_w + node_b)
__global__ __launch_bounds__(256) void k_node_embed(const float* __restrict__ x, const float* __restrict__ w,
                                                    const float* __restrict__ b, unsigned short* __restrict__ hb,
                                                    int n) {
  __shared__ float xs[16 * 48];
  int tid = threadIdx.x;
  int row0 = blockIdx.x * 16;
  for (int idx = tid; idx < 16 * 48; idx += 256) {
    int r = idx / 48, c = idx - r * 48;
    int gr = row0 + r; if (gr >= n) gr = n - 1;
    xs[idx] = x[(size_t)gr * 48 + c];
  }
  __syncthreads();
  float acc[16];
#pragma unroll
  for (int r = 0; r < 16; ++r) acc[r] = 0.0f;
  for (int k = 0; k < 48; ++k) {
    float wv = w[k * 256 + tid];
#pragma unroll
    for (int r = 0; r < 16; ++r) acc[r] = fmaf(xs[r * 48 + k], wv, acc[r]);
  }
  float bb = b[tid];
#pragma unroll
  for (int r = 0; r < 16; ++r) {
    int gr = row0 + r;
    if (gr < n) hb[(size_t)gr * 256 + tid] = f2b(acc[r] + bb);
  }
}

// zin_b[v] = bf16((1+eps)h[v] + sum relu(h[src]+ea@W_eff+b_eff))
// one wave per node (full 256-col row, 4 cols/lane), 4 nodes/block, unroll-2 gather chains.
__global__ __launch_bounds__(256) void k_edge_csr(const uint4* __restrict__ csr,
                                                  const int* __restrict__ startv, const int* __restrict__ degv,
                                                  const float* __restrict__ wef, const float* __restrict__ bef,
                                                  const unsigned short* __restrict__ hb,
                                                  unsigned short* __restrict__ zb,
                                                  const float* __restrict__ eps, int layer, int n) {
  int lane = threadIdx.x & 63;
  int wv = threadIdx.x >> 6;
  int v = blockIdx.x * 4 + wv;
  if (v >= n) return;
  int c0 = lane * 4;
  float4 w0 = *(const float4*)(wef + 0 * 256 + c0);
  float4 w1 = *(const float4*)(wef + 1 * 256 + c0);
  float4 w2 = *(const float4*)(wef + 2 * 256 + c0);
  float4 w3 = *(const float4*)(wef + 3 * 256 + c0);
  float4 w4 = *(const float4*)(wef + 4 * 256 + c0);
  float4 w5 = *(const float4*)(wef + 5 * 256 + c0);
  float4 bf = *(const float4*)(bef + c0);
  int st = startv[v], en = st + degv[v];
  float s = 1.0f + eps[layer];
  uint2 hu = *(const uint2*)(hb + (size_t)v * 256 + c0);
  float ax = s * b2f(hu.x & 0xFFFFu), ay = s * b2f(hu.x >> 16);
  float az = s * b2f(hu.y & 0xFFFFu), aw = s * b2f(hu.y >> 16);
  int j = st;
  for (; j + 2 <= en; j += 2) {
    uint4 e0 = csr[j];
    uint4 e1 = csr[j + 1];
    uint2 g0 = *(const uint2*)(hb + (size_t)(int)e0.w * 256 + c0);
    uint2 g1 = *(const uint2*)(hb + (size_t)(int)e1.w * 256 + c0);
    float a00 = b2f(e0.x & 0xFFFFu), a01 = b2f(e0.x >> 16), a02 = b2f(e0.y & 0xFFFFu);
    float a03 = b2f(e0.y >> 16), a04 = b2f(e0.z & 0xFFFFu), a05 = b2f(e0.z >> 16);
    float a10 = b2f(e1.x & 0xFFFFu), a11 = b2f(e1.x >> 16), a12 = b2f(e1.y & 0xFFFFu);
    float a13 = b2f(e1.y >> 16), a14 = b2f(e1.z & 0xFFFFu), a15 = b2f(e1.z >> 16);
    float m0x = fmaf(a00, w0.x, fmaf(a01, w1.x, fmaf(a02, w2.x, fmaf(a03, w3.x, fmaf(a04, w4.x, fmaf(a05, w5.x, b2f(g0.x & 0xFFFFu) + bf.x))))));
    float m0y = fmaf(a00, w0.y, fmaf(a01, w1.y, fmaf(a02, w2.y, fmaf(a03, w3.y, fmaf(a04, w4.y, fmaf(a05, w5.y, b2f(g0.x >> 16) + bf.y))))));
    float m0z = fmaf(a00, w0.z, fmaf(a01, w1.z, fmaf(a02, w2.z, fmaf(a03, w3.z, fmaf(a04, w4.z, fmaf(a05, w5.z, b2f(g0.y & 0xFFFFu) + bf.z))))));
    float m0w = fmaf(a00, w0.w, fmaf(a01, w1.w, fmaf(a02, w2.w, fmaf(a03, w3.w, fmaf(a04, w4.w, fmaf(a05, w5.w, b2f(g0.y >> 16) + bf.w))))));
    float m1x = fmaf(a10, w0.x, fmaf(a11, w1.x, fmaf(a12, w2.x, fmaf(a13, w3.x, fmaf(a14, w4.x, fmaf(a15, w5.x, b2f(g1.x & 0xFFFFu) + bf.x))))));
    float m1y = fmaf(a10, w0.y, fmaf(a11, w1.y, fmaf(a12, w2.y, fmaf(a13, w3.y, fmaf(a14, w4.y, fmaf(a15, w5.y, b2f(g1.x >> 16) + bf.y))))));
    float m1z = fmaf(a10, w0.z, fmaf(a11, w1.z, fmaf(a12, w2.z, fmaf(a13, w3.z, fmaf(a14, w4.z, fmaf(a15, w5.z, b2f(g1.y & 0xFFFFu) + bf.z))))));
    float m1w = fmaf(a10, w0.w, fmaf(a11, w1.w, fmaf(a12, w2.w, fmaf(a13, w3.w, fmaf(a14, w4.w, fmaf(a15, w5.w, b2f(g1.y >> 16) + bf.w))))));
    ax += (m0x > 0.f ? m0x : 0.f) + (m1x > 0.f ? m1x : 0.f);
    ay += (m0y > 0.f ? m0y : 0.f) + (m1y > 0.f ? m1y : 0.f);
    az += (m0z > 0.f ? m0z : 0.f) + (m1z > 0.f ? m1z : 0.f);
    aw += (m0w > 0.f ? m0w : 0.f) + (m1w > 0.f ? m1w : 0.f);
  }
  if (j < en) {
    uint4 e0 = csr[j];
    uint2 g0 = *(const uint2*)(hb + (size_t)(int)e0.w * 256 + c0);
    float a00 = b2f(e0.x & 0xFFFFu), a01 = b2f(e0.x >> 16), a02 = b2f(e0.y & 0xFFFFu);
    float a03 = b2f(e0.y >> 16), a04 = b2f(e0.z & 0xFFFFu), a05 = b2f(e0.z >> 16);
    float m0x = fmaf(a00, w0.x, fmaf(a01, w1.x, fmaf(a02, w2.x, fmaf(a03, w3.x, fmaf(a04, w4.x, fmaf(a05, w5.x, b2f(g0.x & 0xFFFFu) + bf.x))))));
    float m0y = fmaf(a00, w0.y, fmaf(a01, w1.y, fmaf(a02, w2.y, fmaf(a03, w3.y, fmaf(a04, w4.y, fmaf(a05, w5.y, b2f(g0.x >> 16) + bf.y))))));
    float m0z = fmaf(a00, w0.z, fmaf(a01, w1.z, fmaf(a02, w2.z, fmaf(a03, w3.z, fmaf(a04, w4.z, fmaf(a05, w5.z, b2f(g0.y & 0xFFFFu) + bf.z))))));
    float m0w = fmaf(a00, w0.w, fmaf(a01, w1.w, fmaf(a02, w2.w, fmaf(a03, w3.w, fmaf(a04, w4.w, fmaf(a05, w5.w, b2f(g0.y >> 16) + bf.w))))));
    ax += m0x > 0.f ? m0x : 0.f;
    ay += m0y > 0.f ? m0y : 0.f;
    az += m0z > 0.f ? m0z : 0.f;
    aw += m0w > 0.f ? m0w : 0.f;
  }
  uint2 o;
  o.x = (unsigned int)f2b(ax) | ((unsigned int)f2b(ay) << 16);
  o.y = (unsigned int)f2b(az) | ((unsigned int)f2b(aw) << 16);
  *(uint2*)(zb + (size_t)v * 256 + c0) = o;
}

// Fused MLP: z = relu(zin@W1+b1)@W2+b2 for a 128-row tile.
__global__ __launch_bounds__(256, 2) void k_mlp(const unsigned short* __restrict__ A,
                                                const unsigned short* __restrict__ W1p,
                                                const float* __restrict__ b1,
                                                const unsigned short* __restrict__ W2p,
                                                const float* __restrict__ b2,
                                                float* __restrict__ Z, int M) {
  __shared__ unsigned short t1s[128 * 256];  // 64 KB
  int l = threadIdx.x & 63;
  int w = threadIdx.x >> 6;
  int mloc = l & 15, q = l >> 4;
  int rowh = (w & 1) * 64;
  int colh = (w >> 1) * 128;
  int row0 = blockIdx.x * 128;

  const unsigned short* ap[4];
#pragma unroll
  for (int rt = 0; rt < 4; ++rt) {
    int r = row0 + rowh + rt * 16 + mloc;
    if (r > M - 1) r = M - 1;
    ap[rt] = A + (size_t)r * 256 + q * 8;
  }
  f32x4 acc[4][8];
#pragma unroll
  for (int rt = 0; rt < 4; ++rt)
#pragma unroll
    for (int ct = 0; ct < 8; ++ct) acc[rt][ct] = (f32x4){0.f, 0.f, 0.f, 0.f};

  const unsigned short* w1base = W1p + ((size_t)(colh >> 7)) * 32768 + (size_t)l * 8;
#pragma unroll
  for (int ks = 0; ks < 8; ++ks) {
    s16x8 a[4];
#pragma unroll
    for (int rt = 0; rt < 4; ++rt) a[rt] = *(const s16x8*)(ap[rt] + ks * 32);
#pragma unroll
    for (int ct = 0; ct < 8; ++ct) {
      s16x8 b = *(const s16x8*)(w1base + ks * 4096 + ct * 512);
#pragma unroll
      for (int rt = 0; rt < 4; ++rt)
        acc[rt][ct] = __builtin_amdgcn_mfma_f32_16x16x32_bf16(a[rt], b, acc[rt][ct], 0, 0, 0);
    }
  }
#pragma unroll
  for (int ct = 0; ct < 8; ++ct) {
    int col = colh + ct * 16 + mloc;
    float bv = b1[col];
    int cc = col >> 3, pos = col & 7;
#pragma unroll
    for (int rt = 0; rt < 4; ++rt)
#pragma unroll
      for (int r = 0; r < 4; ++r) {
        int row = rowh + rt * 16 + q * 4 + r;
        float v = acc[rt][ct][r] + bv;
        v = v > 0.f ? v : 0.f;
        t1s[row * 256 + ((cc ^ (row & 31)) << 3) + pos] = f2b(v);
      }
  }
  __syncthreads();
#pragma unroll
  for (int rt = 0; rt < 4; ++rt)
#pragma unroll
    for (int ct = 0; ct < 8; ++ct) acc[rt][ct] = (f32x4){0.f, 0.f, 0.f, 0.f};
  const unsigned short* w2base = W2p + ((size_t)(colh >> 7)) * 32768 + (size_t)l * 8;
#pragma unroll
  for (int ks = 0; ks < 8; ++ks) {
    s16x8 a[4];
#pragma unroll
    for (int rt = 0; rt < 4; ++rt) {
      int row = rowh + rt * 16 + mloc;
      int cc = (q + ks * 4) ^ (row & 31);
      a[rt] = *(const s16x8*)(t1s + row * 256 + (cc << 3));
    }
#pragma unroll
    for (int ct = 0; ct < 8; ++ct) {
      s16x8 b = *(const s16x8*)(w2base + ks * 4096 + ct * 512);
#pragma unroll
      for (int rt = 0; rt < 4; ++rt)
        acc[rt][ct] = __builtin_amdgcn_mfma_f32_16x16x32_bf16(a[rt], b, acc[rt][ct], 0, 0, 0);
    }
  }
#pragma unroll
  for (int ct = 0; ct < 8; ++ct) {
    int col = colh + ct * 16 + mloc;
    float bv = b2[col];
#pragma unroll
    for (int rt = 0; rt < 4; ++rt)
#pragma unroll
      for (int r = 0; r < 4; ++r) {
        int grow = row0 + rowh + rt * 16 + q * 4 + r;
        if (grow < M) Z[(size_t)grow * 256 + col] = acc[rt][ct][r] + bv;
      }
  }
}

// attention: score[row] = tanh(h@W1+b1) @ w2 + b2 — fused
__global__ __launch_bounds__(256) void k_att(const unsigned short* __restrict__ A,
                                             const unsigned short* __restrict__ Bp,
                                             const float* __restrict__ b1,
                                             const float* __restrict__ w2,
                                             const float* __restrict__ b2,
                                             float* __restrict__ scores, int M) {
  int l = threadIdx.x & 63;
  int w = threadIdx.x >> 6;
  int mloc = l & 15, q = l >> 4;
  int row0 = blockIdx.x * 128 + w * 32;

  int r0 = row0 + mloc;      if (r0 > M - 1) r0 = M - 1;
  int r1 = row0 + 16 + mloc; if (r1 > M - 1) r1 = M - 1;
  const unsigned short* ap0 = A + (size_t)r0 * 256 + q * 8;
  const unsigned short* ap1 = A + (size_t)r1 * 256 + q * 8;
  const unsigned short* bp = Bp + (size_t)l * 8;

  f32x4 acc[2][8];
#pragma unroll
  for (int rt = 0; rt < 2; ++rt)
#pragma unroll
    for (int ct = 0; ct < 8; ++ct) acc[rt][ct] = (f32x4){0.f, 0.f, 0.f, 0.f};
#pragma unroll
  for (int ks = 0; ks < 8; ++ks) {
    s16x8 a0 = *(const s16x8*)(ap0 + ks * 32);
    s16x8 a1 = *(const s16x8*)(ap1 + ks * 32);
#pragma unroll
    for (int ct = 0; ct < 8; ++ct) {
      s16x8 b = *(const s16x8*)(bp + ks * 4096 + ct * 512);
      acc[0][ct] = __builtin_amdgcn_mfma_f32_16x16x32_bf16(a0, b, acc[0][ct], 0, 0, 0);
      acc[1][ct] = __builtin_amdgcn_mfma_f32_16x16x32_bf16(a1, b, acc[1][ct], 0, 0, 0);
    }
  }
  float bv[8], wv[8];
#pragma unroll
  for (int ct = 0; ct < 8; ++ct) {
    bv[ct] = b1[ct * 16 + mloc];
    wv[ct] = w2[ct * 16 + mloc];
  }
  float b2v = b2[0];
#pragma unroll
  for (int rt = 0; rt < 2; ++rt)
#pragma unroll
    for (int r = 0; r < 4; ++r) {
      float p = 0.0f;
#pragma unroll
      for (int ct = 0; ct < 8; ++ct) p = fmaf(tanhf(acc[rt][ct][r] + bv[ct]), wv[ct], p);
      p += __shfl_xor(p, 1, 64);
      p += __shfl_xor(p, 2, 64);
      p += __shfl_xor(p, 4, 64);
      p += __shfl_xor(p, 8, 64);
      int row = row0 + rt * 16 + q * 4 + r;
      if (mloc == 0 && row < M) scores[row] = p + b2v;
    }
}

// per-graph per-column S1/S2 of z — one block per graph, no atomics
__global__ __launch_bounds__(256) void k_stats(const float* __restrict__ z, const int* __restrict__ gstart,
                                               const int* __restrict__ cnti,
                                               float* __restrict__ S1, float* __restrict__ S2) {
  int g = blockIdx.x, c = threadIdx.x;
  int r0 = gstart[g], r1 = r0 + cnti[g];
  float s1 = 0.0f, s2 = 0.0f;
  for (int r = r0; r < r1; ++r) {
    float v = z[(size_t)r * 256 + c];
    s1 += v;
    s2 = fmaf(v, v, s2);
  }
  S1[(size_t)g * 256 + c] = s1;
  S2[(size_t)g * 256 + c] = s2;
}

// column BN stats from per-graph S1/S2: one block per column
__global__ __launch_bounds__(256) void k_bn_fin(const float* __restrict__ S1, const float* __restrict__ S2,
                                                const float* __restrict__ gamma, const float* __restrict__ beta,
                                                float* __restrict__ abuf, float* __restrict__ bbuf, int n) {
  __shared__ float r1[256], r2[256];
  int c = blockIdx.x;
  int t = threadIdx.x;
  float s1 = 0.0f, s2 = 0.0f;
  for (int g = t; g < GG; g += 256) {
    s1 += S1[(size_t)g * 256 + c];
    s2 += S2[(size_t)g * 256 + c];
  }
  r1[t] = s1; r2[t] = s2;
  __syncthreads();
  for (int off = 128; off; off >>= 1) {
    if (t < off) { r1[t] += r1[t + off]; r2[t] += r2[t + off]; }
    __syncthreads();
  }
  if (t == 0) {
    float inv = 1.0f / (float)n;
    float mu = r1[0] * inv;
    float var = r2[0] * inv - mu * mu;
    float rstd = rsqrtf(var + 1e-5f);
    float a = gamma[c] * rstd;
    abuf[c] = a;
    bbuf[c] = beta[c] - mu * a;
  }
}

// per-graph: compute gmean/rinv from S1/S2 in-block, then apply BN+PairNorm+relu.
// h -> hb bf16; LAST also fp32 into z (for pooling).
template <int LAST>
__global__ __launch_bounds__(256) void k_apply(float* __restrict__ z, const float* __restrict__ abuf,
                                               const float* __restrict__ bbuf, const int* __restrict__ gstart,
                                               const int* __restrict__ cnti, const float* __restrict__ cntf,
                                               const float* __restrict__ S1, const float* __restrict__ S2,
                                               unsigned short* __restrict__ hb) {
  __shared__ float rT[256], rM[256];
  int g = blockIdx.x, c = threadIdx.x;
  float a = abuf[c], b = bbuf[c];
  float s1 = S1[(size_t)g * 256 + c];
  float s2 = S2[(size_t)g * 256 + c];
  float nr = (float)cnti[g];
  float ic = 1.0f / cntf[g];
  float mean = (a * s1 + nr * b) * ic;
  float term = fmaf(a * a, s2, fmaf(2.0f * a * b, s1, nr * b * b));
  rT[c] = term;
  rM[c] = mean * mean;
  __syncthreads();
  for (int off = 128; off; off >>= 1) {
    if (c < off) { rT[c] += rT[c + off]; rM[c] += rM[c + off]; }
    __syncthreads();
  }
  float cr = nr > 0.0f ? 1.0f : 0.0f;
  float rinv = rsqrtf(1e-5f + rT[0] * ic - cr * rM[0]);
  int r0 = gstart[g], r1 = r0 + cnti[g];
  for (int r = r0; r < r1; ++r) {
    float v = (fmaf(a, z[(size_t)r * 256 + c], b) - mean) * rinv;
    v = v > 0.0f ? v : 0.0f;
    hb[(size_t)r * 256 + c] = f2b(v);
    if (LAST) z[(size_t)r * 256 + c] = v;
  }
}

// per-graph fused pooling + output
__global__ __launch_bounds__(256) void k_poolout(const float* __restrict__ h, const float* __restrict__ scores,
                                                 const int* __restrict__ gstart, const int* __restrict__ cnti,
                                                 const float* __restrict__ cntf, float* __restrict__ out) {
  int g = blockIdx.x, c = threadIdx.x;
  int r0 = gstart[g], r1 = r0 + cnti[g];
  float ma = 0.0f, aa = 0.0f, mx = 0.0f, wa = 0.0f;
  for (int r = r0; r < r1; ++r) {
    float wgt = __expf(scores[r]);
    float hv = h[(size_t)r * 256 + c];
    ma += hv;
    aa = fmaf(hv, wgt, aa);
    mx = fmaxf(mx, hv);
    wa += wgt;
  }
  out[(size_t)g * 768 + c] = ma / cntf[g];
  out[(size_t)g * 768 + 256 + c] = mx;
  out[(size_t)g * 768 + 512 + c] = aa / (wa + 1e-8f);
}

extern "C" void kernel_launch(void* const* d_in, const int* in_sizes, int n_in,
                              void* d_out, int out_size, void* d_ws, size_t ws_size,
                              hipStream_t stream) {
  const float* x         = (const float*)d_in[0];
  const float* edge_attr = (const float*)d_in[1];
  const float* node_w    = (const float*)d_in[2];
  const float* node_b    = (const float*)d_in[3];
  const float* edge_w    = (const float*)d_in[4];
  const float* edge_b    = (const float*)d_in[5];
  const float* conv_w    = (const float*)d_in[6];
  const float* conv_b    = (const float*)d_in[7];
  const float* mlp_w1    = (const float*)d_in[8];
  const float* mlp_b1    = (const float*)d_in[9];
  const float* mlp_w2    = (const float*)d_in[10];
  const float* mlp_b2    = (const float*)d_in[11];
  const float* eps       = (const float*)d_in[12];
  const float* bn_gamma  = (const float*)d_in[13];
  const float* bn_beta   = (const float*)d_in[14];
  const float* att_w1    = (const float*)d_in[15];
  const float* att_b1    = (const float*)d_in[16];
  const float* att_w2    = (const float*)d_in[17];
  const float* att_b2    = (const float*)d_in[18];
  const int*   eidx      = (const int*)d_in[19];
  const int*   batch     = (const int*)d_in[20];
  float* out = (float*)d_out;
  float* ws  = (float*)d_ws;

  float*          zbuf = ws + O_Z;
  unsigned short* zb   = (unsigned short*)(ws + O_ZB);
  unsigned short* hb   = (unsigned short*)(ws + O_HB);
  float* S1    = ws + O_S1;
  float* S2    = ws + O_S2;
  float* abuf  = ws + O_ABUF;
  float* bbuf  = ws + O_BBUF;
  int*   cnti  = (int*)(ws + O_CNTI);
  float* cntf  = ws + O_CNTF;
  float* scor  = ws + O_SCOR;
  int*   curs  = (int*)(ws + O_SCOR);
  float* weff  = ws + O_WEFF;
  float* beff  = ws + O_BEFF;
  int*   deg   = (int*)(ws + O_DEG);
  int*   strt  = (int*)(ws + O_STRT);
  int*   bsum  = (int*)(ws + O_BSUM);
  uint4* csr   = (uint4*)(ws + O_CSR);
  unsigned short* w1p = (unsigned short*)(ws + O_W1P);
  unsigned short* w2p = (unsigned short*)(ws + O_W2P);
  unsigned short* atp = (unsigned short*)(ws + O_ATP);
  int*   gst   = (int*)(ws + O_GST);
  const int* esrc = eidx;
  const int* edst = eidx + EE;

  // graph counts + offsets
  k_zero<<<8, 256, 0, stream>>>((float*)cnti, GG);
  k_count<<<(NN + 255) / 256, 256, 0, stream>>>(batch, cnti, NN);
  k_gscan<<<1, 256, 0, stream>>>(cnti, gst, cntf);

  // fused edge weights + node embedding + weight packing
  k_wfuse<<<LL, 256, 0, stream>>>(edge_w, edge_b, conv_w, conv_b, weff, beff);
  k_node_embed<<<(NN + 15) / 16, 256, 0, stream>>>(x, node_w, node_b, hb, NN);
  k_pack_all<<<528, 256, 0, stream>>>(mlp_w1, mlp_w2, att_w1, w1p, w2p, atp);

  // CSR build (by dst)
  const int nscan = (NN + 255) / 256;  // 391
  k_zero<<<256, 256, 0, stream>>>((float*)deg, NN);
  k_deg<<<(EE + 255) / 256, 256, 0, stream>>>(edst, deg, EE);
  k_scan_part<<<nscan, 256, 0, stream>>>(deg, strt, bsum, NN);
  k_scan_top<<<1, 512, 0, stream>>>(bsum, nscan);
  k_scan_add<<<nscan, 256, 0, stream>>>(strt, bsum, curs, NN);
  k_fill<<<(EE + 255) / 256, 256, 0, stream>>>(edge_attr, esrc, edst, curs, csr, EE);

  const int mtiles = (NN + 127) / 128;  // 782

  for (int i = 0; i < LL; ++i) {
    k_edge_csr<<<NN / 4, 256, 0, stream>>>(csr, strt, deg, weff + (size_t)i * 1536,
                                           beff + (size_t)i * 256, hb, zb, eps, i, NN);
    k_mlp<<<mtiles, 256, 0, stream>>>(zb, w1p + (size_t)i * 65536, mlp_b1 + (size_t)i * 256,
                                      w2p + (size_t)i * 65536, mlp_b2 + (size_t)i * 256, zbuf, NN);
    k_stats<<<GG, 256, 0, stream>>>(zbuf, gst, cnti, S1, S2);
    k_bn_fin<<<256, 256, 0, stream>>>(S1, S2, bn_gamma + (size_t)i * 256, bn_beta + (size_t)i * 256,
                                      abuf, bbuf, NN);
    if (i == LL - 1)
      k_apply<1><<<GG, 256, 0, stream>>>(zbuf, abuf, bbuf, gst, cnti, cntf, S1, S2, hb);
    else
      k_apply<0><<<GG, 256, 0, stream>>>(zbuf, abuf, bbuf, gst, cnti, cntf, S1, S2, hb);
  }

  // pooling (zbuf holds fp32 h)
  k_att<<<mtiles, 256, 0, stream>>>(hb, atp, att_b1, att_w2, att_b2, scor, NN);
  k_poolout<<<GG, 256, 0, stream>>>(zbuf, scor, gst, cnti, cntf, out);
}

// Round 7
// 2072.973 us; speedup vs baseline: 6.1644x; 1.0007x over previous
//
#include <hip/hip_runtime.h>
#include <cstdint>
#include <cstddef>

// Problem constants (fixed instance)
#define NN 100000
#define EE 320000
#define GG 2048
#define LL 8

// Workspace layout (float offsets).
#define O_Z    0ull                      // [N,256] fp32 z; h fp32 (in-place) after last apply
#define O_ZB   25600000ull               // [N,256] bf16 zin
#define O_HB   38400000ull               // [N,256] bf16 h
#define O_S1   51200000ull               // [G,256] S1
#define O_S2   (O_S1 + 524288ull)        // [G,256] S2
#define O_ABUF (O_S2 + 524288ull)        // [256]
#define O_BBUF (O_ABUF + 256ull)         // [256]
#define O_CNTI (O_BBUF + 256ull)         // [G] int
#define O_CNTF (O_CNTI + 2048ull)        // [G]
#define O_SCOR (O_CNTF + 2048ull)        // [N] scores (CSR cursor during setup)
#define O_WEFF (O_SCOR + 100000ull)      // [L,6,256]
#define O_BEFF (O_WEFF + 12288ull)       // [L,256]
#define O_DEG  (O_BEFF + 2048ull)        // [N] int
#define O_STRT (O_DEG + 100000ull)       // [N] int
#define O_BSUM (O_STRT + 100000ull)      // [512] int
#define O_CSR  (O_BSUM + 512ull)         // [E] x 16 B: 6 bf16 attrs + int src
#define O_W1P  (O_CSR + 1280000ull)      // 8 x 65536 bf16 = 262144 floats
#define O_W2P  (O_W1P + 262144ull)
#define O_ATP  (O_W2P + 262144ull)       // 32768 shorts = 16384 floats
#define O_GST  (O_ATP + 16384ull)        // [G] int gstart

typedef short s16x8 __attribute__((ext_vector_type(8)));
typedef float f32x4 __attribute__((ext_vector_type(4)));

__device__ inline float b2f(unsigned int lo16) {
  union { float f; unsigned int u; } x; x.u = lo16 << 16; return x.f;
}
__device__ inline unsigned short f2b(float f) {
  union { float f; unsigned int u; } x; x.f = f;
  unsigned int r = x.u + 0x7FFFu + ((x.u >> 16) & 1u);
  return (unsigned short)(r >> 16);
}

__global__ __launch_bounds__(256) void k_zero(float* __restrict__ p, int n) {
  int i = blockIdx.x * 256 + threadIdx.x;
  int stride = gridDim.x * 256;
  for (; i < n; i += stride) p[i] = 0.0f;
}

__global__ __launch_bounds__(256) void k_count(const int* __restrict__ batch, int* __restrict__ cnti, int n) {
  int i = blockIdx.x * 256 + threadIdx.x;
  if (i < n) atomicAdd(&cnti[batch[i]], 1);
}

// single-block scan over G=2048 counts -> gstart (exclusive), cntf (clamped)
__global__ __launch_bounds__(256) void k_gscan(const int* __restrict__ cnti, int* __restrict__ gstart,
                                               float* __restrict__ cntf) {
  __shared__ int part[256];
  int t = threadIdx.x;
  int base = t * 8;
  int loc[8];
  int s = 0;
#pragma unroll
  for (int i = 0; i < 8; ++i) { loc[i] = s; s += cnti[base + i]; }
  part[t] = s;
  __syncthreads();
  for (int off = 1; off < 256; off <<= 1) {
    int u = (t >= off) ? part[t - off] : 0;
    __syncthreads();
    part[t] += u;
    __syncthreads();
  }
  int p = (t > 0) ? part[t - 1] : 0;
#pragma unroll
  for (int i = 0; i < 8; ++i) {
    gstart[base + i] = p + loc[i];
    float v = (float)cnti[base + i];
    cntf[base + i] = v > 1.0f ? v : 1.0f;
  }
}

// ---------------- CSR build ----------------
__global__ __launch_bounds__(256) void k_deg(const int* __restrict__ edst, int* __restrict__ deg, int ne) {
  int e = blockIdx.x * 256 + threadIdx.x;
  if (e < ne) atomicAdd(&deg[edst[e]], 1);
}

__global__ __launch_bounds__(256) void k_scan_part(const int* __restrict__ deg, int* __restrict__ start,
                                                   int* __restrict__ bsum, int n) {
  __shared__ int s[256];
  int i = blockIdx.x * 256 + threadIdx.x;
  int t = threadIdx.x;
  int v = (i < n) ? deg[i] : 0;
  s[t] = v;
  __syncthreads();
  for (int off = 1; off < 256; off <<= 1) {
    int u = (t >= off) ? s[t - off] : 0;
    __syncthreads();
    s[t] += u;
    __syncthreads();
  }
  if (i < n) start[i] = s[t] - v;
  if (t == 255) bsum[blockIdx.x] = s[255];
}

__global__ __launch_bounds__(512) void k_scan_top(int* __restrict__ bsum, int nb) {
  __shared__ int s[512];
  int t = threadIdx.x;
  int v = (t < nb) ? bsum[t] : 0;
  s[t] = v;
  __syncthreads();
  for (int off = 1; off < 512; off <<= 1) {
    int u = (t >= off) ? s[t - off] : 0;
    __syncthreads();
    s[t] += u;
    __syncthreads();
  }
  if (t < nb) bsum[t] = s[t] - v;
}

__global__ __launch_bounds__(256) void k_scan_add(int* __restrict__ start, const int* __restrict__ bsum,
                                                  int* __restrict__ cursor, int n) {
  int i = blockIdx.x * 256 + threadIdx.x;
  if (i < n) {
    int v = start[i] + bsum[blockIdx.x];
    start[i] = v;
    cursor[i] = v;
  }
}

// CSR entry: uint4 = {attr0|attr1<<16, attr2|attr3<<16, attr4|attr5<<16, src}
__global__ __launch_bounds__(256) void k_fill(const float* __restrict__ ea, const int* __restrict__ esrc,
                                              const int* __restrict__ edst, int* __restrict__ cursor,
                                              uint4* __restrict__ csr, int ne) {
  int e = blockIdx.x * 256 + threadIdx.x;
  if (e >= ne) return;
  int d = edst[e];
  int slot = atomicAdd(&cursor[d], 1);
  const float* ap = ea + (size_t)e * 6;
  uint4 v;
  v.x = (unsigned int)f2b(ap[0]) | ((unsigned int)f2b(ap[1]) << 16);
  v.y = (unsigned int)f2b(ap[2]) | ((unsigned int)f2b(ap[3]) << 16);
  v.z = (unsigned int)f2b(ap[4]) | ((unsigned int)f2b(ap[5]) << 16);
  v.w = (unsigned int)esrc[e];
  csr[slot] = v;
}

// W_eff[i] = edge_w @ conv_w[i]; b_eff[i] = edge_b @ conv_w[i] + conv_b[i]
__global__ __launch_bounds__(256) void k_wfuse(const float* __restrict__ edge_w, const float* __restrict__ edge_b,
                                               const float* __restrict__ conv_w, const float* __restrict__ conv_b,
                                               float* __restrict__ wef, float* __restrict__ bef) {
  __shared__ float ew[6 * 128 + 128];
  int i = blockIdx.x;
  int c = threadIdx.x;
  for (int idx = c; idx < 896; idx += 256)
    ew[idx] = idx < 768 ? edge_w[idx] : edge_b[idx - 768];
  __syncthreads();
  float acc[7] = {0.f, 0.f, 0.f, 0.f, 0.f, 0.f, 0.f};
  const float* cw = conv_w + (size_t)i * 32768 + c;
  for (int j = 0; j < 128; ++j) {
    float w = cw[(size_t)j * 256];
#pragma unroll
    for (int k = 0; k < 6; ++k) acc[k] = fmaf(ew[k * 128 + j], w, acc[k]);
    acc[6] = fmaf(ew[768 + j], w, acc[6]);
  }
#pragma unroll
  for (int k = 0; k < 6; ++k) wef[(size_t)i * 1536 + k * 256 + c] = acc[k];
  bef[(size_t)i * 256 + c] = acc[6] + conv_b[(size_t)i * 256 + c];
}

// pack ALL weights to MFMA B-fragment order in one launch.
__global__ __launch_bounds__(256) void k_pack_all(const float* __restrict__ mw1, const float* __restrict__ mw2,
                                                  const float* __restrict__ aw1,
                                                  unsigned short* __restrict__ w1p,
                                                  unsigned short* __restrict__ w2p,
                                                  unsigned short* __restrict__ atp) {
  int id = blockIdx.x * 256 + threadIdx.x;   // 33*4096 total
  int cbu = id >> 12;
  if (cbu >= 33) return;
  int lid = id & 4095;
  int l = lid & 63;
  int ct = (lid >> 6) & 7;
  int ks = (lid >> 9) & 7;
  const float* B;
  unsigned short* Bp;
  int ldb, cb;
  if (cbu < 32) {
    int m = cbu >> 1;
    cb = cbu & 1;
    ldb = 256;
    if (m < 8) { B = mw1 + (size_t)m * 65536; Bp = w1p + (size_t)m * 65536; }
    else       { B = mw2 + (size_t)(m - 8) * 65536; Bp = w2p + (size_t)(m - 8) * 65536; }
  } else {
    B = aw1; Bp = atp; ldb = 128; cb = 0;
  }
  int n = cb * 128 + ct * 16 + (l & 15);
  int k0 = ks * 32 + (l >> 4) * 8;
  unsigned short* dst = Bp + (((size_t)cb << 12) | (size_t)lid) * 8;
#pragma unroll
  for (int j = 0; j < 8; ++j) dst[j] = f2b(B[(size_t)(k0 + j) * ldb + n]);
}

// hb = bf16(x @ node_w + node_b)
__global__ __launch_bounds__(256) void k_node_embed(const float* __restrict__ x, const float* __restrict__ w,
                                                    const float* __restrict__ b, unsigned short* __restrict__ hb,
                                                    int n) {
  __shared__ float xs[16 * 48];
  int tid = threadIdx.x;
  int row0 = blockIdx.x * 16;
  for (int idx = tid; idx < 16 * 48; idx += 256) {
    int r = idx / 48, c = idx - r * 48;
    int gr = row0 + r; if (gr >= n) gr = n - 1;
    xs[idx] = x[(size_t)gr * 48 + c];
  }
  __syncthreads();
  float acc[16];
#pragma unroll
  for (int r = 0; r < 16; ++r) acc[r] = 0.0f;
  for (int k = 0; k < 48; ++k) {
    float wv = w[k * 256 + tid];
#pragma unroll
    for (int r = 0; r < 16; ++r) acc[r] = fmaf(xs[r * 48 + k], wv, acc[r]);
  }
  float bb = b[tid];
#pragma unroll
  for (int r = 0; r < 16; ++r) {
    int gr = row0 + r;
    if (gr < n) hb[(size_t)gr * 256 + tid] = f2b(acc[r] + bb);
  }
}

// zin_b[v] = bf16((1+eps)h[v] + sum relu(h[src]+ea@W_eff+b_eff))
// one wave per node, 4 nodes/block, unroll-2 gather chains.
__global__ __launch_bounds__(256) void k_edge_csr(const uint4* __restrict__ csr,
                                                  const int* __restrict__ startv, const int* __restrict__ degv,
                                                  const float* __restrict__ wef, const float* __restrict__ bef,
                                                  const unsigned short* __restrict__ hb,
                                                  unsigned short* __restrict__ zb,
                                                  const float* __restrict__ eps, int layer, int n) {
  int lane = threadIdx.x & 63;
  int wv = threadIdx.x >> 6;
  int v = blockIdx.x * 4 + wv;
  if (v >= n) return;
  int c0 = lane * 4;
  float4 w0 = *(const float4*)(wef + 0 * 256 + c0);
  float4 w1 = *(const float4*)(wef + 1 * 256 + c0);
  float4 w2 = *(const float4*)(wef + 2 * 256 + c0);
  float4 w3 = *(const float4*)(wef + 3 * 256 + c0);
  float4 w4 = *(const float4*)(wef + 4 * 256 + c0);
  float4 w5 = *(const float4*)(wef + 5 * 256 + c0);
  float4 bf = *(const float4*)(bef + c0);
  int st = startv[v], en = st + degv[v];
  float s = 1.0f + eps[layer];
  uint2 hu = *(const uint2*)(hb + (size_t)v * 256 + c0);
  float ax = s * b2f(hu.x & 0xFFFFu), ay = s * b2f(hu.x >> 16);
  float az = s * b2f(hu.y & 0xFFFFu), aw = s * b2f(hu.y >> 16);
  int j = st;
  for (; j + 2 <= en; j += 2) {
    uint4 e0 = csr[j];
    uint4 e1 = csr[j + 1];
    uint2 g0 = *(const uint2*)(hb + (size_t)(int)e0.w * 256 + c0);
    uint2 g1 = *(const uint2*)(hb + (size_t)(int)e1.w * 256 + c0);
    float a00 = b2f(e0.x & 0xFFFFu), a01 = b2f(e0.x >> 16), a02 = b2f(e0.y & 0xFFFFu);
    float a03 = b2f(e0.y >> 16), a04 = b2f(e0.z & 0xFFFFu), a05 = b2f(e0.z >> 16);
    float a10 = b2f(e1.x & 0xFFFFu), a11 = b2f(e1.x >> 16), a12 = b2f(e1.y & 0xFFFFu);
    float a13 = b2f(e1.y >> 16), a14 = b2f(e1.z & 0xFFFFu), a15 = b2f(e1.z >> 16);
    float m0x = fmaf(a00, w0.x, fmaf(a01, w1.x, fmaf(a02, w2.x, fmaf(a03, w3.x, fmaf(a04, w4.x, fmaf(a05, w5.x, b2f(g0.x & 0xFFFFu) + bf.x))))));
    float m0y = fmaf(a00, w0.y, fmaf(a01, w1.y, fmaf(a02, w2.y, fmaf(a03, w3.y, fmaf(a04, w4.y, fmaf(a05, w5.y, b2f(g0.x >> 16) + bf.y))))));
    float m0z = fmaf(a00, w0.z, fmaf(a01, w1.z, fmaf(a02, w2.z, fmaf(a03, w3.z, fmaf(a04, w4.z, fmaf(a05, w5.z, b2f(g0.y & 0xFFFFu) + bf.z))))));
    float m0w = fmaf(a00, w0.w, fmaf(a01, w1.w, fmaf(a02, w2.w, fmaf(a03, w3.w, fmaf(a04, w4.w, fmaf(a05, w5.w, b2f(g0.y >> 16) + bf.w))))));
    float m1x = fmaf(a10, w0.x, fmaf(a11, w1.x, fmaf(a12, w2.x, fmaf(a13, w3.x, fmaf(a14, w4.x, fmaf(a15, w5.x, b2f(g1.x & 0xFFFFu) + bf.x))))));
    float m1y = fmaf(a10, w0.y, fmaf(a11, w1.y, fmaf(a12, w2.y, fmaf(a13, w3.y, fmaf(a14, w4.y, fmaf(a15, w5.y, b2f(g1.x >> 16) + bf.y))))));
    float m1z = fmaf(a10, w0.z, fmaf(a11, w1.z, fmaf(a12, w2.z, fmaf(a13, w3.z, fmaf(a14, w4.z, fmaf(a15, w5.z, b2f(g1.y & 0xFFFFu) + bf.z))))));
    float m1w = fmaf(a10, w0.w, fmaf(a11, w1.w, fmaf(a12, w2.w, fmaf(a13, w3.w, fmaf(a14, w4.w, fmaf(a15, w5.w, b2f(g1.y >> 16) + bf.w))))));
    ax += (m0x > 0.f ? m0x : 0.f) + (m1x > 0.f ? m1x : 0.f);
    ay += (m0y > 0.f ? m0y : 0.f) + (m1y > 0.f ? m1y : 0.f);
    az += (m0z > 0.f ? m0z : 0.f) + (m1z > 0.f ? m1z : 0.f);
    aw += (m0w > 0.f ? m0w : 0.f) + (m1w > 0.f ? m1w : 0.f);
  }
  if (j < en) {
    uint4 e0 = csr[j];
    uint2 g0 = *(const uint2*)(hb + (size_t)(int)e0.w * 256 + c0);
    float a00 = b2f(e0.x & 0xFFFFu), a01 = b2f(e0.x >> 16), a02 = b2f(e0.y & 0xFFFFu);
    float a03 = b2f(e0.y >> 16), a04 = b2f(e0.z & 0xFFFFu), a05 = b2f(e0.z >> 16);
    float m0x = fmaf(a00, w0.x, fmaf(a01, w1.x, fmaf(a02, w2.x, fmaf(a03, w3.x, fmaf(a04, w4.x, fmaf(a05, w5.x, b2f(g0.x & 0xFFFFu) + bf.x))))));
    float m0y = fmaf(a00, w0.y, fmaf(a01, w1.y, fmaf(a02, w2.y, fmaf(a03, w3.y, fmaf(a04, w4.y, fmaf(a05, w5.y, b2f(g0.x >> 16) + bf.y))))));
    float m0z = fmaf(a00, w0.z, fmaf(a01, w1.z, fmaf(a02, w2.z, fmaf(a03, w3.z, fmaf(a04, w4.z, fmaf(a05, w5.z, b2f(g0.y & 0xFFFFu) + bf.z))))));
    float m0w = fmaf(a00, w0.w, fmaf(a01, w1.w, fmaf(a02, w2.w, fmaf(a03, w3.w, fmaf(a04, w4.w, fmaf(a05, w5.w, b2f(g0.y >> 16) + bf.w))))));
    ax += m0x > 0.f ? m0x : 0.f;
    ay += m0y > 0.f ? m0y : 0.f;
    az += m0z > 0.f ? m0z : 0.f;
    aw += m0w > 0.f ? m0w : 0.f;
  }
  uint2 o;
  o.x = (unsigned int)f2b(ax) | ((unsigned int)f2b(ay) << 16);
  o.y = (unsigned int)f2b(az) | ((unsigned int)f2b(aw) << 16);
  *(uint2*)(zb + (size_t)v * 256 + c0) = o;
}

// Fused MLP: z = relu(zin@W1+b1)@W2+b2 for a 64-row tile.
// 4 waves: wave w -> rows (w&1)*32..+32, cols (w>>1)*128..+128. t1 in 32 KB LDS (bf16, XOR-swizzled).
// 64-row tile (vs 128): halves LDS + acc regs -> 4 blocks/CU resident (was 2) for latency hiding.
__global__ __launch_bounds__(256, 4) void k_mlp(const unsigned short* __restrict__ A,
                                                const unsigned short* __restrict__ W1p,
                                                const float* __restrict__ b1,
                                                const unsigned short* __restrict__ W2p,
                                                const float* __restrict__ b2,
                                                float* __restrict__ Z, int M) {
  __shared__ unsigned short t1s[64 * 256];  // 32 KB
  int l = threadIdx.x & 63;
  int w = threadIdx.x >> 6;
  int mloc = l & 15, q = l >> 4;
  int rowg = (w & 1) * 32;
  int colh = (w >> 1) * 128;
  int row0 = blockIdx.x * 64;

  const unsigned short* ap[2];
#pragma unroll
  for (int rt = 0; rt < 2; ++rt) {
    int r = row0 + rowg + rt * 16 + mloc;
    if (r > M - 1) r = M - 1;
    ap[rt] = A + (size_t)r * 256 + q * 8;
  }
  f32x4 acc[2][8];
#pragma unroll
  for (int rt = 0; rt < 2; ++rt)
#pragma unroll
    for (int ct = 0; ct < 8; ++ct) acc[rt][ct] = (f32x4){0.f, 0.f, 0.f, 0.f};

  const unsigned short* w1base = W1p + ((size_t)(colh >> 7)) * 32768 + (size_t)l * 8;
#pragma unroll
  for (int ks = 0; ks < 8; ++ks) {
    s16x8 a0 = *(const s16x8*)(ap[0] + ks * 32);
    s16x8 a1 = *(const s16x8*)(ap[1] + ks * 32);
#pragma unroll
    for (int ct = 0; ct < 8; ++ct) {
      s16x8 b = *(const s16x8*)(w1base + ks * 4096 + ct * 512);
      acc[0][ct] = __builtin_amdgcn_mfma_f32_16x16x32_bf16(a0, b, acc[0][ct], 0, 0, 0);
      acc[1][ct] = __builtin_amdgcn_mfma_f32_16x16x32_bf16(a1, b, acc[1][ct], 0, 0, 0);
    }
  }
  // epilogue 1: bias+relu -> LDS bf16 (XOR swizzle on 16-B chunks)
#pragma unroll
  for (int ct = 0; ct < 8; ++ct) {
    int col = colh + ct * 16 + mloc;
    float bv = b1[col];
    int cc = col >> 3, pos = col & 7;
#pragma unroll
    for (int rt = 0; rt < 2; ++rt)
#pragma unroll
      for (int r = 0; r < 4; ++r) {
        int row = rowg + rt * 16 + q * 4 + r;
        float v = acc[rt][ct][r] + bv;
        v = v > 0.f ? v : 0.f;
        t1s[row * 256 + ((cc ^ (row & 31)) << 3) + pos] = f2b(v);
      }
  }
  __syncthreads();
  // GEMM2: A from LDS
#pragma unroll
  for (int rt = 0; rt < 2; ++rt)
#pragma unroll
    for (int ct = 0; ct < 8; ++ct) acc[rt][ct] = (f32x4){0.f, 0.f, 0.f, 0.f};
  const unsigned short* w2base = W2p + ((size_t)(colh >> 7)) * 32768 + (size_t)l * 8;
#pragma unroll
  for (int ks = 0; ks < 8; ++ks) {
    s16x8 a[2];
#pragma unroll
    for (int rt = 0; rt < 2; ++rt) {
      int row = rowg + rt * 16 + mloc;
      int cc = (q + ks * 4) ^ (row & 31);
      a[rt] = *(const s16x8*)(t1s + row * 256 + (cc << 3));
    }
#pragma unroll
    for (int ct = 0; ct < 8; ++ct) {
      s16x8 b = *(const s16x8*)(w2base + ks * 4096 + ct * 512);
      acc[0][ct] = __builtin_amdgcn_mfma_f32_16x16x32_bf16(a[0], b, acc[0][ct], 0, 0, 0);
      acc[1][ct] = __builtin_amdgcn_mfma_f32_16x16x32_bf16(a[1], b, acc[1][ct], 0, 0, 0);
    }
  }
  // epilogue 2: bias -> fp32 Z
#pragma unroll
  for (int ct = 0; ct < 8; ++ct) {
    int col = colh + ct * 16 + mloc;
    float bv = b2[col];
#pragma unroll
    for (int rt = 0; rt < 2; ++rt)
#pragma unroll
      for (int r = 0; r < 4; ++r) {
        int grow = row0 + rowg + rt * 16 + q * 4 + r;
        if (grow < M) Z[(size_t)grow * 256 + col] = acc[rt][ct][r] + bv;
      }
  }
}

// attention: score[row] = tanh(h@W1+b1) @ w2 + b2 — fused
__global__ __launch_bounds__(256) void k_att(const unsigned short* __restrict__ A,
                                             const unsigned short* __restrict__ Bp,
                                             const float* __restrict__ b1,
                                             const float* __restrict__ w2,
                                             const float* __restrict__ b2,
                                             float* __restrict__ scores, int M) {
  int l = threadIdx.x & 63;
  int w = threadIdx.x >> 6;
  int mloc = l & 15, q = l >> 4;
  int row0 = blockIdx.x * 128 + w * 32;

  int r0 = row0 + mloc;      if (r0 > M - 1) r0 = M - 1;
  int r1 = row0 + 16 + mloc; if (r1 > M - 1) r1 = M - 1;
  const unsigned short* ap0 = A + (size_t)r0 * 256 + q * 8;
  const unsigned short* ap1 = A + (size_t)r1 * 256 + q * 8;
  const unsigned short* bp = Bp + (size_t)l * 8;

  f32x4 acc[2][8];
#pragma unroll
  for (int rt = 0; rt < 2; ++rt)
#pragma unroll
    for (int ct = 0; ct < 8; ++ct) acc[rt][ct] = (f32x4){0.f, 0.f, 0.f, 0.f};
#pragma unroll
  for (int ks = 0; ks < 8; ++ks) {
    s16x8 a0 = *(const s16x8*)(ap0 + ks * 32);
    s16x8 a1 = *(const s16x8*)(ap1 + ks * 32);
#pragma unroll
    for (int ct = 0; ct < 8; ++ct) {
      s16x8 b = *(const s16x8*)(bp + ks * 4096 + ct * 512);
      acc[0][ct] = __builtin_amdgcn_mfma_f32_16x16x32_bf16(a0, b, acc[0][ct], 0, 0, 0);
      acc[1][ct] = __builtin_amdgcn_mfma_f32_16x16x32_bf16(a1, b, acc[1][ct], 0, 0, 0);
    }
  }
  float bv[8], wv[8];
#pragma unroll
  for (int ct = 0; ct < 8; ++ct) {
    bv[ct] = b1[ct * 16 + mloc];
    wv[ct] = w2[ct * 16 + mloc];
  }
  float b2v = b2[0];
#pragma unroll
  for (int rt = 0; rt < 2; ++rt)
#pragma unroll
    for (int r = 0; r < 4; ++r) {
      float p = 0.0f;
#pragma unroll
      for (int ct = 0; ct < 8; ++ct) p = fmaf(tanhf(acc[rt][ct][r] + bv[ct]), wv[ct], p);
      p += __shfl_xor(p, 1, 64);
      p += __shfl_xor(p, 2, 64);
      p += __shfl_xor(p, 4, 64);
      p += __shfl_xor(p, 8, 64);
      int row = row0 + rt * 16 + q * 4 + r;
      if (mloc == 0 && row < M) scores[row] = p + b2v;
    }
}

// per-graph per-column S1/S2 of z — one block per graph, no atomics
__global__ __launch_bounds__(256) void k_stats(const float* __restrict__ z, const int* __restrict__ gstart,
                                               const int* __restrict__ cnti,
                                               float* __restrict__ S1, float* __restrict__ S2) {
  int g = blockIdx.x, c = threadIdx.x;
  int r0 = gstart[g], r1 = r0 + cnti[g];
  float s1 = 0.0f, s2 = 0.0f;
  for (int r = r0; r < r1; ++r) {
    float v = z[(size_t)r * 256 + c];
    s1 += v;
    s2 = fmaf(v, v, s2);
  }
  S1[(size_t)g * 256 + c] = s1;
  S2[(size_t)g * 256 + c] = s2;
}

// column BN stats from per-graph S1/S2: one block per column
__global__ __launch_bounds__(256) void k_bn_fin(const float* __restrict__ S1, const float* __restrict__ S2,
                                                const float* __restrict__ gamma, const float* __restrict__ beta,
                                                float* __restrict__ abuf, float* __restrict__ bbuf, int n) {
  __shared__ float r1[256], r2[256];
  int c = blockIdx.x;
  int t = threadIdx.x;
  float s1 = 0.0f, s2 = 0.0f;
  for (int g = t; g < GG; g += 256) {
    s1 += S1[(size_t)g * 256 + c];
    s2 += S2[(size_t)g * 256 + c];
  }
  r1[t] = s1; r2[t] = s2;
  __syncthreads();
  for (int off = 128; off; off >>= 1) {
    if (t < off) { r1[t] += r1[t + off]; r2[t] += r2[t + off]; }
    __syncthreads();
  }
  if (t == 0) {
    float inv = 1.0f / (float)n;
    float mu = r1[0] * inv;
    float var = r2[0] * inv - mu * mu;
    float rstd = rsqrtf(var + 1e-5f);
    float a = gamma[c] * rstd;
    abuf[c] = a;
    bbuf[c] = beta[c] - mu * a;
  }
}

// per-graph: compute gmean/rinv from S1/S2 in-block, then apply BN+PairNorm+relu.
template <int LAST>
__global__ __launch_bounds__(256) void k_apply(float* __restrict__ z, const float* __restrict__ abuf,
                                               const float* __restrict__ bbuf, const int* __restrict__ gstart,
                                               const int* __restrict__ cnti, const float* __restrict__ cntf,
                                               const float* __restrict__ S1, const float* __restrict__ S2,
                                               unsigned short* __restrict__ hb) {
  __shared__ float rT[256], rM[256];
  int g = blockIdx.x, c = threadIdx.x;
  float a = abuf[c], b = bbuf[c];
  float s1 = S1[(size_t)g * 256 + c];
  float s2 = S2[(size_t)g * 256 + c];
  float nr = (float)cnti[g];
  float ic = 1.0f / cntf[g];
  float mean = (a * s1 + nr * b) * ic;
  float term = fmaf(a * a, s2, fmaf(2.0f * a * b, s1, nr * b * b));
  rT[c] = term;
  rM[c] = mean * mean;
  __syncthreads();
  for (int off = 128; off; off >>= 1) {
    if (c < off) { rT[c] += rT[c + off]; rM[c] += rM[c + off]; }
    __syncthreads();
  }
  float cr = nr > 0.0f ? 1.0f : 0.0f;
  float rinv = rsqrtf(1e-5f + rT[0] * ic - cr * rM[0]);
  int r0 = gstart[g], r1 = r0 + cnti[g];
  for (int r = r0; r < r1; ++r) {
    float v = (fmaf(a, z[(size_t)r * 256 + c], b) - mean) * rinv;
    v = v > 0.0f ? v : 0.0f;
    hb[(size_t)r * 256 + c] = f2b(v);
    if (LAST) z[(size_t)r * 256 + c] = v;
  }
}

// per-graph fused pooling + output
__global__ __launch_bounds__(256) void k_poolout(const float* __restrict__ h, const float* __restrict__ scores,
                                                 const int* __restrict__ gstart, const int* __restrict__ cnti,
                                                 const float* __restrict__ cntf, float* __restrict__ out) {
  int g = blockIdx.x, c = threadIdx.x;
  int r0 = gstart[g], r1 = r0 + cnti[g];
  float ma = 0.0f, aa = 0.0f, mx = 0.0f, wa = 0.0f;
  for (int r = r0; r < r1; ++r) {
    float wgt = __expf(scores[r]);
    float hv = h[(size_t)r * 256 + c];
    ma += hv;
    aa = fmaf(hv, wgt, aa);
    mx = fmaxf(mx, hv);
    wa += wgt;
  }
  out[(size_t)g * 768 + c] = ma / cntf[g];
  out[(size_t)g * 768 + 256 + c] = mx;
  out[(size_t)g * 768 + 512 + c] = aa / (wa + 1e-8f);
}

extern "C" void kernel_launch(void* const* d_in, const int* in_sizes, int n_in,
                              void* d_out, int out_size, void* d_ws, size_t ws_size,
                              hipStream_t stream) {
  const float* x         = (const float*)d_in[0];
  const float* edge_attr = (const float*)d_in[1];
  const float* node_w    = (const float*)d_in[2];
  const float* node_b    = (const float*)d_in[3];
  const float* edge_w    = (const float*)d_in[4];
  const float* edge_b    = (const float*)d_in[5];
  const float* conv_w    = (const float*)d_in[6];
  const float* conv_b    = (const float*)d_in[7];
  const float* mlp_w1    = (const float*)d_in[8];
  const float* mlp_b1    = (const float*)d_in[9];
  const float* mlp_w2    = (const float*)d_in[10];
  const float* mlp_b2    = (const float*)d_in[11];
  const float* eps       = (const float*)d_in[12];
  const float* bn_gamma  = (const float*)d_in[13];
  const float* bn_beta   = (const float*)d_in[14];
  const float* att_w1    = (const float*)d_in[15];
  const float* att_b1    = (const float*)d_in[16];
  const float* att_w2    = (const float*)d_in[17];
  const float* att_b2    = (const float*)d_in[18];
  const int*   eidx      = (const int*)d_in[19];
  const int*   batch     = (const int*)d_in[20];
  float* out = (float*)d_out;
  float* ws  = (float*)d_ws;

  float*          zbuf = ws + O_Z;
  unsigned short* zb   = (unsigned short*)(ws + O_ZB);
  unsigned short* hb   = (unsigned short*)(ws + O_HB);
  float* S1    = ws + O_S1;
  float* S2    = ws + O_S2;
  float* abuf  = ws + O_ABUF;
  float* bbuf  = ws + O_BBUF;
  int*   cnti  = (int*)(ws + O_CNTI);
  float* cntf  = ws + O_CNTF;
  float* scor  = ws + O_SCOR;
  int*   curs  = (int*)(ws + O_SCOR);
  float* weff  = ws + O_WEFF;
  float* beff  = ws + O_BEFF;
  int*   deg   = (int*)(ws + O_DEG);
  int*   strt  = (int*)(ws + O_STRT);
  int*   bsum  = (int*)(ws + O_BSUM);
  uint4* csr   = (uint4*)(ws + O_CSR);
  unsigned short* w1p = (unsigned short*)(ws + O_W1P);
  unsigned short* w2p = (unsigned short*)(ws + O_W2P);
  unsigned short* atp = (unsigned short*)(ws + O_ATP);
  int*   gst   = (int*)(ws + O_GST);
  const int* esrc = eidx;
  const int* edst = eidx + EE;

  // graph counts + offsets
  k_zero<<<8, 256, 0, stream>>>((float*)cnti, GG);
  k_count<<<(NN + 255) / 256, 256, 0, stream>>>(batch, cnti, NN);
  k_gscan<<<1, 256, 0, stream>>>(cnti, gst, cntf);

  // fused edge weights + node embedding + weight packing
  k_wfuse<<<LL, 256, 0, stream>>>(edge_w, edge_b, conv_w, conv_b, weff, beff);
  k_node_embed<<<(NN + 15) / 16, 256, 0, stream>>>(x, node_w, node_b, hb, NN);
  k_pack_all<<<528, 256, 0, stream>>>(mlp_w1, mlp_w2, att_w1, w1p, w2p, atp);

  // CSR build (by dst)
  const int nscan = (NN + 255) / 256;  // 391
  k_zero<<<256, 256, 0, stream>>>((float*)deg, NN);
  k_deg<<<(EE + 255) / 256, 256, 0, stream>>>(edst, deg, EE);
  k_scan_part<<<nscan, 256, 0, stream>>>(deg, strt, bsum, NN);
  k_scan_top<<<1, 512, 0, stream>>>(bsum, nscan);
  k_scan_add<<<nscan, 256, 0, stream>>>(strt, bsum, curs, NN);
  k_fill<<<(EE + 255) / 256, 256, 0, stream>>>(edge_attr, esrc, edst, curs, csr, EE);

  const int mtiles64  = (NN + 63) / 64;    // 1563
  const int mtiles128 = (NN + 127) / 128;  // 782

  for (int i = 0; i < LL; ++i) {
    k_edge_csr<<<NN / 4, 256, 0, stream>>>(csr, strt, deg, weff + (size_t)i * 1536,
                                           beff + (size_t)i * 256, hb, zb, eps, i, NN);
    k_mlp<<<mtiles64, 256, 0, stream>>>(zb, w1p + (size_t)i * 65536, mlp_b1 + (size_t)i * 256,
                                        w2p + (size_t)i * 65536, mlp_b2 + (size_t)i * 256, zbuf, NN);
    k_stats<<<GG, 256, 0, stream>>>(zbuf, gst, cnti, S1, S2);
    k_bn_fin<<<256, 256, 0, stream>>>(S1, S2, bn_gamma + (size_t)i * 256, bn_beta + (size_t)i * 256,
                                      abuf, bbuf, NN);
    if (i == LL - 1)
      k_apply<1><<<GG, 256, 0, stream>>>(zbuf, abuf, bbuf, gst, cnti, cntf, S1, S2, hb);
    else
      k_apply<0><<<GG, 256, 0, stream>>>(zbuf, abuf, bbuf, gst, cnti, cntf, S1, S2, hb);
  }

  // pooling (zbuf holds fp32 h)
  k_att<<<mtiles128, 256, 0, stream>>>(hb, atp, att_b1, att_w2, att_b2, scor, NN);
  k_poolout<<<GG, 256, 0, stream>>>(zbuf, scor, gst, cnti, cntf, out);
}

// Round 8
// 1809.643 us; speedup vs baseline: 7.0614x; 1.1455x over previous
//
#include <hip/hip_runtime.h>
#include <cstdint>
#include <cstddef>

// Problem constants (fixed instance)
#define NN 100000
#define EE 320000
#define GG 2048
#define LL 8

// Workspace layout (float offsets).
#define O_Z    0ull                      // [N,256] fp32 z; h fp32 (in-place) after last apply
#define O_ZB   25600000ull               // [N,256] bf16 zin
#define O_HB   38400000ull               // [N,256] bf16 h
#define O_S1   51200000ull               // [G,256] S1
#define O_S2   (O_S1 + 524288ull)        // [G,256] S2
#define O_ABUF (O_S2 + 524288ull)        // [256]
#define O_BBUF (O_ABUF + 256ull)         // [256]
#define O_CNTI (O_BBUF + 256ull)         // [G] int
#define O_CNTF (O_CNTI + 2048ull)        // [G]
#define O_SCOR (O_CNTF + 2048ull)        // [N] scores (CSR cursor during setup)
#define O_WEFF (O_SCOR + 100000ull)      // [L,6,256]
#define O_BEFF (O_WEFF + 12288ull)       // [L,256]
#define O_DEG  (O_BEFF + 2048ull)        // [N] int
#define O_STRT (O_DEG + 100000ull)       // [N] int
#define O_BSUM (O_STRT + 100000ull)      // [512] int
#define O_CSR  (O_BSUM + 512ull)         // [E] x 16 B: 6 bf16 attrs + int src
#define O_W1P  (O_CSR + 1280000ull)      // 8 x 65536 bf16 = 262144 floats
#define O_W2P  (O_W1P + 262144ull)
#define O_ATP  (O_W2P + 262144ull)       // 32768 shorts = 16384 floats
#define O_GST  (O_ATP + 16384ull)        // [G] int gstart

typedef short s16x8 __attribute__((ext_vector_type(8)));
typedef float f32x4 __attribute__((ext_vector_type(4)));

__device__ inline float b2f(unsigned int lo16) {
  union { float f; unsigned int u; } x; x.u = lo16 << 16; return x.f;
}
__device__ inline unsigned short f2b(float f) {
  union { float f; unsigned int u; } x; x.f = f;
  unsigned int r = x.u + 0x7FFFu + ((x.u >> 16) & 1u);
  return (unsigned short)(r >> 16);
}

__global__ __launch_bounds__(256) void k_zero(float* __restrict__ p, int n) {
  int i = blockIdx.x * 256 + threadIdx.x;
  int stride = gridDim.x * 256;
  for (; i < n; i += stride) p[i] = 0.0f;
}

__global__ __launch_bounds__(256) void k_count(const int* __restrict__ batch, int* __restrict__ cnti, int n) {
  int i = blockIdx.x * 256 + threadIdx.x;
  if (i < n) atomicAdd(&cnti[batch[i]], 1);
}

// single-block scan over G=2048 counts -> gstart (exclusive), cntf (clamped)
__global__ __launch_bounds__(256) void k_gscan(const int* __restrict__ cnti, int* __restrict__ gstart,
                                               float* __restrict__ cntf) {
  __shared__ int part[256];
  int t = threadIdx.x;
  int base = t * 8;
  int loc[8];
  int s = 0;
#pragma unroll
  for (int i = 0; i < 8; ++i) { loc[i] = s; s += cnti[base + i]; }
  part[t] = s;
  __syncthreads();
  for (int off = 1; off < 256; off <<= 1) {
    int u = (t >= off) ? part[t - off] : 0;
    __syncthreads();
    part[t] += u;
    __syncthreads();
  }
  int p = (t > 0) ? part[t - 1] : 0;
#pragma unroll
  for (int i = 0; i < 8; ++i) {
    gstart[base + i] = p + loc[i];
    float v = (float)cnti[base + i];
    cntf[base + i] = v > 1.0f ? v : 1.0f;
  }
}

// ---------------- CSR build ----------------
__global__ __launch_bounds__(256) void k_deg(const int* __restrict__ edst, int* __restrict__ deg, int ne) {
  int e = blockIdx.x * 256 + threadIdx.x;
  if (e < ne) atomicAdd(&deg[edst[e]], 1);
}

__global__ __launch_bounds__(256) void k_scan_part(const int* __restrict__ deg, int* __restrict__ start,
                                                   int* __restrict__ bsum, int n) {
  __shared__ int s[256];
  int i = blockIdx.x * 256 + threadIdx.x;
  int t = threadIdx.x;
  int v = (i < n) ? deg[i] : 0;
  s[t] = v;
  __syncthreads();
  for (int off = 1; off < 256; off <<= 1) {
    int u = (t >= off) ? s[t - off] : 0;
    __syncthreads();
    s[t] += u;
    __syncthreads();
  }
  if (i < n) start[i] = s[t] - v;
  if (t == 255) bsum[blockIdx.x] = s[255];
}

__global__ __launch_bounds__(512) void k_scan_top(int* __restrict__ bsum, int nb) {
  __shared__ int s[512];
  int t = threadIdx.x;
  int v = (t < nb) ? bsum[t] : 0;
  s[t] = v;
  __syncthreads();
  for (int off = 1; off < 512; off <<= 1) {
    int u = (t >= off) ? s[t - off] : 0;
    __syncthreads();
    s[t] += u;
    __syncthreads();
  }
  if (t < nb) bsum[t] = s[t] - v;
}

__global__ __launch_bounds__(256) void k_scan_add(int* __restrict__ start, const int* __restrict__ bsum,
                                                  int* __restrict__ cursor, int n) {
  int i = blockIdx.x * 256 + threadIdx.x;
  if (i < n) {
    int v = start[i] + bsum[blockIdx.x];
    start[i] = v;
    cursor[i] = v;
  }
}

// CSR entry: uint4 = {attr0|attr1<<16, attr2|attr3<<16, attr4|attr5<<16, src}
__global__ __launch_bounds__(256) void k_fill(const float* __restrict__ ea, const int* __restrict__ esrc,
                                              const int* __restrict__ edst, int* __restrict__ cursor,
                                              uint4* __restrict__ csr, int ne) {
  int e = blockIdx.x * 256 + threadIdx.x;
  if (e >= ne) return;
  int d = edst[e];
  int slot = atomicAdd(&cursor[d], 1);
  const float* ap = ea + (size_t)e * 6;
  uint4 v;
  v.x = (unsigned int)f2b(ap[0]) | ((unsigned int)f2b(ap[1]) << 16);
  v.y = (unsigned int)f2b(ap[2]) | ((unsigned int)f2b(ap[3]) << 16);
  v.z = (unsigned int)f2b(ap[4]) | ((unsigned int)f2b(ap[5]) << 16);
  v.w = (unsigned int)esrc[e];
  csr[slot] = v;
}

// W_eff[i] = edge_w @ conv_w[i]; b_eff[i] = edge_b @ conv_w[i] + conv_b[i]
__global__ __launch_bounds__(256) void k_wfuse(const float* __restrict__ edge_w, const float* __restrict__ edge_b,
                                               const float* __restrict__ conv_w, const float* __restrict__ conv_b,
                                               float* __restrict__ wef, float* __restrict__ bef) {
  __shared__ float ew[6 * 128 + 128];
  int i = blockIdx.x;
  int c = threadIdx.x;
  for (int idx = c; idx < 896; idx += 256)
    ew[idx] = idx < 768 ? edge_w[idx] : edge_b[idx - 768];
  __syncthreads();
  float acc[7] = {0.f, 0.f, 0.f, 0.f, 0.f, 0.f, 0.f};
  const float* cw = conv_w + (size_t)i * 32768 + c;
  for (int j = 0; j < 128; ++j) {
    float w = cw[(size_t)j * 256];
#pragma unroll
    for (int k = 0; k < 6; ++k) acc[k] = fmaf(ew[k * 128 + j], w, acc[k]);
    acc[6] = fmaf(ew[768 + j], w, acc[6]);
  }
#pragma unroll
  for (int k = 0; k < 6; ++k) wef[(size_t)i * 1536 + k * 256 + c] = acc[k];
  bef[(size_t)i * 256 + c] = acc[6] + conv_b[(size_t)i * 256 + c];
}

// pack ALL weights to MFMA B-fragment order in one launch.
__global__ __launch_bounds__(256) void k_pack_all(const float* __restrict__ mw1, const float* __restrict__ mw2,
                                                  const float* __restrict__ aw1,
                                                  unsigned short* __restrict__ w1p,
                                                  unsigned short* __restrict__ w2p,
                                                  unsigned short* __restrict__ atp) {
  int id = blockIdx.x * 256 + threadIdx.x;   // 33*4096 total
  int cbu = id >> 12;
  if (cbu >= 33) return;
  int lid = id & 4095;
  int l = lid & 63;
  int ct = (lid >> 6) & 7;
  int ks = (lid >> 9) & 7;
  const float* B;
  unsigned short* Bp;
  int ldb, cb;
  if (cbu < 32) {
    int m = cbu >> 1;
    cb = cbu & 1;
    ldb = 256;
    if (m < 8) { B = mw1 + (size_t)m * 65536; Bp = w1p + (size_t)m * 65536; }
    else       { B = mw2 + (size_t)(m - 8) * 65536; Bp = w2p + (size_t)(m - 8) * 65536; }
  } else {
    B = aw1; Bp = atp; ldb = 128; cb = 0;
  }
  int n = cb * 128 + ct * 16 + (l & 15);
  int k0 = ks * 32 + (l >> 4) * 8;
  unsigned short* dst = Bp + (((size_t)cb << 12) | (size_t)lid) * 8;
#pragma unroll
  for (int j = 0; j < 8; ++j) dst[j] = f2b(B[(size_t)(k0 + j) * ldb + n]);
}

// hb = bf16(x @ node_w + node_b)
__global__ __launch_bounds__(256) void k_node_embed(const float* __restrict__ x, const float* __restrict__ w,
                                                    const float* __restrict__ b, unsigned short* __restrict__ hb,
                                                    int n) {
  __shared__ float xs[16 * 48];
  int tid = threadIdx.x;
  int row0 = blockIdx.x * 16;
  for (int idx = tid; idx < 16 * 48; idx += 256) {
    int r = idx / 48, c = idx - r * 48;
    int gr = row0 + r; if (gr >= n) gr = n - 1;
    xs[idx] = x[(size_t)gr * 48 + c];
  }
  __syncthreads();
  float acc[16];
#pragma unroll
  for (int r = 0; r < 16; ++r) acc[r] = 0.0f;
  for (int k = 0; k < 48; ++k) {
    float wv = w[k * 256 + tid];
#pragma unroll
    for (int r = 0; r < 16; ++r) acc[r] = fmaf(xs[r * 48 + k], wv, acc[r]);
  }
  float bb = b[tid];
#pragma unroll
  for (int r = 0; r < 16; ++r) {
    int gr = row0 + r;
    if (gr < n) hb[(size_t)gr * 256 + tid] = f2b(acc[r] + bb);
  }
}

// zin_b[v] = bf16((1+eps)h[v] + sum relu(h[src]+ea@W_eff+b_eff))
// ONE WAVE = 4 NODES interleaved: per iteration 4 independent CSR-load -> gather chains (4x MLP),
// wave-uniform predication (no divergence). 16 nodes per 256-thread block.
__global__ __launch_bounds__(256) void k_edge_csr(const uint4* __restrict__ csr,
                                                  const int* __restrict__ startv, const int* __restrict__ degv,
                                                  const float* __restrict__ wef, const float* __restrict__ bef,
                                                  const unsigned short* __restrict__ hb,
                                                  unsigned short* __restrict__ zb,
                                                  const float* __restrict__ eps, int layer, int n) {
  int lane = threadIdx.x & 63;
  int wv = threadIdx.x >> 6;
  int v0 = (blockIdx.x * 4 + wv) * 4;
  if (v0 >= n) return;
  int c0 = lane * 4;
  float4 w0 = *(const float4*)(wef + 0 * 256 + c0);
  float4 w1 = *(const float4*)(wef + 1 * 256 + c0);
  float4 w2 = *(const float4*)(wef + 2 * 256 + c0);
  float4 w3 = *(const float4*)(wef + 3 * 256 + c0);
  float4 w4 = *(const float4*)(wef + 4 * 256 + c0);
  float4 w5 = *(const float4*)(wef + 5 * 256 + c0);
  float4 bf = *(const float4*)(bef + c0);
  float s = 1.0f + eps[layer];

  int dg[4], pp[4];
  float4 acc[4];
#pragma unroll
  for (int k = 0; k < 4; ++k) {
    int v = v0 + k;
    dg[k] = degv[v];
    int st = startv[v];
    pp[k] = st < (EE - 1) ? st : (EE - 1);
    uint2 hu = *(const uint2*)(hb + (size_t)v * 256 + c0);
    acc[k].x = s * b2f(hu.x & 0xFFFFu);
    acc[k].y = s * b2f(hu.x >> 16);
    acc[k].z = s * b2f(hu.y & 0xFFFFu);
    acc[k].w = s * b2f(hu.y >> 16);
  }
  int mx = dg[0] > dg[1] ? dg[0] : dg[1];
  int mx2 = dg[2] > dg[3] ? dg[2] : dg[3];
  if (mx2 > mx) mx = mx2;

  for (int t = 0; t < mx; ++t) {
    uint4 e[4];
#pragma unroll
    for (int k = 0; k < 4; ++k) e[k] = csr[pp[k]];
    uint2 g[4];
#pragma unroll
    for (int k = 0; k < 4; ++k) g[k] = *(const uint2*)(hb + (size_t)(int)e[k].w * 256 + c0);
#pragma unroll
    for (int k = 0; k < 4; ++k) {
      if (t < dg[k]) {
        float a0 = b2f(e[k].x & 0xFFFFu), a1 = b2f(e[k].x >> 16), a2 = b2f(e[k].y & 0xFFFFu);
        float a3 = b2f(e[k].y >> 16), a4 = b2f(e[k].z & 0xFFFFu), a5 = b2f(e[k].z >> 16);
        float mxv = fmaf(a0, w0.x, fmaf(a1, w1.x, fmaf(a2, w2.x, fmaf(a3, w3.x, fmaf(a4, w4.x, fmaf(a5, w5.x, b2f(g[k].x & 0xFFFFu) + bf.x))))));
        float myv = fmaf(a0, w0.y, fmaf(a1, w1.y, fmaf(a2, w2.y, fmaf(a3, w3.y, fmaf(a4, w4.y, fmaf(a5, w5.y, b2f(g[k].x >> 16) + bf.y))))));
        float mzv = fmaf(a0, w0.z, fmaf(a1, w1.z, fmaf(a2, w2.z, fmaf(a3, w3.z, fmaf(a4, w4.z, fmaf(a5, w5.z, b2f(g[k].y & 0xFFFFu) + bf.z))))));
        float mwv = fmaf(a0, w0.w, fmaf(a1, w1.w, fmaf(a2, w2.w, fmaf(a3, w3.w, fmaf(a4, w4.w, fmaf(a5, w5.w, b2f(g[k].y >> 16) + bf.w))))));
        acc[k].x += mxv > 0.f ? mxv : 0.f;
        acc[k].y += myv > 0.f ? myv : 0.f;
        acc[k].z += mzv > 0.f ? mzv : 0.f;
        acc[k].w += mwv > 0.f ? mwv : 0.f;
      }
      pp[k] += (t < dg[k] - 1) ? 1 : 0;
    }
  }
#pragma unroll
  for (int k = 0; k < 4; ++k) {
    uint2 o;
    o.x = (unsigned int)f2b(acc[k].x) | ((unsigned int)f2b(acc[k].y) << 16);
    o.y = (unsigned int)f2b(acc[k].z) | ((unsigned int)f2b(acc[k].w) << 16);
    *(uint2*)(zb + (size_t)(v0 + k) * 256 + c0) = o;
  }
}

// Fused MLP: z = relu(zin@W1+b1)@W2+b2 for a 64-row tile.
// 4 waves: wave w -> rows (w&1)*32..+32, cols (w>>1)*128..+128. t1 in LDS (bf16, XOR-swizzled).
// Epilogue 2 bounces C through LDS (reusing t1 space) so HBM writes are full coalesced rows.
__global__ __launch_bounds__(256, 4) void k_mlp(const unsigned short* __restrict__ A,
                                                const unsigned short* __restrict__ W1p,
                                                const float* __restrict__ b1,
                                                const unsigned short* __restrict__ W2p,
                                                const float* __restrict__ b2,
                                                float* __restrict__ Z, int M) {
  __shared__ __align__(16) unsigned char smem[33024];        // max(64*256*2, 32*258*4)
  unsigned short* t1s = (unsigned short*)smem;
  float* zc = (float*)smem;                                  // 32 x (stride 258) fp32
  int l = threadIdx.x & 63;
  int w = threadIdx.x >> 6;
  int mloc = l & 15, q = l >> 4;
  int rowg = (w & 1) * 32;
  int colh = (w >> 1) * 128;
  int row0 = blockIdx.x * 64;

  const unsigned short* ap[2];
#pragma unroll
  for (int rt = 0; rt < 2; ++rt) {
    int r = row0 + rowg + rt * 16 + mloc;
    if (r > M - 1) r = M - 1;
    ap[rt] = A + (size_t)r * 256 + q * 8;
  }
  f32x4 acc[2][8];
#pragma unroll
  for (int rt = 0; rt < 2; ++rt)
#pragma unroll
    for (int ct = 0; ct < 8; ++ct) acc[rt][ct] = (f32x4){0.f, 0.f, 0.f, 0.f};

  const unsigned short* w1base = W1p + ((size_t)(colh >> 7)) * 32768 + (size_t)l * 8;
#pragma unroll
  for (int ks = 0; ks < 8; ++ks) {
    s16x8 a0 = *(const s16x8*)(ap[0] + ks * 32);
    s16x8 a1 = *(const s16x8*)(ap[1] + ks * 32);
#pragma unroll
    for (int ct = 0; ct < 8; ++ct) {
      s16x8 b = *(const s16x8*)(w1base + ks * 4096 + ct * 512);
      acc[0][ct] = __builtin_amdgcn_mfma_f32_16x16x32_bf16(a0, b, acc[0][ct], 0, 0, 0);
      acc[1][ct] = __builtin_amdgcn_mfma_f32_16x16x32_bf16(a1, b, acc[1][ct], 0, 0, 0);
    }
  }
  // epilogue 1: bias+relu -> LDS bf16 (XOR swizzle on 16-B chunks)
#pragma unroll
  for (int ct = 0; ct < 8; ++ct) {
    int col = colh + ct * 16 + mloc;
    float bv = b1[col];
    int cc = col >> 3, pos = col & 7;
#pragma unroll
    for (int rt = 0; rt < 2; ++rt)
#pragma unroll
      for (int r = 0; r < 4; ++r) {
        int row = rowg + rt * 16 + q * 4 + r;
        float v = acc[rt][ct][r] + bv;
        v = v > 0.f ? v : 0.f;
        t1s[row * 256 + ((cc ^ (row & 31)) << 3) + pos] = f2b(v);
      }
  }
  __syncthreads();
  // GEMM2: A from LDS
#pragma unroll
  for (int rt = 0; rt < 2; ++rt)
#pragma unroll
    for (int ct = 0; ct < 8; ++ct) acc[rt][ct] = (f32x4){0.f, 0.f, 0.f, 0.f};
  const unsigned short* w2base = W2p + ((size_t)(colh >> 7)) * 32768 + (size_t)l * 8;
#pragma unroll
  for (int ks = 0; ks < 8; ++ks) {
    s16x8 a[2];
#pragma unroll
    for (int rt = 0; rt < 2; ++rt) {
      int row = rowg + rt * 16 + mloc;
      int cc = (q + ks * 4) ^ (row & 31);
      a[rt] = *(const s16x8*)(t1s + row * 256 + (cc << 3));
    }
#pragma unroll
    for (int ct = 0; ct < 8; ++ct) {
      s16x8 b = *(const s16x8*)(w2base + ks * 4096 + ct * 512);
      acc[0][ct] = __builtin_amdgcn_mfma_f32_16x16x32_bf16(a[0], b, acc[0][ct], 0, 0, 0);
      acc[1][ct] = __builtin_amdgcn_mfma_f32_16x16x32_bf16(a[1], b, acc[1][ct], 0, 0, 0);
    }
  }
  // bias into registers
  float bv2[8];
#pragma unroll
  for (int ct = 0; ct < 8; ++ct) bv2[ct] = b2[colh + ct * 16 + mloc];

  // epilogue 2: bounce through LDS per 32-row half, then coalesced full-row stores
#pragma unroll
  for (int half = 0; half < 2; ++half) {
    __syncthreads();   // t1s reads done (half 0) / previous copy done (half 1)
    if ((w & 1) == half) {
#pragma unroll
      for (int ct = 0; ct < 8; ++ct) {
        int col = colh + ct * 16 + mloc;
#pragma unroll
        for (int rt = 0; rt < 2; ++rt)
#pragma unroll
          for (int r = 0; r < 4; ++r) {
            int row = rt * 16 + q * 4 + r;               // 0..31 local
            zc[row * 258 + col] = acc[rt][ct][r] + bv2[ct];
          }
      }
    }
    __syncthreads();
    int baserow = row0 + half * 32;
#pragma unroll
    for (int it = 0; it < 8; ++it) {
      int row = it * 4 + w;                               // one row per wave
      int grow = baserow + row;
      float4 vv = *(const float4*)(zc + row * 258 + l * 4);
      if (grow < M) *(float4*)(Z + (size_t)grow * 256 + l * 4) = vv;
    }
  }
}

// attention: score[row] = tanh(h@W1+b1) @ w2 + b2 — fused
__global__ __launch_bounds__(256) void k_att(const unsigned short* __restrict__ A,
                                             const unsigned short* __restrict__ Bp,
                                             const float* __restrict__ b1,
                                             const float* __restrict__ w2,
                                             const float* __restrict__ b2,
                                             float* __restrict__ scores, int M) {
  int l = threadIdx.x & 63;
  int w = threadIdx.x >> 6;
  int mloc = l & 15, q = l >> 4;
  int row0 = blockIdx.x * 128 + w * 32;

  int r0 = row0 + mloc;      if (r0 > M - 1) r0 = M - 1;
  int r1 = row0 + 16 + mloc; if (r1 > M - 1) r1 = M - 1;
  const unsigned short* ap0 = A + (size_t)r0 * 256 + q * 8;
  const unsigned short* ap1 = A + (size_t)r1 * 256 + q * 8;
  const unsigned short* bp = Bp + (size_t)l * 8;

  f32x4 acc[2][8];
#pragma unroll
  for (int rt = 0; rt < 2; ++rt)
#pragma unroll
    for (int ct = 0; ct < 8; ++ct) acc[rt][ct] = (f32x4){0.f, 0.f, 0.f, 0.f};
#pragma unroll
  for (int ks = 0; ks < 8; ++ks) {
    s16x8 a0 = *(const s16x8*)(ap0 + ks * 32);
    s16x8 a1 = *(const s16x8*)(ap1 + ks * 32);
#pragma unroll
    for (int ct = 0; ct < 8; ++ct) {
      s16x8 b = *(const s16x8*)(bp + ks * 4096 + ct * 512);
      acc[0][ct] = __builtin_amdgcn_mfma_f32_16x16x32_bf16(a0, b, acc[0][ct], 0, 0, 0);
      acc[1][ct] = __builtin_amdgcn_mfma_f32_16x16x32_bf16(a1, b, acc[1][ct], 0, 0, 0);
    }
  }
  float bv[8], wv[8];
#pragma unroll
  for (int ct = 0; ct < 8; ++ct) {
    bv[ct] = b1[ct * 16 + mloc];
    wv[ct] = w2[ct * 16 + mloc];
  }
  float b2v = b2[0];
#pragma unroll
  for (int rt = 0; rt < 2; ++rt)
#pragma unroll
    for (int r = 0; r < 4; ++r) {
      float p = 0.0f;
#pragma unroll
      for (int ct = 0; ct < 8; ++ct) p = fmaf(tanhf(acc[rt][ct][r] + bv[ct]), wv[ct], p);
      p += __shfl_xor(p, 1, 64);
      p += __shfl_xor(p, 2, 64);
      p += __shfl_xor(p, 4, 64);
      p += __shfl_xor(p, 8, 64);
      int row = row0 + rt * 16 + q * 4 + r;
      if (mloc == 0 && row < M) scores[row] = p + b2v;
    }
}

// per-graph per-column S1/S2 of z — one block per graph, no atomics
__global__ __launch_bounds__(256) void k_stats(const float* __restrict__ z, const int* __restrict__ gstart,
                                               const int* __restrict__ cnti,
                                               float* __restrict__ S1, float* __restrict__ S2) {
  int g = blockIdx.x, c = threadIdx.x;
  int r0 = gstart[g], r1 = r0 + cnti[g];
  float s1 = 0.0f, s2 = 0.0f;
  for (int r = r0; r < r1; ++r) {
    float v = z[(size_t)r * 256 + c];
    s1 += v;
    s2 = fmaf(v, v, s2);
  }
  S1[(size_t)g * 256 + c] = s1;
  S2[(size_t)g * 256 + c] = s2;
}

// column BN stats from per-graph S1/S2: one block per column
__global__ __launch_bounds__(256) void k_bn_fin(const float* __restrict__ S1, const float* __restrict__ S2,
                                                const float* __restrict__ gamma, const float* __restrict__ beta,
                                                float* __restrict__ abuf, float* __restrict__ bbuf, int n) {
  __shared__ float r1[256], r2[256];
  int c = blockIdx.x;
  int t = threadIdx.x;
  float s1 = 0.0f, s2 = 0.0f;
  for (int g = t; g < GG; g += 256) {
    s1 += S1[(size_t)g * 256 + c];
    s2 += S2[(size_t)g * 256 + c];
  }
  r1[t] = s1; r2[t] = s2;
  __syncthreads();
  for (int off = 128; off; off >>= 1) {
    if (t < off) { r1[t] += r1[t + off]; r2[t] += r2[t + off]; }
    __syncthreads();
  }
  if (t == 0) {
    float inv = 1.0f / (float)n;
    float mu = r1[0] * inv;
    float var = r2[0] * inv - mu * mu;
    float rstd = rsqrtf(var + 1e-5f);
    float a = gamma[c] * rstd;
    abuf[c] = a;
    bbuf[c] = beta[c] - mu * a;
  }
}

// per-graph: compute gmean/rinv from S1/S2 in-block, then apply BN+PairNorm+relu.
template <int LAST>
__global__ __launch_bounds__(256) void k_apply(float* __restrict__ z, const float* __restrict__ abuf,
                                               const float* __restrict__ bbuf, const int* __restrict__ gstart,
                                               const int* __restrict__ cnti, const float* __restrict__ cntf,
                                               const float* __restrict__ S1, const float* __restrict__ S2,
                                               unsigned short* __restrict__ hb) {
  __shared__ float rT[256], rM[256];
  int g = blockIdx.x, c = threadIdx.x;
  float a = abuf[c], b = bbuf[c];
  float s1 = S1[(size_t)g * 256 + c];
  float s2 = S2[(size_t)g * 256 + c];
  float nr = (float)cnti[g];
  float ic = 1.0f / cntf[g];
  float mean = (a * s1 + nr * b) * ic;
  float term = fmaf(a * a, s2, fmaf(2.0f * a * b, s1, nr * b * b));
  rT[c] = term;
  rM[c] = mean * mean;
  __syncthreads();
  for (int off = 128; off; off >>= 1) {
    if (c < off) { rT[c] += rT[c + off]; rM[c] += rM[c + off]; }
    __syncthreads();
  }
  float cr = nr > 0.0f ? 1.0f : 0.0f;
  float rinv = rsqrtf(1e-5f + rT[0] * ic - cr * rM[0]);
  int r0 = gstart[g], r1 = r0 + cnti[g];
  for (int r = r0; r < r1; ++r) {
    float v = (fmaf(a, z[(size_t)r * 256 + c], b) - mean) * rinv;
    v = v > 0.0f ? v : 0.0f;
    hb[(size_t)r * 256 + c] = f2b(v);
    if (LAST) z[(size_t)r * 256 + c] = v;
  }
}

// per-graph fused pooling + output
__global__ __launch_bounds__(256) void k_poolout(const float* __restrict__ h, const float* __restrict__ scores,
                                                 const int* __restrict__ gstart, const int* __restrict__ cnti,
                                                 const float* __restrict__ cntf, float* __restrict__ out) {
  int g = blockIdx.x, c = threadIdx.x;
  int r0 = gstart[g], r1 = r0 + cnti[g];
  float ma = 0.0f, aa = 0.0f, mx = 0.0f, wa = 0.0f;
  for (int r = r0; r < r1; ++r) {
    float wgt = __expf(scores[r]);
    float hv = h[(size_t)r * 256 + c];
    ma += hv;
    aa = fmaf(hv, wgt, aa);
    mx = fmaxf(mx, hv);
    wa += wgt;
  }
  out[(size_t)g * 768 + c] = ma / cntf[g];
  out[(size_t)g * 768 + 256 + c] = mx;
  out[(size_t)g * 768 + 512 + c] = aa / (wa + 1e-8f);
}

extern "C" void kernel_launch(void* const* d_in, const int* in_sizes, int n_in,
                              void* d_out, int out_size, void* d_ws, size_t ws_size,
                              hipStream_t stream) {
  const float* x         = (const float*)d_in[0];
  const float* edge_attr = (const float*)d_in[1];
  const float* node_w    = (const float*)d_in[2];
  const float* node_b    = (const float*)d_in[3];
  const float* edge_w    = (const float*)d_in[4];
  const float* edge_b    = (const float*)d_in[5];
  const float* conv_w    = (const float*)d_in[6];
  const float* conv_b    = (const float*)d_in[7];
  const float* mlp_w1    = (const float*)d_in[8];
  const float* mlp_b1    = (const float*)d_in[9];
  const float* mlp_w2    = (const float*)d_in[10];
  const float* mlp_b2    = (const float*)d_in[11];
  const float* eps       = (const float*)d_in[12];
  const float* bn_gamma  = (const float*)d_in[13];
  const float* bn_beta   = (const float*)d_in[14];
  const float* att_w1    = (const float*)d_in[15];
  const float* att_b1    = (const float*)d_in[16];
  const float* att_w2    = (const float*)d_in[17];
  const float* att_b2    = (const float*)d_in[18];
  const int*   eidx      = (const int*)d_in[19];
  const int*   batch     = (const int*)d_in[20];
  float* out = (float*)d_out;
  float* ws  = (float*)d_ws;

  float*          zbuf = ws + O_Z;
  unsigned short* zb   = (unsigned short*)(ws + O_ZB);
  unsigned short* hb   = (unsigned short*)(ws + O_HB);
  float* S1    = ws + O_S1;
  float* S2    = ws + O_S2;
  float* abuf  = ws + O_ABUF;
  float* bbuf  = ws + O_BBUF;
  int*   cnti  = (int*)(ws + O_CNTI);
  float* cntf  = ws + O_CNTF;
  float* scor  = ws + O_SCOR;
  int*   curs  = (int*)(ws + O_SCOR);
  float* weff  = ws + O_WEFF;
  float* beff  = ws + O_BEFF;
  int*   deg   = (int*)(ws + O_DEG);
  int*   strt  = (int*)(ws + O_STRT);
  int*   bsum  = (int*)(ws + O_BSUM);
  uint4* csr   = (uint4*)(ws + O_CSR);
  unsigned short* w1p = (unsigned short*)(ws + O_W1P);
  unsigned short* w2p = (unsigned short*)(ws + O_W2P);
  unsigned short* atp = (unsigned short*)(ws + O_ATP);
  int*   gst   = (int*)(ws + O_GST);
  const int* esrc = eidx;
  const int* edst = eidx + EE;

  // graph counts + offsets
  k_zero<<<8, 256, 0, stream>>>((float*)cnti, GG);
  k_count<<<(NN + 255) / 256, 256, 0, stream>>>(batch, cnti, NN);
  k_gscan<<<1, 256, 0, stream>>>(cnti, gst, cntf);

  // fused edge weights + node embedding + weight packing
  k_wfuse<<<LL, 256, 0, stream>>>(edge_w, edge_b, conv_w, conv_b, weff, beff);
  k_node_embed<<<(NN + 15) / 16, 256, 0, stream>>>(x, node_w, node_b, hb, NN);
  k_pack_all<<<528, 256, 0, stream>>>(mlp_w1, mlp_w2, att_w1, w1p, w2p, atp);

  // CSR build (by dst)
  const int nscan = (NN + 255) / 256;  // 391
  k_zero<<<256, 256, 0, stream>>>((float*)deg, NN);
  k_deg<<<(EE + 255) / 256, 256, 0, stream>>>(edst, deg, EE);
  k_scan_part<<<nscan, 256, 0, stream>>>(deg, strt, bsum, NN);
  k_scan_top<<<1, 512, 0, stream>>>(bsum, nscan);
  k_scan_add<<<nscan, 256, 0, stream>>>(strt, bsum, curs, NN);
  k_fill<<<(EE + 255) / 256, 256, 0, stream>>>(edge_attr, esrc, edst, curs, csr, EE);

  const int mtiles64  = (NN + 63) / 64;    // 1563
  const int mtiles128 = (NN + 127) / 128;  // 782

  for (int i = 0; i < LL; ++i) {
    k_edge_csr<<<NN / 16, 256, 0, stream>>>(csr, strt, deg, weff + (size_t)i * 1536,
                                            beff + (size_t)i * 256, hb, zb, eps, i, NN);
    k_mlp<<<mtiles64, 256, 0, stream>>>(zb, w1p + (size_t)i * 65536, mlp_b1 + (size_t)i * 256,
                                        w2p + (size_t)i * 65536, mlp_b2 + (size_t)i * 256, zbuf, NN);
    k_stats<<<GG, 256, 0, stream>>>(zbuf, gst, cnti, S1, S2);
    k_bn_fin<<<256, 256, 0, stream>>>(S1, S2, bn_gamma + (size_t)i * 256, bn_beta + (size_t)i * 256,
                                      abuf, bbuf, NN);
    if (i == LL - 1)
      k_apply<1><<<GG, 256, 0, stream>>>(zbuf, abuf, bbuf, gst, cnti, cntf, S1, S2, hb);
    else
      k_apply<0><<<GG, 256, 0, stream>>>(zbuf, abuf, bbuf, gst, cnti, cntf, S1, S2, hb);
  }

  // pooling (zbuf holds fp32 h)
  k_att<<<mtiles128, 256, 0, stream>>>(hb, atp, att_b1, att_w2, att_b2, scor, NN);
  k_poolout<<<GG, 256, 0, stream>>>(zbuf, scor, gst, cnti, cntf, out);
}

// Round 9
// 1705.017 us; speedup vs baseline: 7.4948x; 1.0614x over previous
//
#include <hip/hip_runtime.h>
#include <cstdint>
#include <cstddef>

// Problem constants (fixed instance)
#define NN 100000
#define EE 320000
#define GG 2048
#define LL 8

// Workspace layout (float offsets).
#define O_Z    0ull                      // [N,256] fp32 z; h fp32 (in-place) after last apply
#define O_ZB   25600000ull               // [N,256] bf16 zin
#define O_HB   38400000ull               // [N,256] bf16 h
#define O_S1   51200000ull               // [G,256] S1
#define O_S2   (O_S1 + 524288ull)        // [G,256] S2
#define O_ABUF (O_S2 + 524288ull)        // [256]
#define O_BBUF (O_ABUF + 256ull)         // [256]
#define O_CNTI (O_BBUF + 256ull)         // [G] int
#define O_CNTF (O_CNTI + 2048ull)        // [G]
#define O_SCOR (O_CNTF + 2048ull)        // [N] scores (CSR cursor during setup)
#define O_WEFF (O_SCOR + 100000ull)      // [L,6,256]
#define O_BEFF (O_WEFF + 12288ull)       // [L,256]
#define O_DEG  (O_BEFF + 2048ull)        // [N] int
#define O_STRT (O_DEG + 100000ull)       // [N] int
#define O_BSUM (O_STRT + 100000ull)      // [512] int
#define O_CSR  (O_BSUM + 512ull)         // [E] x 16 B: 6 bf16 attrs + int src
#define O_W1P  (O_CSR + 1280000ull)      // 8 x 65536 bf16 = 262144 floats
#define O_W2P  (O_W1P + 262144ull)
#define O_ATP  (O_W2P + 262144ull)       // 32768 shorts = 16384 floats
#define O_GST  (O_ATP + 16384ull)        // [G] int gstart
#define O_NWP  (O_GST + 2048ull)         // node_w packed: 2cb x 3ks x 8ct x 64 x 8 = 24576 shorts

typedef short s16x8 __attribute__((ext_vector_type(8)));
typedef float f32x4 __attribute__((ext_vector_type(4)));

__device__ inline float b2f(unsigned int lo16) {
  union { float f; unsigned int u; } x; x.u = lo16 << 16; return x.f;
}
__device__ inline unsigned short f2b(float f) {
  union { float f; unsigned int u; } x; x.f = f;
  unsigned int r = x.u + 0x7FFFu + ((x.u >> 16) & 1u);
  return (unsigned short)(r >> 16);
}
__device__ inline unsigned short f2b_lo(float v) {   // residual after bf16 hi
  unsigned short h = f2b(v);
  float hf = b2f((unsigned int)h);
  return f2b(v - hf);
}

__global__ __launch_bounds__(256) void k_zero(float* __restrict__ p, int n) {
  int i = blockIdx.x * 256 + threadIdx.x;
  int stride = gridDim.x * 256;
  for (; i < n; i += stride) p[i] = 0.0f;
}

__global__ __launch_bounds__(256) void k_count(const int* __restrict__ batch, int* __restrict__ cnti, int n) {
  int i = blockIdx.x * 256 + threadIdx.x;
  if (i < n) atomicAdd(&cnti[batch[i]], 1);
}

// single-block scan over G=2048 counts -> gstart (exclusive), cntf (clamped)
__global__ __launch_bounds__(256) void k_gscan(const int* __restrict__ cnti, int* __restrict__ gstart,
                                               float* __restrict__ cntf) {
  __shared__ int part[256];
  int t = threadIdx.x;
  int base = t * 8;
  int loc[8];
  int s = 0;
#pragma unroll
  for (int i = 0; i < 8; ++i) { loc[i] = s; s += cnti[base + i]; }
  part[t] = s;
  __syncthreads();
  for (int off = 1; off < 256; off <<= 1) {
    int u = (t >= off) ? part[t - off] : 0;
    __syncthreads();
    part[t] += u;
    __syncthreads();
  }
  int p = (t > 0) ? part[t - 1] : 0;
#pragma unroll
  for (int i = 0; i < 8; ++i) {
    gstart[base + i] = p + loc[i];
    float v = (float)cnti[base + i];
    cntf[base + i] = v > 1.0f ? v : 1.0f;
  }
}

// ---------------- CSR build ----------------
__global__ __launch_bounds__(256) void k_deg(const int* __restrict__ edst, int* __restrict__ deg, int ne) {
  int e = blockIdx.x * 256 + threadIdx.x;
  if (e < ne) atomicAdd(&deg[edst[e]], 1);
}

__global__ __launch_bounds__(256) void k_scan_part(const int* __restrict__ deg, int* __restrict__ start,
                                                   int* __restrict__ bsum, int n) {
  __shared__ int s[256];
  int i = blockIdx.x * 256 + threadIdx.x;
  int t = threadIdx.x;
  int v = (i < n) ? deg[i] : 0;
  s[t] = v;
  __syncthreads();
  for (int off = 1; off < 256; off <<= 1) {
    int u = (t >= off) ? s[t - off] : 0;
    __syncthreads();
    s[t] += u;
    __syncthreads();
  }
  if (i < n) start[i] = s[t] - v;
  if (t == 255) bsum[blockIdx.x] = s[255];
}

__global__ __launch_bounds__(512) void k_scan_top(int* __restrict__ bsum, int nb) {
  __shared__ int s[512];
  int t = threadIdx.x;
  int v = (t < nb) ? bsum[t] : 0;
  s[t] = v;
  __syncthreads();
  for (int off = 1; off < 512; off <<= 1) {
    int u = (t >= off) ? s[t - off] : 0;
    __syncthreads();
    s[t] += u;
    __syncthreads();
  }
  if (t < nb) bsum[t] = s[t] - v;
}

__global__ __launch_bounds__(256) void k_scan_add(int* __restrict__ start, const int* __restrict__ bsum,
                                                  int* __restrict__ cursor, int n) {
  int i = blockIdx.x * 256 + threadIdx.x;
  if (i < n) {
    int v = start[i] + bsum[blockIdx.x];
    start[i] = v;
    cursor[i] = v;
  }
}

// CSR entry: uint4 = {attr0|attr1<<16, attr2|attr3<<16, attr4|attr5<<16, src}
__global__ __launch_bounds__(256) void k_fill(const float* __restrict__ ea, const int* __restrict__ esrc,
                                              const int* __restrict__ edst, int* __restrict__ cursor,
                                              uint4* __restrict__ csr, int ne) {
  int e = blockIdx.x * 256 + threadIdx.x;
  if (e >= ne) return;
  int d = edst[e];
  int slot = atomicAdd(&cursor[d], 1);
  const float* ap = ea + (size_t)e * 6;
  uint4 v;
  v.x = (unsigned int)f2b(ap[0]) | ((unsigned int)f2b(ap[1]) << 16);
  v.y = (unsigned int)f2b(ap[2]) | ((unsigned int)f2b(ap[3]) << 16);
  v.z = (unsigned int)f2b(ap[4]) | ((unsigned int)f2b(ap[5]) << 16);
  v.w = (unsigned int)esrc[e];
  csr[slot] = v;
}

// W_eff[i] = edge_w @ conv_w[i]; b_eff[i] = edge_b @ conv_w[i] + conv_b[i]
__global__ __launch_bounds__(256) void k_wfuse(const float* __restrict__ edge_w, const float* __restrict__ edge_b,
                                               const float* __restrict__ conv_w, const float* __restrict__ conv_b,
                                               float* __restrict__ wef, float* __restrict__ bef) {
  __shared__ float ew[6 * 128 + 128];
  int i = blockIdx.x;
  int c = threadIdx.x;
  for (int idx = c; idx < 896; idx += 256)
    ew[idx] = idx < 768 ? edge_w[idx] : edge_b[idx - 768];
  __syncthreads();
  float acc[7] = {0.f, 0.f, 0.f, 0.f, 0.f, 0.f, 0.f};
  const float* cw = conv_w + (size_t)i * 32768 + c;
  for (int j = 0; j < 128; ++j) {
    float w = cw[(size_t)j * 256];
#pragma unroll
    for (int k = 0; k < 6; ++k) acc[k] = fmaf(ew[k * 128 + j], w, acc[k]);
    acc[6] = fmaf(ew[768 + j], w, acc[6]);
  }
#pragma unroll
  for (int k = 0; k < 6; ++k) wef[(size_t)i * 1536 + k * 256 + c] = acc[k];
  bef[(size_t)i * 256 + c] = acc[6] + conv_b[(size_t)i * 256 + c];
}

// pack ALL mlp/att weights to MFMA B-fragment order in one launch.
__global__ __launch_bounds__(256) void k_pack_all(const float* __restrict__ mw1, const float* __restrict__ mw2,
                                                  const float* __restrict__ aw1,
                                                  unsigned short* __restrict__ w1p,
                                                  unsigned short* __restrict__ w2p,
                                                  unsigned short* __restrict__ atp) {
  int id = blockIdx.x * 256 + threadIdx.x;   // 33*4096 total
  int cbu = id >> 12;
  if (cbu >= 33) return;
  int lid = id & 4095;
  int l = lid & 63;
  int ct = (lid >> 6) & 7;
  int ks = (lid >> 9) & 7;
  const float* B;
  unsigned short* Bp;
  int ldb, cb;
  if (cbu < 32) {
    int m = cbu >> 1;
    cb = cbu & 1;
    ldb = 256;
    if (m < 8) { B = mw1 + (size_t)m * 65536; Bp = w1p + (size_t)m * 65536; }
    else       { B = mw2 + (size_t)(m - 8) * 65536; Bp = w2p + (size_t)(m - 8) * 65536; }
  } else {
    B = aw1; Bp = atp; ldb = 128; cb = 0;
  }
  int n = cb * 128 + ct * 16 + (l & 15);
  int k0 = ks * 32 + (l >> 4) * 8;
  unsigned short* dst = Bp + (((size_t)cb << 12) | (size_t)lid) * 8;
#pragma unroll
  for (int j = 0; j < 8; ++j) dst[j] = f2b(B[(size_t)(k0 + j) * ldb + n]);
}

// pack node_w [48,256] -> bf16 K_eff=96 fragment order: [cb][ks3][ct][lane][8],
// k<48 -> w[k], k>=48 -> w[k-48] (duplicated for the hi/lo x split).
__global__ __launch_bounds__(256) void k_pack_node(const float* __restrict__ w,
                                                   unsigned short* __restrict__ Wp) {
  int id = blockIdx.x * 256 + threadIdx.x;   // 3072 total
  if (id >= 3072) return;
  int l = id & 63;
  int t = id >> 6;
  int ct = t & 7;
  int u = t >> 3;          // 0..5
  int ks = u % 3;
  int cb = u / 3;
  int n = cb * 128 + ct * 16 + (l & 15);
  unsigned short* dst = Wp + (size_t)id * 8;
#pragma unroll
  for (int j = 0; j < 8; ++j) {
    int kk = ks * 32 + ((l >> 4) << 3) + j;
    int ksrc = kk < 48 ? kk : kk - 48;
    dst[j] = f2b(w[(size_t)ksrc * 256 + n]);
  }
}

// hb = bf16(x @ node_w + node_b) via MFMA. x split exactly into hi+lo bf16 (K_eff=96),
// so the only quantization is node_w -> bf16. Wave w: rows (w&1)*32, cols (w>>1)*128.
__global__ __launch_bounds__(256) void k_embed_mfma(const float* __restrict__ x,
                                                    const unsigned short* __restrict__ Wp,
                                                    const float* __restrict__ b,
                                                    unsigned short* __restrict__ hb, int M) {
  int l = threadIdx.x & 63;
  int w = threadIdx.x >> 6;
  int mloc = l & 15, q = l >> 4;
  int row0 = blockIdx.x * 64 + (w & 1) * 32;
  int colh = (w >> 1) * 128;

  f32x4 acc[2][8];
#pragma unroll
  for (int rt = 0; rt < 2; ++rt)
#pragma unroll
    for (int ct = 0; ct < 8; ++ct) acc[rt][ct] = (f32x4){0.f, 0.f, 0.f, 0.f};

  union { s16x8 v; unsigned short u[8]; } a[2][3];
#pragma unroll
  for (int rt = 0; rt < 2; ++rt) {
    int r = row0 + rt * 16 + mloc;
    if (r > M - 1) r = M - 1;
    const float* xr = x + (size_t)r * 48;
    // ks0: hi[q*8 .. +7]
    const float* p0 = xr + q * 8;
    // ks1: q<2 -> hi[32+q*8 ..], else lo[(q-2)*8 ..]
    const float* p1 = xr + (q < 2 ? 32 + q * 8 : (q - 2) * 8);
    // ks2: lo[16+q*8 ..]
    const float* p2 = xr + 16 + q * 8;
#pragma unroll
    for (int j = 0; j < 8; ++j) {
      a[rt][0].u[j] = f2b(p0[j]);
      a[rt][1].u[j] = (q < 2) ? f2b(p1[j]) : f2b_lo(p1[j]);
      a[rt][2].u[j] = f2b_lo(p2[j]);
    }
  }

  const unsigned short* bp = Wp + (size_t)(colh >> 7) * 12288 + (size_t)l * 8;
#pragma unroll
  for (int ks = 0; ks < 3; ++ks) {
#pragma unroll
    for (int ct = 0; ct < 8; ++ct) {
      s16x8 bb = *(const s16x8*)(bp + ks * 4096 + ct * 512);
      acc[0][ct] = __builtin_amdgcn_mfma_f32_16x16x32_bf16(a[0][ks].v, bb, acc[0][ct], 0, 0, 0);
      acc[1][ct] = __builtin_amdgcn_mfma_f32_16x16x32_bf16(a[1][ks].v, bb, acc[1][ct], 0, 0, 0);
    }
  }

#pragma unroll
  for (int ct = 0; ct < 8; ++ct) {
    int col = colh + ct * 16 + mloc;
    float bv = b[col];
#pragma unroll
    for (int rt = 0; rt < 2; ++rt)
#pragma unroll
      for (int r = 0; r < 4; ++r) {
        int row = row0 + rt * 16 + q * 4 + r;
        if (row < M) hb[(size_t)row * 256 + col] = f2b(acc[rt][ct][r] + bv);
      }
  }
}

// zin_b[v] = bf16((1+eps)h[v] + sum relu(h[src]+ea@W_eff+b_eff))
// ONE WAVE = 4 NODES interleaved (4 independent gather chains), 16 nodes/block.
__global__ __launch_bounds__(256) void k_edge_csr(const uint4* __restrict__ csr,
                                                  const int* __restrict__ startv, const int* __restrict__ degv,
                                                  const float* __restrict__ wef, const float* __restrict__ bef,
                                                  const unsigned short* __restrict__ hb,
                                                  unsigned short* __restrict__ zb,
                                                  const float* __restrict__ eps, int layer, int n) {
  int lane = threadIdx.x & 63;
  int wv = threadIdx.x >> 6;
  int v0 = (blockIdx.x * 4 + wv) * 4;
  if (v0 >= n) return;
  int c0 = lane * 4;
  float4 w0 = *(const float4*)(wef + 0 * 256 + c0);
  float4 w1 = *(const float4*)(wef + 1 * 256 + c0);
  float4 w2 = *(const float4*)(wef + 2 * 256 + c0);
  float4 w3 = *(const float4*)(wef + 3 * 256 + c0);
  float4 w4 = *(const float4*)(wef + 4 * 256 + c0);
  float4 w5 = *(const float4*)(wef + 5 * 256 + c0);
  float4 bf = *(const float4*)(bef + c0);
  float s = 1.0f + eps[layer];

  int dg[4], pp[4];
  float4 acc[4];
#pragma unroll
  for (int k = 0; k < 4; ++k) {
    int v = v0 + k;
    dg[k] = degv[v];
    int st = startv[v];
    pp[k] = st < (EE - 1) ? st : (EE - 1);
    uint2 hu = *(const uint2*)(hb + (size_t)v * 256 + c0);
    acc[k].x = s * b2f(hu.x & 0xFFFFu);
    acc[k].y = s * b2f(hu.x >> 16);
    acc[k].z = s * b2f(hu.y & 0xFFFFu);
    acc[k].w = s * b2f(hu.y >> 16);
  }
  int mx = dg[0] > dg[1] ? dg[0] : dg[1];
  int mx2 = dg[2] > dg[3] ? dg[2] : dg[3];
  if (mx2 > mx) mx = mx2;

  for (int t = 0; t < mx; ++t) {
    uint4 e[4];
#pragma unroll
    for (int k = 0; k < 4; ++k) e[k] = csr[pp[k]];
    uint2 g[4];
#pragma unroll
    for (int k = 0; k < 4; ++k) g[k] = *(const uint2*)(hb + (size_t)(int)e[k].w * 256 + c0);
#pragma unroll
    for (int k = 0; k < 4; ++k) {
      if (t < dg[k]) {
        float a0 = b2f(e[k].x & 0xFFFFu), a1 = b2f(e[k].x >> 16), a2 = b2f(e[k].y & 0xFFFFu);
        float a3 = b2f(e[k].y >> 16), a4 = b2f(e[k].z & 0xFFFFu), a5 = b2f(e[k].z >> 16);
        float mxv = fmaf(a0, w0.x, fmaf(a1, w1.x, fmaf(a2, w2.x, fmaf(a3, w3.x, fmaf(a4, w4.x, fmaf(a5, w5.x, b2f(g[k].x & 0xFFFFu) + bf.x))))));
        float myv = fmaf(a0, w0.y, fmaf(a1, w1.y, fmaf(a2, w2.y, fmaf(a3, w3.y, fmaf(a4, w4.y, fmaf(a5, w5.y, b2f(g[k].x >> 16) + bf.y))))));
        float mzv = fmaf(a0, w0.z, fmaf(a1, w1.z, fmaf(a2, w2.z, fmaf(a3, w3.z, fmaf(a4, w4.z, fmaf(a5, w5.z, b2f(g[k].y & 0xFFFFu) + bf.z))))));
        float mwv = fmaf(a0, w0.w, fmaf(a1, w1.w, fmaf(a2, w2.w, fmaf(a3, w3.w, fmaf(a4, w4.w, fmaf(a5, w5.w, b2f(g[k].y >> 16) + bf.w))))));
        acc[k].x += mxv > 0.f ? mxv : 0.f;
        acc[k].y += myv > 0.f ? myv : 0.f;
        acc[k].z += mzv > 0.f ? mzv : 0.f;
        acc[k].w += mwv > 0.f ? mwv : 0.f;
      }
      pp[k] += (t < dg[k] - 1) ? 1 : 0;
    }
  }
#pragma unroll
  for (int k = 0; k < 4; ++k) {
    uint2 o;
    o.x = (unsigned int)f2b(acc[k].x) | ((unsigned int)f2b(acc[k].y) << 16);
    o.y = (unsigned int)f2b(acc[k].z) | ((unsigned int)f2b(acc[k].w) << 16);
    *(uint2*)(zb + (size_t)(v0 + k) * 256 + c0) = o;
  }
}

// Fused MLP + per-graph stats: z = relu(zin@W1+b1)@W2+b2 for a 64-row tile; the LDS-resident
// C tile also feeds segmented per-graph S1/S2 accumulation (atomicAdd; S1/S2 pre-zeroed).
__global__ __launch_bounds__(256, 4) void k_mlp(const unsigned short* __restrict__ A,
                                                const unsigned short* __restrict__ W1p,
                                                const float* __restrict__ b1,
                                                const unsigned short* __restrict__ W2p,
                                                const float* __restrict__ b2,
                                                float* __restrict__ Z,
                                                const int* __restrict__ batchv,
                                                float* __restrict__ S1, float* __restrict__ S2, int M) {
  __shared__ __align__(16) unsigned char smem[33024];        // max(64*256*2, 32*258*4)
  unsigned short* t1s = (unsigned short*)smem;
  float* zc = (float*)smem;                                  // 32 x (stride 258) fp32
  int l = threadIdx.x & 63;
  int w = threadIdx.x >> 6;
  int mloc = l & 15, q = l >> 4;
  int rowg = (w & 1) * 32;
  int colh = (w >> 1) * 128;
  int row0 = blockIdx.x * 64;

  const unsigned short* ap[2];
#pragma unroll
  for (int rt = 0; rt < 2; ++rt) {
    int r = row0 + rowg + rt * 16 + mloc;
    if (r > M - 1) r = M - 1;
    ap[rt] = A + (size_t)r * 256 + q * 8;
  }
  f32x4 acc[2][8];
#pragma unroll
  for (int rt = 0; rt < 2; ++rt)
#pragma unroll
    for (int ct = 0; ct < 8; ++ct) acc[rt][ct] = (f32x4){0.f, 0.f, 0.f, 0.f};

  const unsigned short* w1base = W1p + ((size_t)(colh >> 7)) * 32768 + (size_t)l * 8;
#pragma unroll
  for (int ks = 0; ks < 8; ++ks) {
    s16x8 a0 = *(const s16x8*)(ap[0] + ks * 32);
    s16x8 a1 = *(const s16x8*)(ap[1] + ks * 32);
#pragma unroll
    for (int ct = 0; ct < 8; ++ct) {
      s16x8 b = *(const s16x8*)(w1base + ks * 4096 + ct * 512);
      acc[0][ct] = __builtin_amdgcn_mfma_f32_16x16x32_bf16(a0, b, acc[0][ct], 0, 0, 0);
      acc[1][ct] = __builtin_amdgcn_mfma_f32_16x16x32_bf16(a1, b, acc[1][ct], 0, 0, 0);
    }
  }
  // epilogue 1: bias+relu -> LDS bf16 (XOR swizzle on 16-B chunks)
#pragma unroll
  for (int ct = 0; ct < 8; ++ct) {
    int col = colh + ct * 16 + mloc;
    float bv = b1[col];
    int cc = col >> 3, pos = col & 7;
#pragma unroll
    for (int rt = 0; rt < 2; ++rt)
#pragma unroll
      for (int r = 0; r < 4; ++r) {
        int row = rowg + rt * 16 + q * 4 + r;
        float v = acc[rt][ct][r] + bv;
        v = v > 0.f ? v : 0.f;
        t1s[row * 256 + ((cc ^ (row & 31)) << 3) + pos] = f2b(v);
      }
  }
  __syncthreads();
  // GEMM2: A from LDS
#pragma unroll
  for (int rt = 0; rt < 2; ++rt)
#pragma unroll
    for (int ct = 0; ct < 8; ++ct) acc[rt][ct] = (f32x4){0.f, 0.f, 0.f, 0.f};
  const unsigned short* w2base = W2p + ((size_t)(colh >> 7)) * 32768 + (size_t)l * 8;
#pragma unroll
  for (int ks = 0; ks < 8; ++ks) {
    s16x8 a[2];
#pragma unroll
    for (int rt = 0; rt < 2; ++rt) {
      int row = rowg + rt * 16 + mloc;
      int cc = (q + ks * 4) ^ (row & 31);
      a[rt] = *(const s16x8*)(t1s + row * 256 + (cc << 3));
    }
#pragma unroll
    for (int ct = 0; ct < 8; ++ct) {
      s16x8 b = *(const s16x8*)(w2base + ks * 4096 + ct * 512);
      acc[0][ct] = __builtin_amdgcn_mfma_f32_16x16x32_bf16(a[0], b, acc[0][ct], 0, 0, 0);
      acc[1][ct] = __builtin_amdgcn_mfma_f32_16x16x32_bf16(a[1], b, acc[1][ct], 0, 0, 0);
    }
  }
  // bias into registers
  float bv2[8];
#pragma unroll
  for (int ct = 0; ct < 8; ++ct) bv2[ct] = b2[colh + ct * 16 + mloc];

  // epilogue 2: bounce through LDS per 32-row half -> coalesced stores + fused stats
#pragma unroll
  for (int half = 0; half < 2; ++half) {
    __syncthreads();
    if ((w & 1) == half) {
#pragma unroll
      for (int ct = 0; ct < 8; ++ct) {
        int col = colh + ct * 16 + mloc;
#pragma unroll
        for (int rt = 0; rt < 2; ++rt)
#pragma unroll
          for (int r = 0; r < 4; ++r) {
            int row = rt * 16 + q * 4 + r;               // 0..31 local
            zc[row * 258 + col] = acc[rt][ct][r] + bv2[ct];
          }
      }
    }
    __syncthreads();
    int baserow = row0 + half * 32;
#pragma unroll
    for (int it = 0; it < 8; ++it) {
      int row = it * 4 + w;                               // one row per wave
      int grow = baserow + row;
      float4 vv = *(const float4*)(zc + row * 258 + l * 4);
      if (grow < M) *(float4*)(Z + (size_t)grow * 256 + l * 4) = vv;
    }
    // fused per-graph S1/S2 (thread = column, segmented by sorted batch)
    {
      int c = threadIdx.x;
      int rend = (M - baserow) < 32 ? (M - baserow) : 32;
      if (rend > 0) {
        float s1 = 0.f, s2 = 0.f;
        int gcur = batchv[baserow];
        for (int row = 0; row < rend; ++row) {
          int g = batchv[baserow + row];
          if (g != gcur) {
            atomicAdd(&S1[(size_t)gcur * 256 + c], s1);
            atomicAdd(&S2[(size_t)gcur * 256 + c], s2);
            s1 = 0.f; s2 = 0.f; gcur = g;
          }
          float v = zc[row * 258 + c];
          s1 += v;
          s2 = fmaf(v, v, s2);
        }
        atomicAdd(&S1[(size_t)gcur * 256 + c], s1);
        atomicAdd(&S2[(size_t)gcur * 256 + c], s2);
      }
    }
  }
}

// attention: score[row] = tanh(h@W1+b1) @ w2 + b2 — fused
__global__ __launch_bounds__(256) void k_att(const unsigned short* __restrict__ A,
                                             const unsigned short* __restrict__ Bp,
                                             const float* __restrict__ b1,
                                             const float* __restrict__ w2,
                                             const float* __restrict__ b2,
                                             float* __restrict__ scores, int M) {
  int l = threadIdx.x & 63;
  int w = threadIdx.x >> 6;
  int mloc = l & 15, q = l >> 4;
  int row0 = blockIdx.x * 128 + w * 32;

  int r0 = row0 + mloc;      if (r0 > M - 1) r0 = M - 1;
  int r1 = row0 + 16 + mloc; if (r1 > M - 1) r1 = M - 1;
  const unsigned short* ap0 = A + (size_t)r0 * 256 + q * 8;
  const unsigned short* ap1 = A + (size_t)r1 * 256 + q * 8;
  const unsigned short* bp = Bp + (size_t)l * 8;

  f32x4 acc[2][8];
#pragma unroll
  for (int rt = 0; rt < 2; ++rt)
#pragma unroll
    for (int ct = 0; ct < 8; ++ct) acc[rt][ct] = (f32x4){0.f, 0.f, 0.f, 0.f};
#pragma unroll
  for (int ks = 0; ks < 8; ++ks) {
    s16x8 a0 = *(const s16x8*)(ap0 + ks * 32);
    s16x8 a1 = *(const s16x8*)(ap1 + ks * 32);
#pragma unroll
    for (int ct = 0; ct < 8; ++ct) {
      s16x8 b = *(const s16x8*)(bp + ks * 4096 + ct * 512);
      acc[0][ct] = __builtin_amdgcn_mfma_f32_16x16x32_bf16(a0, b, acc[0][ct], 0, 0, 0);
      acc[1][ct] = __builtin_amdgcn_mfma_f32_16x16x32_bf16(a1, b, acc[1][ct], 0, 0, 0);
    }
  }
  float bv[8], wv[8];
#pragma unroll
  for (int ct = 0; ct < 8; ++ct) {
    bv[ct] = b1[ct * 16 + mloc];
    wv[ct] = w2[ct * 16 + mloc];
  }
  float b2v = b2[0];
#pragma unroll
  for (int rt = 0; rt < 2; ++rt)
#pragma unroll
    for (int r = 0; r < 4; ++r) {
      float p = 0.0f;
#pragma unroll
      for (int ct = 0; ct < 8; ++ct) p = fmaf(tanhf(acc[rt][ct][r] + bv[ct]), wv[ct], p);
      p += __shfl_xor(p, 1, 64);
      p += __shfl_xor(p, 2, 64);
      p += __shfl_xor(p, 4, 64);
      p += __shfl_xor(p, 8, 64);
      int row = row0 + rt * 16 + q * 4 + r;
      if (mloc == 0 && row < M) scores[row] = p + b2v;
    }
}

// column BN stats from per-graph S1/S2: one block per column
__global__ __launch_bounds__(256) void k_bn_fin(const float* __restrict__ S1, const float* __restrict__ S2,
                                                const float* __restrict__ gamma, const float* __restrict__ beta,
                                                float* __restrict__ abuf, float* __restrict__ bbuf, int n) {
  __shared__ float r1[256], r2[256];
  int c = blockIdx.x;
  int t = threadIdx.x;
  float s1 = 0.0f, s2 = 0.0f;
  for (int g = t; g < GG; g += 256) {
    s1 += S1[(size_t)g * 256 + c];
    s2 += S2[(size_t)g * 256 + c];
  }
  r1[t] = s1; r2[t] = s2;
  __syncthreads();
  for (int off = 128; off; off >>= 1) {
    if (t < off) { r1[t] += r1[t + off]; r2[t] += r2[t + off]; }
    __syncthreads();
  }
  if (t == 0) {
    float inv = 1.0f / (float)n;
    float mu = r1[0] * inv;
    float var = r2[0] * inv - mu * mu;
    float rstd = rsqrtf(var + 1e-5f);
    float a = gamma[c] * rstd;
    abuf[c] = a;
    bbuf[c] = beta[c] - mu * a;
  }
}

// per-graph: gmean/rinv from S1/S2 in-block, apply BN+PairNorm+relu; zeroes S1/S2 for next layer.
template <int LAST>
__global__ __launch_bounds__(256) void k_apply(float* __restrict__ z, const float* __restrict__ abuf,
                                               const float* __restrict__ bbuf, const int* __restrict__ gstart,
                                               const int* __restrict__ cnti, const float* __restrict__ cntf,
                                               float* __restrict__ S1, float* __restrict__ S2,
                                               unsigned short* __restrict__ hb) {
  __shared__ float rT[256], rM[256];
  int g = blockIdx.x, c = threadIdx.x;
  float a = abuf[c], b = bbuf[c];
  size_t idx = (size_t)g * 256 + c;
  float s1 = S1[idx];
  float s2 = S2[idx];
  S1[idx] = 0.0f;          // re-zero for next layer's fused stats
  S2[idx] = 0.0f;
  float nr = (float)cnti[g];
  float ic = 1.0f / cntf[g];
  float mean = (a * s1 + nr * b) * ic;
  float term = fmaf(a * a, s2, fmaf(2.0f * a * b, s1, nr * b * b));
  rT[c] = term;
  rM[c] = mean * mean;
  __syncthreads();
  for (int off = 128; off; off >>= 1) {
    if (c < off) { rT[c] += rT[c + off]; rM[c] += rM[c + off]; }
    __syncthreads();
  }
  float cr = nr > 0.0f ? 1.0f : 0.0f;
  float rinv = rsqrtf(1e-5f + rT[0] * ic - cr * rM[0]);
  int r0 = gstart[g], r1 = r0 + cnti[g];
  for (int r = r0; r < r1; ++r) {
    float v = (fmaf(a, z[(size_t)r * 256 + c], b) - mean) * rinv;
    v = v > 0.0f ? v : 0.0f;
    hb[(size_t)r * 256 + c] = f2b(v);
    if (LAST) z[(size_t)r * 256 + c] = v;
  }
}

// per-graph fused pooling + output
__global__ __launch_bounds__(256) void k_poolout(const float* __restrict__ h, const float* __restrict__ scores,
                                                 const int* __restrict__ gstart, const int* __restrict__ cnti,
                                                 const float* __restrict__ cntf, float* __restrict__ out) {
  int g = blockIdx.x, c = threadIdx.x;
  int r0 = gstart[g], r1 = r0 + cnti[g];
  float ma = 0.0f, aa = 0.0f, mx = 0.0f, wa = 0.0f;
  for (int r = r0; r < r1; ++r) {
    float wgt = __expf(scores[r]);
    float hv = h[(size_t)r * 256 + c];
    ma += hv;
    aa = fmaf(hv, wgt, aa);
    mx = fmaxf(mx, hv);
    wa += wgt;
  }
  out[(size_t)g * 768 + c] = ma / cntf[g];
  out[(size_t)g * 768 + 256 + c] = mx;
  out[(size_t)g * 768 + 512 + c] = aa / (wa + 1e-8f);
}

extern "C" void kernel_launch(void* const* d_in, const int* in_sizes, int n_in,
                              void* d_out, int out_size, void* d_ws, size_t ws_size,
                              hipStream_t stream) {
  const float* x         = (const float*)d_in[0];
  const float* edge_attr = (const float*)d_in[1];
  const float* node_w    = (const float*)d_in[2];
  const float* node_b    = (const float*)d_in[3];
  const float* edge_w    = (const float*)d_in[4];
  const float* edge_b    = (const float*)d_in[5];
  const float* conv_w    = (const float*)d_in[6];
  const float* conv_b    = (const float*)d_in[7];
  const float* mlp_w1    = (const float*)d_in[8];
  const float* mlp_b1    = (const float*)d_in[9];
  const float* mlp_w2    = (const float*)d_in[10];
  const float* mlp_b2    = (const float*)d_in[11];
  const float* eps       = (const float*)d_in[12];
  const float* bn_gamma  = (const float*)d_in[13];
  const float* bn_beta   = (const float*)d_in[14];
  const float* att_w1    = (const float*)d_in[15];
  const float* att_b1    = (const float*)d_in[16];
  const float* att_w2    = (const float*)d_in[17];
  const float* att_b2    = (const float*)d_in[18];
  const int*   eidx      = (const int*)d_in[19];
  const int*   batch     = (const int*)d_in[20];
  float* out = (float*)d_out;
  float* ws  = (float*)d_ws;

  float*          zbuf = ws + O_Z;
  unsigned short* zb   = (unsigned short*)(ws + O_ZB);
  unsigned short* hb   = (unsigned short*)(ws + O_HB);
  float* S1    = ws + O_S1;
  float* S2    = ws + O_S2;
  float* abuf  = ws + O_ABUF;
  float* bbuf  = ws + O_BBUF;
  int*   cnti  = (int*)(ws + O_CNTI);
  float* cntf  = ws + O_CNTF;
  float* scor  = ws + O_SCOR;
  int*   curs  = (int*)(ws + O_SCOR);
  float* weff  = ws + O_WEFF;
  float* beff  = ws + O_BEFF;
  int*   deg   = (int*)(ws + O_DEG);
  int*   strt  = (int*)(ws + O_STRT);
  int*   bsum  = (int*)(ws + O_BSUM);
  uint4* csr   = (uint4*)(ws + O_CSR);
  unsigned short* w1p = (unsigned short*)(ws + O_W1P);
  unsigned short* w2p = (unsigned short*)(ws + O_W2P);
  unsigned short* atp = (unsigned short*)(ws + O_ATP);
  int*   gst   = (int*)(ws + O_GST);
  unsigned short* nwp = (unsigned short*)(ws + O_NWP);
  const int* esrc = eidx;
  const int* edst = eidx + EE;

  // graph counts + offsets
  k_zero<<<8, 256, 0, stream>>>((float*)cnti, GG);
  k_count<<<(NN + 255) / 256, 256, 0, stream>>>(batch, cnti, NN);
  k_gscan<<<1, 256, 0, stream>>>(cnti, gst, cntf);

  // fused edge weights + weight packing + MFMA node embedding
  k_wfuse<<<LL, 256, 0, stream>>>(edge_w, edge_b, conv_w, conv_b, weff, beff);
  k_pack_all<<<528, 256, 0, stream>>>(mlp_w1, mlp_w2, att_w1, w1p, w2p, atp);
  k_pack_node<<<12, 256, 0, stream>>>(node_w, nwp);
  k_embed_mfma<<<(NN + 63) / 64, 256, 0, stream>>>(x, nwp, node_b, hb, NN);

  // S1/S2 zero for layer-0 fused stats (subsequent layers re-zeroed by k_apply)
  k_zero<<<1024, 256, 0, stream>>>(S1, 2 * 524288);

  // CSR build (by dst)
  const int nscan = (NN + 255) / 256;  // 391
  k_zero<<<256, 256, 0, stream>>>((float*)deg, NN);
  k_deg<<<(EE + 255) / 256, 256, 0, stream>>>(edst, deg, EE);
  k_scan_part<<<nscan, 256, 0, stream>>>(deg, strt, bsum, NN);
  k_scan_top<<<1, 512, 0, stream>>>(bsum, nscan);
  k_scan_add<<<nscan, 256, 0, stream>>>(strt, bsum, curs, NN);
  k_fill<<<(EE + 255) / 256, 256, 0, stream>>>(edge_attr, esrc, edst, curs, csr, EE);

  const int mtiles64  = (NN + 63) / 64;    // 1563
  const int mtiles128 = (NN + 127) / 128;  // 782

  for (int i = 0; i < LL; ++i) {
    k_edge_csr<<<NN / 16, 256, 0, stream>>>(csr, strt, deg, weff + (size_t)i * 1536,
                                            beff + (size_t)i * 256, hb, zb, eps, i, NN);
    k_mlp<<<mtiles64, 256, 0, stream>>>(zb, w1p + (size_t)i * 65536, mlp_b1 + (size_t)i * 256,
                                        w2p + (size_t)i * 65536, mlp_b2 + (size_t)i * 256, zbuf,
                                        batch, S1, S2, NN);
    k_bn_fin<<<256, 256, 0, stream>>>(S1, S2, bn_gamma + (size_t)i * 256, bn_beta + (size_t)i * 256,
                                      abuf, bbuf, NN);
    if (i == LL - 1)
      k_apply<1><<<GG, 256, 0, stream>>>(zbuf, abuf, bbuf, gst, cnti, cntf, S1, S2, hb);
    else
      k_apply<0><<<GG, 256, 0, stream>>>(zbuf, abuf, bbuf, gst, cnti, cntf, S1, S2, hb);
  }

  // pooling (zbuf holds fp32 h)
  k_att<<<mtiles128, 256, 0, stream>>>(hb, atp, att_b1, att_w2, att_b2, scor, NN);
  k_poolout<<<GG, 256, 0, stream>>>(zbuf, scor, gst, cnti, cntf, out);
}

// Round 10
// 1559.496 us; speedup vs baseline: 8.1941x; 1.0933x over previous
//
#include <hip/hip_runtime.h>
#include <cstdint>
#include <cstddef>

// Problem constants (fixed instance)
#define NN 100000
#define EE 320000
#define GG 2048
#define LL 8

// Workspace layout (float offsets).
#define O_Z    0ull                      // [N,256] fp32 z; h fp32 (in-place) after last apply
#define O_ZB   25600000ull               // [N,256] bf16 zin
#define O_HB   38400000ull               // [N,256] bf16 h
#define O_S1   51200000ull               // [G,256] S1
#define O_S2   (O_S1 + 524288ull)        // [G,256] S2
#define O_ABUF (O_S2 + 524288ull)        // [256]
#define O_BBUF (O_ABUF + 256ull)         // [256]
#define O_CNTI (O_BBUF + 256ull)         // [G] int
#define O_CNTF (O_CNTI + 2048ull)        // [G]
#define O_SCOR (O_CNTF + 2048ull)        // [N] scores (CSR cursor during setup)
#define O_WEFF (O_SCOR + 100000ull)      // [L,6,256]
#define O_BEFF (O_WEFF + 12288ull)       // [L,256]
#define O_DEG  (O_BEFF + 2048ull)        // [N] int
#define O_STRT (O_DEG + 100000ull)       // [N] int
#define O_BSUM (O_STRT + 100000ull)      // [512] int
#define O_CSR  (O_BSUM + 512ull)         // [E] x 16 B: 6 bf16 attrs + int src
#define O_W1P  (O_CSR + 1280000ull)      // 8 x 65536 bf16 = 262144 floats
#define O_W2P  (O_W1P + 262144ull)
#define O_ATP  (O_W2P + 262144ull)       // 32768 shorts = 16384 floats
#define O_GST  (O_ATP + 16384ull)        // [G] int gstart
#define O_NWP  (O_GST + 2048ull)         // node_w packed: 24576 shorts = 12288 floats
#define O_BNP  (O_NWP + 12288ull)        // bn partials: 2 x [64,256] = 32768 floats

typedef short s16x8 __attribute__((ext_vector_type(8)));
typedef float f32x4 __attribute__((ext_vector_type(4)));

__device__ inline float b2f(unsigned int lo16) {
  union { float f; unsigned int u; } x; x.u = lo16 << 16; return x.f;
}
__device__ inline unsigned short f2b(float f) {
  union { float f; unsigned int u; } x; x.f = f;
  unsigned int r = x.u + 0x7FFFu + ((x.u >> 16) & 1u);
  return (unsigned short)(r >> 16);
}
__device__ inline unsigned short f2b_lo(float v) {   // residual after bf16 hi
  unsigned short h = f2b(v);
  float hf = b2f((unsigned int)h);
  return f2b(v - hf);
}

__global__ __launch_bounds__(256) void k_zero(float* __restrict__ p, int n) {
  int i = blockIdx.x * 256 + threadIdx.x;
  int stride = gridDim.x * 256;
  for (; i < n; i += stride) p[i] = 0.0f;
}

__global__ __launch_bounds__(256) void k_count(const int* __restrict__ batch, int* __restrict__ cnti, int n) {
  int i = blockIdx.x * 256 + threadIdx.x;
  if (i < n) atomicAdd(&cnti[batch[i]], 1);
}

// single-block scan over G=2048 counts -> gstart (exclusive), cntf (clamped)
__global__ __launch_bounds__(256) void k_gscan(const int* __restrict__ cnti, int* __restrict__ gstart,
                                               float* __restrict__ cntf) {
  __shared__ int part[256];
  int t = threadIdx.x;
  int base = t * 8;
  int loc[8];
  int s = 0;
#pragma unroll
  for (int i = 0; i < 8; ++i) { loc[i] = s; s += cnti[base + i]; }
  part[t] = s;
  __syncthreads();
  for (int off = 1; off < 256; off <<= 1) {
    int u = (t >= off) ? part[t - off] : 0;
    __syncthreads();
    part[t] += u;
    __syncthreads();
  }
  int p = (t > 0) ? part[t - 1] : 0;
#pragma unroll
  for (int i = 0; i < 8; ++i) {
    gstart[base + i] = p + loc[i];
    float v = (float)cnti[base + i];
    cntf[base + i] = v > 1.0f ? v : 1.0f;
  }
}

// ---------------- CSR build ----------------
__global__ __launch_bounds__(256) void k_deg(const int* __restrict__ edst, int* __restrict__ deg, int ne) {
  int e = blockIdx.x * 256 + threadIdx.x;
  if (e < ne) atomicAdd(&deg[edst[e]], 1);
}

__global__ __launch_bounds__(256) void k_scan_part(const int* __restrict__ deg, int* __restrict__ start,
                                                   int* __restrict__ bsum, int n) {
  __shared__ int s[256];
  int i = blockIdx.x * 256 + threadIdx.x;
  int t = threadIdx.x;
  int v = (i < n) ? deg[i] : 0;
  s[t] = v;
  __syncthreads();
  for (int off = 1; off < 256; off <<= 1) {
    int u = (t >= off) ? s[t - off] : 0;
    __syncthreads();
    s[t] += u;
    __syncthreads();
  }
  if (i < n) start[i] = s[t] - v;
  if (t == 255) bsum[blockIdx.x] = s[255];
}

__global__ __launch_bounds__(512) void k_scan_top(int* __restrict__ bsum, int nb) {
  __shared__ int s[512];
  int t = threadIdx.x;
  int v = (t < nb) ? bsum[t] : 0;
  s[t] = v;
  __syncthreads();
  for (int off = 1; off < 512; off <<= 1) {
    int u = (t >= off) ? s[t - off] : 0;
    __syncthreads();
    s[t] += u;
    __syncthreads();
  }
  if (t < nb) bsum[t] = s[t] - v;
}

__global__ __launch_bounds__(256) void k_scan_add(int* __restrict__ start, const int* __restrict__ bsum,
                                                  int* __restrict__ cursor, int n) {
  int i = blockIdx.x * 256 + threadIdx.x;
  if (i < n) {
    int v = start[i] + bsum[blockIdx.x];
    start[i] = v;
    cursor[i] = v;
  }
}

// CSR entry: uint4 = {attr0|attr1<<16, attr2|attr3<<16, attr4|attr5<<16, src}
__global__ __launch_bounds__(256) void k_fill(const float* __restrict__ ea, const int* __restrict__ esrc,
                                              const int* __restrict__ edst, int* __restrict__ cursor,
                                              uint4* __restrict__ csr, int ne) {
  int e = blockIdx.x * 256 + threadIdx.x;
  if (e >= ne) return;
  int d = edst[e];
  int slot = atomicAdd(&cursor[d], 1);
  const float* ap = ea + (size_t)e * 6;
  uint4 v;
  v.x = (unsigned int)f2b(ap[0]) | ((unsigned int)f2b(ap[1]) << 16);
  v.y = (unsigned int)f2b(ap[2]) | ((unsigned int)f2b(ap[3]) << 16);
  v.z = (unsigned int)f2b(ap[4]) | ((unsigned int)f2b(ap[5]) << 16);
  v.w = (unsigned int)esrc[e];
  csr[slot] = v;
}

// W_eff[i] = edge_w @ conv_w[i]; b_eff[i] = edge_b @ conv_w[i] + conv_b[i]
__global__ __launch_bounds__(256) void k_wfuse(const float* __restrict__ edge_w, const float* __restrict__ edge_b,
                                               const float* __restrict__ conv_w, const float* __restrict__ conv_b,
                                               float* __restrict__ wef, float* __restrict__ bef) {
  __shared__ float ew[6 * 128 + 128];
  int i = blockIdx.x;
  int c = threadIdx.x;
  for (int idx = c; idx < 896; idx += 256)
    ew[idx] = idx < 768 ? edge_w[idx] : edge_b[idx - 768];
  __syncthreads();
  float acc[7] = {0.f, 0.f, 0.f, 0.f, 0.f, 0.f, 0.f};
  const float* cw = conv_w + (size_t)i * 32768 + c;
  for (int j = 0; j < 128; ++j) {
    float w = cw[(size_t)j * 256];
#pragma unroll
    for (int k = 0; k < 6; ++k) acc[k] = fmaf(ew[k * 128 + j], w, acc[k]);
    acc[6] = fmaf(ew[768 + j], w, acc[6]);
  }
#pragma unroll
  for (int k = 0; k < 6; ++k) wef[(size_t)i * 1536 + k * 256 + c] = acc[k];
  bef[(size_t)i * 256 + c] = acc[6] + conv_b[(size_t)i * 256 + c];
}

// pack ALL mlp/att weights to MFMA B-fragment order in one launch.
__global__ __launch_bounds__(256) void k_pack_all(const float* __restrict__ mw1, const float* __restrict__ mw2,
                                                  const float* __restrict__ aw1,
                                                  unsigned short* __restrict__ w1p,
                                                  unsigned short* __restrict__ w2p,
                                                  unsigned short* __restrict__ atp) {
  int id = blockIdx.x * 256 + threadIdx.x;   // 33*4096 total
  int cbu = id >> 12;
  if (cbu >= 33) return;
  int lid = id & 4095;
  int l = lid & 63;
  int ct = (lid >> 6) & 7;
  int ks = (lid >> 9) & 7;
  const float* B;
  unsigned short* Bp;
  int ldb, cb;
  if (cbu < 32) {
    int m = cbu >> 1;
    cb = cbu & 1;
    ldb = 256;
    if (m < 8) { B = mw1 + (size_t)m * 65536; Bp = w1p + (size_t)m * 65536; }
    else       { B = mw2 + (size_t)(m - 8) * 65536; Bp = w2p + (size_t)(m - 8) * 65536; }
  } else {
    B = aw1; Bp = atp; ldb = 128; cb = 0;
  }
  int n = cb * 128 + ct * 16 + (l & 15);
  int k0 = ks * 32 + (l >> 4) * 8;
  unsigned short* dst = Bp + (((size_t)cb << 12) | (size_t)lid) * 8;
#pragma unroll
  for (int j = 0; j < 8; ++j) dst[j] = f2b(B[(size_t)(k0 + j) * ldb + n]);
}

// pack node_w [48,256] -> bf16 K_eff=96 fragment order: [cb][ks3][ct][lane][8]
__global__ __launch_bounds__(256) void k_pack_node(const float* __restrict__ w,
                                                   unsigned short* __restrict__ Wp) {
  int id = blockIdx.x * 256 + threadIdx.x;   // 3072 total
  if (id >= 3072) return;
  int l = id & 63;
  int t = id >> 6;
  int ct = t & 7;
  int u = t >> 3;          // 0..5
  int ks = u % 3;
  int cb = u / 3;
  int n = cb * 128 + ct * 16 + (l & 15);
  unsigned short* dst = Wp + (size_t)id * 8;
#pragma unroll
  for (int j = 0; j < 8; ++j) {
    int kk = ks * 32 + ((l >> 4) << 3) + j;
    int ksrc = kk < 48 ? kk : kk - 48;
    dst[j] = f2b(w[(size_t)ksrc * 256 + n]);
  }
}

// hb = bf16(x @ node_w + node_b) via MFMA, x staged through LDS (coalesced global reads).
// x split exactly into hi+lo bf16 (K_eff=96) — only node_w is quantized.
__global__ __launch_bounds__(256) void k_embed_mfma(const float* __restrict__ x,
                                                    const unsigned short* __restrict__ Wp,
                                                    const float* __restrict__ b,
                                                    unsigned short* __restrict__ hb, int M) {
  __shared__ float xs[64 * 50];                 // stride 50 to spread banks
  int tid = threadIdx.x;
  int row0g = blockIdx.x * 64;
  for (int idx = tid; idx < 3072; idx += 256) {
    int r = idx / 48, c = idx - r * 48;
    int gr = row0g + r; if (gr > M - 1) gr = M - 1;
    xs[r * 50 + c] = x[(size_t)gr * 48 + c];
  }
  __syncthreads();

  int l = tid & 63;
  int w = tid >> 6;
  int mloc = l & 15, q = l >> 4;
  int rowl0 = (w & 1) * 32;
  int colh = (w >> 1) * 128;

  f32x4 acc[2][8];
#pragma unroll
  for (int rt = 0; rt < 2; ++rt)
#pragma unroll
    for (int ct = 0; ct < 8; ++ct) acc[rt][ct] = (f32x4){0.f, 0.f, 0.f, 0.f};

  union { s16x8 v; unsigned short u[8]; } a[2][3];
#pragma unroll
  for (int rt = 0; rt < 2; ++rt) {
    const float* xr = xs + (rowl0 + rt * 16 + mloc) * 50;
    const float* p0 = xr + q * 8;
    const float* p1 = xr + (q < 2 ? 32 + q * 8 : (q - 2) * 8);
    const float* p2 = xr + 16 + q * 8;
#pragma unroll
    for (int j = 0; j < 8; ++j) {
      a[rt][0].u[j] = f2b(p0[j]);
      a[rt][1].u[j] = (q < 2) ? f2b(p1[j]) : f2b_lo(p1[j]);
      a[rt][2].u[j] = f2b_lo(p2[j]);
    }
  }

  const unsigned short* bp = Wp + (size_t)(colh >> 7) * 12288 + (size_t)l * 8;
#pragma unroll
  for (int ks = 0; ks < 3; ++ks) {
#pragma unroll
    for (int ct = 0; ct < 8; ++ct) {
      s16x8 bb = *(const s16x8*)(bp + ks * 4096 + ct * 512);
      acc[0][ct] = __builtin_amdgcn_mfma_f32_16x16x32_bf16(a[0][ks].v, bb, acc[0][ct], 0, 0, 0);
      acc[1][ct] = __builtin_amdgcn_mfma_f32_16x16x32_bf16(a[1][ks].v, bb, acc[1][ct], 0, 0, 0);
    }
  }

#pragma unroll
  for (int ct = 0; ct < 8; ++ct) {
    int col = colh + ct * 16 + mloc;
    float bv = b[col];
#pragma unroll
    for (int rt = 0; rt < 2; ++rt)
#pragma unroll
      for (int r = 0; r < 4; ++r) {
        int row = row0g + rowl0 + rt * 16 + q * 4 + r;
        if (row < M) hb[(size_t)row * 256 + col] = f2b(acc[rt][ct][r] + bv);
      }
  }
}

// zin_b[v] = bf16((1+eps)h[v] + sum relu(h[src]+ea@W_eff+b_eff))
// ONE WAVE = 4 NODES interleaved; CSR entries software-pipelined (csr[t+1] loads
// issue during gather(t)+FMA(t)).
__global__ __launch_bounds__(256) void k_edge_csr(const uint4* __restrict__ csr,
                                                  const int* __restrict__ startv, const int* __restrict__ degv,
                                                  const float* __restrict__ wef, const float* __restrict__ bef,
                                                  const unsigned short* __restrict__ hb,
                                                  unsigned short* __restrict__ zb,
                                                  const float* __restrict__ eps, int layer, int n) {
  int lane = threadIdx.x & 63;
  int wv = threadIdx.x >> 6;
  int v0 = (blockIdx.x * 4 + wv) * 4;
  if (v0 >= n) return;
  int c0 = lane * 4;
  float4 w0 = *(const float4*)(wef + 0 * 256 + c0);
  float4 w1 = *(const float4*)(wef + 1 * 256 + c0);
  float4 w2 = *(const float4*)(wef + 2 * 256 + c0);
  float4 w3 = *(const float4*)(wef + 3 * 256 + c0);
  float4 w4 = *(const float4*)(wef + 4 * 256 + c0);
  float4 w5 = *(const float4*)(wef + 5 * 256 + c0);
  float4 bf = *(const float4*)(bef + c0);
  float s = 1.0f + eps[layer];

  int dg[4], pp[4];
  float4 acc[4];
#pragma unroll
  for (int k = 0; k < 4; ++k) {
    int v = v0 + k;
    dg[k] = degv[v];
    int st = startv[v];
    pp[k] = st < (EE - 1) ? st : (EE - 1);
    uint2 hu = *(const uint2*)(hb + (size_t)v * 256 + c0);
    acc[k].x = s * b2f(hu.x & 0xFFFFu);
    acc[k].y = s * b2f(hu.x >> 16);
    acc[k].z = s * b2f(hu.y & 0xFFFFu);
    acc[k].w = s * b2f(hu.y >> 16);
  }
  int mx = dg[0] > dg[1] ? dg[0] : dg[1];
  int mx2 = dg[2] > dg[3] ? dg[2] : dg[3];
  if (mx2 > mx) mx = mx2;

  uint4 e[4];
#pragma unroll
  for (int k = 0; k < 4; ++k) e[k] = csr[pp[k]];

  for (int t = 0; t < mx; ++t) {
    uint2 g[4];
#pragma unroll
    for (int k = 0; k < 4; ++k) g[k] = *(const uint2*)(hb + (size_t)(int)e[k].w * 256 + c0);
    // advance pointers and prefetch next CSR entries (overlap with FMA below)
    uint4 en[4];
#pragma unroll
    for (int k = 0; k < 4; ++k) {
      pp[k] += (t < dg[k] - 1) ? 1 : 0;
      en[k] = csr[pp[k]];
    }
#pragma unroll
    for (int k = 0; k < 4; ++k) {
      if (t < dg[k]) {
        float a0 = b2f(e[k].x & 0xFFFFu), a1 = b2f(e[k].x >> 16), a2 = b2f(e[k].y & 0xFFFFu);
        float a3 = b2f(e[k].y >> 16), a4 = b2f(e[k].z & 0xFFFFu), a5 = b2f(e[k].z >> 16);
        float mxv = fmaf(a0, w0.x, fmaf(a1, w1.x, fmaf(a2, w2.x, fmaf(a3, w3.x, fmaf(a4, w4.x, fmaf(a5, w5.x, b2f(g[k].x & 0xFFFFu) + bf.x))))));
        float myv = fmaf(a0, w0.y, fmaf(a1, w1.y, fmaf(a2, w2.y, fmaf(a3, w3.y, fmaf(a4, w4.y, fmaf(a5, w5.y, b2f(g[k].x >> 16) + bf.y))))));
        float mzv = fmaf(a0, w0.z, fmaf(a1, w1.z, fmaf(a2, w2.z, fmaf(a3, w3.z, fmaf(a4, w4.z, fmaf(a5, w5.z, b2f(g[k].y & 0xFFFFu) + bf.z))))));
        float mwv = fmaf(a0, w0.w, fmaf(a1, w1.w, fmaf(a2, w2.w, fmaf(a3, w3.w, fmaf(a4, w4.w, fmaf(a5, w5.w, b2f(g[k].y >> 16) + bf.w))))));
        acc[k].x += mxv > 0.f ? mxv : 0.f;
        acc[k].y += myv > 0.f ? myv : 0.f;
        acc[k].z += mzv > 0.f ? mzv : 0.f;
        acc[k].w += mwv > 0.f ? mwv : 0.f;
      }
      e[k] = en[k];
    }
  }
#pragma unroll
  for (int k = 0; k < 4; ++k) {
    uint2 o;
    o.x = (unsigned int)f2b(acc[k].x) | ((unsigned int)f2b(acc[k].y) << 16);
    o.y = (unsigned int)f2b(acc[k].z) | ((unsigned int)f2b(acc[k].w) << 16);
    *(uint2*)(zb + (size_t)(v0 + k) * 256 + c0) = o;
  }
}

// Fused MLP + per-graph stats: z = relu(zin@W1+b1)@W2+b2 for a 64-row tile; LDS-resident
// C tile feeds segmented per-graph S1/S2 accumulation (atomicAdd; S1/S2 pre-zeroed).
__global__ __launch_bounds__(256, 4) void k_mlp(const unsigned short* __restrict__ A,
                                                const unsigned short* __restrict__ W1p,
                                                const float* __restrict__ b1,
                                                const unsigned short* __restrict__ W2p,
                                                const float* __restrict__ b2,
                                                float* __restrict__ Z,
                                                const int* __restrict__ batchv,
                                                float* __restrict__ S1, float* __restrict__ S2, int M) {
  __shared__ __align__(16) unsigned char smem[33024];        // max(64*256*2, 32*258*4)
  unsigned short* t1s = (unsigned short*)smem;
  float* zc = (float*)smem;                                  // 32 x (stride 258) fp32
  int l = threadIdx.x & 63;
  int w = threadIdx.x >> 6;
  int mloc = l & 15, q = l >> 4;
  int rowg = (w & 1) * 32;
  int colh = (w >> 1) * 128;
  int row0 = blockIdx.x * 64;

  const unsigned short* ap[2];
#pragma unroll
  for (int rt = 0; rt < 2; ++rt) {
    int r = row0 + rowg + rt * 16 + mloc;
    if (r > M - 1) r = M - 1;
    ap[rt] = A + (size_t)r * 256 + q * 8;
  }
  f32x4 acc[2][8];
#pragma unroll
  for (int rt = 0; rt < 2; ++rt)
#pragma unroll
    for (int ct = 0; ct < 8; ++ct) acc[rt][ct] = (f32x4){0.f, 0.f, 0.f, 0.f};

  const unsigned short* w1base = W1p + ((size_t)(colh >> 7)) * 32768 + (size_t)l * 8;
#pragma unroll
  for (int ks = 0; ks < 8; ++ks) {
    s16x8 a0 = *(const s16x8*)(ap[0] + ks * 32);
    s16x8 a1 = *(const s16x8*)(ap[1] + ks * 32);
#pragma unroll
    for (int ct = 0; ct < 8; ++ct) {
      s16x8 b = *(const s16x8*)(w1base + ks * 4096 + ct * 512);
      acc[0][ct] = __builtin_amdgcn_mfma_f32_16x16x32_bf16(a0, b, acc[0][ct], 0, 0, 0);
      acc[1][ct] = __builtin_amdgcn_mfma_f32_16x16x32_bf16(a1, b, acc[1][ct], 0, 0, 0);
    }
  }
  // epilogue 1: bias+relu -> LDS bf16 (XOR swizzle on 16-B chunks)
#pragma unroll
  for (int ct = 0; ct < 8; ++ct) {
    int col = colh + ct * 16 + mloc;
    float bv = b1[col];
    int cc = col >> 3, pos = col & 7;
#pragma unroll
    for (int rt = 0; rt < 2; ++rt)
#pragma unroll
      for (int r = 0; r < 4; ++r) {
        int row = rowg + rt * 16 + q * 4 + r;
        float v = acc[rt][ct][r] + bv;
        v = v > 0.f ? v : 0.f;
        t1s[row * 256 + ((cc ^ (row & 31)) << 3) + pos] = f2b(v);
      }
  }
  __syncthreads();
  // GEMM2: A from LDS
#pragma unroll
  for (int rt = 0; rt < 2; ++rt)
#pragma unroll
    for (int ct = 0; ct < 8; ++ct) acc[rt][ct] = (f32x4){0.f, 0.f, 0.f, 0.f};
  const unsigned short* w2base = W2p + ((size_t)(colh >> 7)) * 32768 + (size_t)l * 8;
#pragma unroll
  for (int ks = 0; ks < 8; ++ks) {
    s16x8 a[2];
#pragma unroll
    for (int rt = 0; rt < 2; ++rt) {
      int row = rowg + rt * 16 + mloc;
      int cc = (q + ks * 4) ^ (row & 31);
      a[rt] = *(const s16x8*)(t1s + row * 256 + (cc << 3));
    }
#pragma unroll
    for (int ct = 0; ct < 8; ++ct) {
      s16x8 b = *(const s16x8*)(w2base + ks * 4096 + ct * 512);
      acc[0][ct] = __builtin_amdgcn_mfma_f32_16x16x32_bf16(a[0], b, acc[0][ct], 0, 0, 0);
      acc[1][ct] = __builtin_amdgcn_mfma_f32_16x16x32_bf16(a[1], b, acc[1][ct], 0, 0, 0);
    }
  }
  // bias into registers
  float bv2[8];
#pragma unroll
  for (int ct = 0; ct < 8; ++ct) bv2[ct] = b2[colh + ct * 16 + mloc];

  // epilogue 2: bounce through LDS per 32-row half -> coalesced stores + fused stats
#pragma unroll
  for (int half = 0; half < 2; ++half) {
    __syncthreads();
    if ((w & 1) == half) {
#pragma unroll
      for (int ct = 0; ct < 8; ++ct) {
        int col = colh + ct * 16 + mloc;
#pragma unroll
        for (int rt = 0; rt < 2; ++rt)
#pragma unroll
          for (int r = 0; r < 4; ++r) {
            int row = rt * 16 + q * 4 + r;               // 0..31 local
            zc[row * 258 + col] = acc[rt][ct][r] + bv2[ct];
          }
      }
    }
    __syncthreads();
    int baserow = row0 + half * 32;
#pragma unroll
    for (int it = 0; it < 8; ++it) {
      int row = it * 4 + w;                               // one row per wave
      int grow = baserow + row;
      float4 vv = *(const float4*)(zc + row * 258 + l * 4);
      if (grow < M) *(float4*)(Z + (size_t)grow * 256 + l * 4) = vv;
    }
    // fused per-graph S1/S2 (thread = column, segmented by sorted batch)
    {
      int c = threadIdx.x;
      int rend = (M - baserow) < 32 ? (M - baserow) : 32;
      if (rend > 0) {
        float s1 = 0.f, s2 = 0.f;
        int gcur = batchv[baserow];
        for (int row = 0; row < rend; ++row) {
          int g = batchv[baserow + row];
          if (g != gcur) {
            atomicAdd(&S1[(size_t)gcur * 256 + c], s1);
            atomicAdd(&S2[(size_t)gcur * 256 + c], s2);
            s1 = 0.f; s2 = 0.f; gcur = g;
          }
          float v = zc[row * 258 + c];
          s1 += v;
          s2 = fmaf(v, v, s2);
        }
        atomicAdd(&S1[(size_t)gcur * 256 + c], s1);
        atomicAdd(&S2[(size_t)gcur * 256 + c], s2);
      }
    }
  }
}

// attention: score[row] = tanh(h@W1+b1) @ w2 + b2 — fused
__global__ __launch_bounds__(256) void k_att(const unsigned short* __restrict__ A,
                                             const unsigned short* __restrict__ Bp,
                                             const float* __restrict__ b1,
                                             const float* __restrict__ w2,
                                             const float* __restrict__ b2,
                                             float* __restrict__ scores, int M) {
  int l = threadIdx.x & 63;
  int w = threadIdx.x >> 6;
  int mloc = l & 15, q = l >> 4;
  int row0 = blockIdx.x * 128 + w * 32;

  int r0 = row0 + mloc;      if (r0 > M - 1) r0 = M - 1;
  int r1 = row0 + 16 + mloc; if (r1 > M - 1) r1 = M - 1;
  const unsigned short* ap0 = A + (size_t)r0 * 256 + q * 8;
  const unsigned short* ap1 = A + (size_t)r1 * 256 + q * 8;
  const unsigned short* bp = Bp + (size_t)l * 8;

  f32x4 acc[2][8];
#pragma unroll
  for (int rt = 0; rt < 2; ++rt)
#pragma unroll
    for (int ct = 0; ct < 8; ++ct) acc[rt][ct] = (f32x4){0.f, 0.f, 0.f, 0.f};
#pragma unroll
  for (int ks = 0; ks < 8; ++ks) {
    s16x8 a0 = *(const s16x8*)(ap0 + ks * 32);
    s16x8 a1 = *(const s16x8*)(ap1 + ks * 32);
#pragma unroll
    for (int ct = 0; ct < 8; ++ct) {
      s16x8 b = *(const s16x8*)(bp + ks * 4096 + ct * 512);
      acc[0][ct] = __builtin_amdgcn_mfma_f32_16x16x32_bf16(a0, b, acc[0][ct], 0, 0, 0);
      acc[1][ct] = __builtin_amdgcn_mfma_f32_16x16x32_bf16(a1, b, acc[1][ct], 0, 0, 0);
    }
  }
  float bv[8], wv[8];
#pragma unroll
  for (int ct = 0; ct < 8; ++ct) {
    bv[ct] = b1[ct * 16 + mloc];
    wv[ct] = w2[ct * 16 + mloc];
  }
  float b2v = b2[0];
#pragma unroll
  for (int rt = 0; rt < 2; ++rt)
#pragma unroll
    for (int r = 0; r < 4; ++r) {
      float p = 0.0f;
#pragma unroll
      for (int ct = 0; ct < 8; ++ct) p = fmaf(tanhf(acc[rt][ct][r] + bv[ct]), wv[ct], p);
      p += __shfl_xor(p, 1, 64);
      p += __shfl_xor(p, 2, 64);
      p += __shfl_xor(p, 4, 64);
      p += __shfl_xor(p, 8, 64);
      int row = row0 + rt * 16 + q * 4 + r;
      if (mloc == 0 && row < M) scores[row] = p + b2v;
    }
}

// BN partial: block b sums S1/S2 over graphs [b*32,(b+1)*32) — coalesced (thread = column)
__global__ __launch_bounds__(256) void k_bn_part(const float* __restrict__ S1, const float* __restrict__ S2,
                                                 float* __restrict__ P1, float* __restrict__ P2) {
  int b = blockIdx.x, c = threadIdx.x;
  float s1 = 0.0f, s2 = 0.0f;
  for (int g = b * 32; g < b * 32 + 32; ++g) {
    s1 += S1[(size_t)g * 256 + c];
    s2 += S2[(size_t)g * 256 + c];
  }
  P1[(size_t)b * 256 + c] = s1;
  P2[(size_t)b * 256 + c] = s2;
}

// BN finalize: fold 64 partials per column, compute abuf/bbuf (thread = column, no reduce)
__global__ __launch_bounds__(256) void k_bn_fin2(const float* __restrict__ P1, const float* __restrict__ P2,
                                                 const float* __restrict__ gamma, const float* __restrict__ beta,
                                                 float* __restrict__ abuf, float* __restrict__ bbuf, int n) {
  int c = threadIdx.x;
  float s1 = 0.0f, s2 = 0.0f;
  for (int r = 0; r < 64; ++r) {
    s1 += P1[(size_t)r * 256 + c];
    s2 += P2[(size_t)r * 256 + c];
  }
  float inv = 1.0f / (float)n;
  float mu = s1 * inv;
  float var = s2 * inv - mu * mu;
  float rstd = rsqrtf(var + 1e-5f);
  float a = gamma[c] * rstd;
  abuf[c] = a;
  bbuf[c] = beta[c] - mu * a;
}

// per-graph: gmean/rinv from S1/S2 in-block, apply BN+PairNorm+relu; zeroes S1/S2 for next layer.
template <int LAST>
__global__ __launch_bounds__(256) void k_apply(float* __restrict__ z, const float* __restrict__ abuf,
                                               const float* __restrict__ bbuf, const int* __restrict__ gstart,
                                               const int* __restrict__ cnti, const float* __restrict__ cntf,
                                               float* __restrict__ S1, float* __restrict__ S2,
                                               unsigned short* __restrict__ hb) {
  __shared__ float rT[256], rM[256];
  int g = blockIdx.x, c = threadIdx.x;
  float a = abuf[c], b = bbuf[c];
  size_t idx = (size_t)g * 256 + c;
  float s1 = S1[idx];
  float s2 = S2[idx];
  S1[idx] = 0.0f;          // re-zero for next layer's fused stats
  S2[idx] = 0.0f;
  float nr = (float)cnti[g];
  float ic = 1.0f / cntf[g];
  float mean = (a * s1 + nr * b) * ic;
  float term = fmaf(a * a, s2, fmaf(2.0f * a * b, s1, nr * b * b));
  rT[c] = term;
  rM[c] = mean * mean;
  __syncthreads();
  for (int off = 128; off; off >>= 1) {
    if (c < off) { rT[c] += rT[c + off]; rM[c] += rM[c + off]; }
    __syncthreads();
  }
  float cr = nr > 0.0f ? 1.0f : 0.0f;
  float rinv = rsqrtf(1e-5f + rT[0] * ic - cr * rM[0]);
  int r0 = gstart[g], r1 = r0 + cnti[g];
  for (int r = r0; r < r1; ++r) {
    float v = (fmaf(a, z[(size_t)r * 256 + c], b) - mean) * rinv;
    v = v > 0.0f ? v : 0.0f;
    hb[(size_t)r * 256 + c] = f2b(v);
    if (LAST) z[(size_t)r * 256 + c] = v;
  }
}

// per-graph fused pooling + output
__global__ __launch_bounds__(256) void k_poolout(const float* __restrict__ h, const float* __restrict__ scores,
                                                 const int* __restrict__ gstart, const int* __restrict__ cnti,
                                                 const float* __restrict__ cntf, float* __restrict__ out) {
  int g = blockIdx.x, c = threadIdx.x;
  int r0 = gstart[g], r1 = r0 + cnti[g];
  float ma = 0.0f, aa = 0.0f, mx = 0.0f, wa = 0.0f;
  for (int r = r0; r < r1; ++r) {
    float wgt = __expf(scores[r]);
    float hv = h[(size_t)r * 256 + c];
    ma += hv;
    aa = fmaf(hv, wgt, aa);
    mx = fmaxf(mx, hv);
    wa += wgt;
  }
  out[(size_t)g * 768 + c] = ma / cntf[g];
  out[(size_t)g * 768 + 256 + c] = mx;
  out[(size_t)g * 768 + 512 + c] = aa / (wa + 1e-8f);
}

extern "C" void kernel_launch(void* const* d_in, const int* in_sizes, int n_in,
                              void* d_out, int out_size, void* d_ws, size_t ws_size,
                              hipStream_t stream) {
  const float* x         = (const float*)d_in[0];
  const float* edge_attr = (const float*)d_in[1];
  const float* node_w    = (const float*)d_in[2];
  const float* node_b    = (const float*)d_in[3];
  const float* edge_w    = (const float*)d_in[4];
  const float* edge_b    = (const float*)d_in[5];
  const float* conv_w    = (const float*)d_in[6];
  const float* conv_b    = (const float*)d_in[7];
  const float* mlp_w1    = (const float*)d_in[8];
  const float* mlp_b1    = (const float*)d_in[9];
  const float* mlp_w2    = (const float*)d_in[10];
  const float* mlp_b2    = (const float*)d_in[11];
  const float* eps       = (const float*)d_in[12];
  const float* bn_gamma  = (const float*)d_in[13];
  const float* bn_beta   = (const float*)d_in[14];
  const float* att_w1    = (const float*)d_in[15];
  const float* att_b1    = (const float*)d_in[16];
  const float* att_w2    = (const float*)d_in[17];
  const float* att_b2    = (const float*)d_in[18];
  const int*   eidx      = (const int*)d_in[19];
  const int*   batch     = (const int*)d_in[20];
  float* out = (float*)d_out;
  float* ws  = (float*)d_ws;

  float*          zbuf = ws + O_Z;
  unsigned short* zb   = (unsigned short*)(ws + O_ZB);
  unsigned short* hb   = (unsigned short*)(ws + O_HB);
  float* S1    = ws + O_S1;
  float* S2    = ws + O_S2;
  float* abuf  = ws + O_ABUF;
  float* bbuf  = ws + O_BBUF;
  int*   cnti  = (int*)(ws + O_CNTI);
  float* cntf  = ws + O_CNTF;
  float* scor  = ws + O_SCOR;
  int*   curs  = (int*)(ws + O_SCOR);
  float* weff  = ws + O_WEFF;
  float* beff  = ws + O_BEFF;
  int*   deg   = (int*)(ws + O_DEG);
  int*   strt  = (int*)(ws + O_STRT);
  int*   bsum  = (int*)(ws + O_BSUM);
  uint4* csr   = (uint4*)(ws + O_CSR);
  unsigned short* w1p = (unsigned short*)(ws + O_W1P);
  unsigned short* w2p = (unsigned short*)(ws + O_W2P);
  unsigned short* atp = (unsigned short*)(ws + O_ATP);
  int*   gst   = (int*)(ws + O_GST);
  unsigned short* nwp = (unsigned short*)(ws + O_NWP);
  float* bnp1  = ws + O_BNP;
  float* bnp2  = ws + O_BNP + 16384;
  const int* esrc = eidx;
  const int* edst = eidx + EE;

  // graph counts + offsets
  k_zero<<<8, 256, 0, stream>>>((float*)cnti, GG);
  k_count<<<(NN + 255) / 256, 256, 0, stream>>>(batch, cnti, NN);
  k_gscan<<<1, 256, 0, stream>>>(cnti, gst, cntf);

  // fused edge weights + weight packing + MFMA node embedding
  k_wfuse<<<LL, 256, 0, stream>>>(edge_w, edge_b, conv_w, conv_b, weff, beff);
  k_pack_all<<<528, 256, 0, stream>>>(mlp_w1, mlp_w2, att_w1, w1p, w2p, atp);
  k_pack_node<<<12, 256, 0, stream>>>(node_w, nwp);
  k_embed_mfma<<<(NN + 63) / 64, 256, 0, stream>>>(x, nwp, node_b, hb, NN);

  // S1/S2 zero for layer-0 fused stats (subsequent layers re-zeroed by k_apply)
  k_zero<<<1024, 256, 0, stream>>>(S1, 2 * 524288);

  // CSR build (by dst)
  const int nscan = (NN + 255) / 256;  // 391
  k_zero<<<256, 256, 0, stream>>>((float*)deg, NN);
  k_deg<<<(EE + 255) / 256, 256, 0, stream>>>(edst, deg, EE);
  k_scan_part<<<nscan, 256, 0, stream>>>(deg, strt, bsum, NN);
  k_scan_top<<<1, 512, 0, stream>>>(bsum, nscan);
  k_scan_add<<<nscan, 256, 0, stream>>>(strt, bsum, curs, NN);
  k_fill<<<(EE + 255) / 256, 256, 0, stream>>>(edge_attr, esrc, edst, curs, csr, EE);

  const int mtiles64  = (NN + 63) / 64;    // 1563
  const int mtiles128 = (NN + 127) / 128;  // 782

  for (int i = 0; i < LL; ++i) {
    k_edge_csr<<<NN / 16, 256, 0, stream>>>(csr, strt, deg, weff + (size_t)i * 1536,
                                            beff + (size_t)i * 256, hb, zb, eps, i, NN);
    k_mlp<<<mtiles64, 256, 0, stream>>>(zb, w1p + (size_t)i * 65536, mlp_b1 + (size_t)i * 256,
                                        w2p + (size_t)i * 65536, mlp_b2 + (size_t)i * 256, zbuf,
                                        batch, S1, S2, NN);
    k_bn_part<<<64, 256, 0, stream>>>(S1, S2, bnp1, bnp2);
    k_bn_fin2<<<1, 256, 0, stream>>>(bnp1, bnp2, bn_gamma + (size_t)i * 256,
                                     bn_beta + (size_t)i * 256, abuf, bbuf, NN);
    if (i == LL - 1)
      k_apply<1><<<GG, 256, 0, stream>>>(zbuf, abuf, bbuf, gst, cnti, cntf, S1, S2, hb);
    else
      k_apply<0><<<GG, 256, 0, stream>>>(zbuf, abuf, bbuf, gst, cnti, cntf, S1, S2, hb);
  }

  // pooling (zbuf holds fp32 h)
  k_att<<<mtiles128, 256, 0, stream>>>(hb, atp, att_b1, att_w2, att_b2, scor, NN);
  k_poolout<<<GG, 256, 0, stream>>>(zbuf, scor, gst, cnti, cntf, out);
}